// Round 8
// baseline (525.322 us; speedup 1.0000x reference)
//
#include <hip/hip_runtime.h>
#include <stdint.h>

typedef __attribute__((ext_vector_type(8))) short bf16x8;
typedef __attribute__((ext_vector_type(4))) short short4v;
typedef __attribute__((ext_vector_type(4))) float f32x4;

#define MFMA16(a, b, c) __builtin_amdgcn_mfma_f32_16x16x32_bf16((a), (b), (c), 0, 0, 0)

__device__ __forceinline__ float b2f(short s) {
  unsigned u = ((unsigned)(unsigned short)s) << 16;
  return __builtin_bit_cast(float, u);
}
__device__ __forceinline__ short f2b(float f) {
  unsigned u = __builtin_bit_cast(unsigned, f);
  u = (u + 0x7fffu + ((u >> 16) & 1u)) >> 16;
  return (short)u;
}

// async global->LDS, 16B per lane; lds dest is wave-uniform base (HW adds lane*16)
__device__ __forceinline__ void gl_lds16(const short* g, short* l) {
  __builtin_amdgcn_global_load_lds((const __attribute__((address_space(1))) void*)g,
                                   (__attribute__((address_space(3))) void*)l, 16, 0, 0);
}

// -------- convert f32 -> bf16 (8 elems/thread) --------
__global__ __launch_bounds__(256) void convert_kernel(const float* __restrict__ src,
                                                      short* __restrict__ dst, int n) {
  int i = (blockIdx.x * 256 + threadIdx.x) * 8;
  if (i >= n) return;
  f32x4 a = *(const f32x4*)(src + i);
  f32x4 b = *(const f32x4*)(src + i + 4);
  short4v o0, o1;
#pragma unroll
  for (int j = 0; j < 4; ++j) { o0[j] = f2b(a[j]); o1[j] = f2b(b[j]); }
  *(short4v*)(dst + i) = o0;
  *(short4v*)(dst + i + 4) = o1;
}

// -------- RMSNorm: f32 in, f32 gamma, bf16 out; one block per row of 1024 --------
__global__ __launch_bounds__(256) void rmsnorm_f32(const float* __restrict__ X,
                                                   const float* __restrict__ G,
                                                   short* __restrict__ O) {
  int row = blockIdx.x;
  int t = threadIdx.x;
  f32x4 v = *(const f32x4*)(X + (size_t)row * 1024 + t * 4);
  float ss = 0.f;
#pragma unroll
  for (int j = 0; j < 4; ++j) ss += v[j] * v[j];
#pragma unroll
  for (int d = 1; d < 64; d <<= 1) ss += __shfl_xor(ss, d, 64);
  __shared__ float red[4];
  if ((t & 63) == 0) red[t >> 6] = ss;
  __syncthreads();
  float tot = red[0] + red[1] + red[2] + red[3];
  float rinv = rsqrtf(tot * (1.0f / 1024.0f) + 1e-5f);
  f32x4 g = *(const f32x4*)(G + t * 4);
  short4v o;
#pragma unroll
  for (int j = 0; j < 4; ++j) o[j] = f2b(v[j] * rinv * g[j]);
  *(short4v*)(O + (size_t)row * 1024 + t * 4) = o;
}

// ---------------- GEMM (256 thr, 4 waves 2x2, 128x128, BK=32, gl_lds staging)
// MODE 0: C = AB (bf16 out)
// MODE 2: C = silu(Res_bf16) * AB (bf16 out, in-place over Res allowed)
// MODE 3: QKV-split: N=1024 segments -> C/C1/C2; RoPE fused on segments 0,1 (Q,K)
template <int MODE>
__global__ __launch_bounds__(256) void gemm_bt(const short* __restrict__ A,
                                               const short* __restrict__ Bt,
                                               const void* Res, void* C,
                                               void* C1, void* C2,
                                               int M, int N, int K) {
  __shared__ __attribute__((aligned(16))) short Alds[128 * 32];
  __shared__ __attribute__((aligned(16))) short Blds[128 * 32];
  int tid = threadIdx.x;
  int lane = tid & 63, w = tid >> 6;
  int wr = w >> 1, wc = w & 1;
  int l15 = lane & 15, lg = lane >> 4;
  int m0 = blockIdx.y * 128, n0 = blockIdx.x * 128;
  void* Cw = C;
  int ncol0 = n0;
  int seg = 0;
  if (MODE == 3) {
    seg = n0 >> 10;
    Cw = (seg == 0) ? C : (seg == 1) ? C1 : C2;
    ncol0 = n0 & 1023;
  }
  f32x4 acc[4][4] = {};
  int arow = tid >> 2, acol = (tid & 3) * 8;  // LDS byte off = 16*tid (linear)
  const short* Ap = A + (size_t)(m0 + arow) * K + acol;
  const short* Bp = Bt + (size_t)(n0 + arow) * K + acol;
  int wb = w * 512;
  for (int k0 = 0; k0 < K; k0 += 32) {
    gl_lds16(Ap + k0, Alds + wb);
    gl_lds16(Ap + (size_t)64 * K + k0, Alds + 2048 + wb);
    gl_lds16(Bp + k0, Blds + wb);
    gl_lds16(Bp + (size_t)64 * K + k0, Blds + 2048 + wb);
    __syncthreads();
    bf16x8 af[4], bfr[4];
#pragma unroll
    for (int i = 0; i < 4; ++i) {
      af[i] = *(const bf16x8*)(Alds + (wr * 64 + i * 16 + l15) * 32 + lg * 8);
      bfr[i] = *(const bf16x8*)(Blds + (wc * 64 + i * 16 + l15) * 32 + lg * 8);
    }
#pragma unroll
    for (int mi = 0; mi < 4; ++mi)
#pragma unroll
      for (int ni = 0; ni < 4; ++ni)
        acc[mi][ni] = MFMA16(af[mi], bfr[ni], acc[mi][ni]);
    __syncthreads();
  }
#pragma unroll
  for (int mi = 0; mi < 4; ++mi) {
#pragma unroll
    for (int r = 0; r < 4; ++r) {
      int row = m0 + wr * 64 + mi * 16 + lg * 4 + r;
      size_t base = (size_t)row * N;
#pragma unroll
      for (int ni = 0; ni < 4; ++ni) {
        int col = ncol0 + wc * 64 + ni * 16 + l15;
        float v = acc[mi][ni][r];
        if (MODE == 3 && seg <= 1) {
          // fused RoPE: pair = adjacent cols; col parity == lane parity
          int pos = row & 2047;
          int ii = (col & 62) >> 1;
          float invf2 = exp2f(-(float)ii * 0.4152410118f) * 0.15915494309f;  // rev/pos
          float rev = (float)pos * invf2;
          rev -= rintf(rev);                 // [-0.5, 0.5] revolutions
          float angr = rev * 6.28318530718f; // [-pi, pi]
          float sn = __sinf(angr), cs = __cosf(angr);
          float partner = __shfl_xor(v, 1, 64);
          float t = partner * sn;
          v = v * cs + (((l15 & 1) == 0) ? -t : t);
        }
        if (MODE == 2) {
          float rr = b2f(((const short*)Res)[base + col]);
          v = rr / (1.f + __expf(-rr)) * v;
          ((short*)Cw)[base + col] = f2b(v);
        } else {
          ((short*)Cw)[base + col] = f2b(v);
        }
      }
    }
  }
}

// ---------------- GEMM wide: 512 thr, 8 waves 2x4, 128x128, C = AB + Resf (f32 out)
__global__ __launch_bounds__(512) void gemm_wide(const short* __restrict__ A,
                                                 const short* __restrict__ Bt,
                                                 const float* Res, float* C,
                                                 int M, int N, int K) {
  __shared__ __attribute__((aligned(16))) short Alds[128 * 32];
  __shared__ __attribute__((aligned(16))) short Blds[128 * 32];
  int tid = threadIdx.x;
  int lane = tid & 63, w = tid >> 6;       // 8 waves
  int wr = w >> 2, wc = w & 3;             // 2 x 4
  int l15 = lane & 15, lg = lane >> 4;
  int m0 = blockIdx.y * 128, n0 = blockIdx.x * 128;
  f32x4 acc[4][2] = {};
  int arow = tid >> 2, acol = (tid & 3) * 8;
  const short* Ap = A + (size_t)(m0 + arow) * K + acol;
  const short* Bp = Bt + (size_t)(n0 + arow) * K + acol;
  int wb = w * 512;
  for (int k0 = 0; k0 < K; k0 += 32) {
    gl_lds16(Ap + k0, Alds + wb);
    gl_lds16(Bp + k0, Blds + wb);
    __syncthreads();
    bf16x8 af[4], bfr[2];
#pragma unroll
    for (int i = 0; i < 4; ++i)
      af[i] = *(const bf16x8*)(Alds + (wr * 64 + i * 16 + l15) * 32 + lg * 8);
#pragma unroll
    for (int i = 0; i < 2; ++i)
      bfr[i] = *(const bf16x8*)(Blds + (wc * 32 + i * 16 + l15) * 32 + lg * 8);
#pragma unroll
    for (int mi = 0; mi < 4; ++mi)
#pragma unroll
      for (int ni = 0; ni < 2; ++ni)
        acc[mi][ni] = MFMA16(af[mi], bfr[ni], acc[mi][ni]);
    __syncthreads();
  }
#pragma unroll
  for (int mi = 0; mi < 4; ++mi) {
#pragma unroll
    for (int r = 0; r < 4; ++r) {
      int row = m0 + wr * 64 + mi * 16 + lg * 4 + r;
      size_t base = (size_t)row * N;
#pragma unroll
      for (int ni = 0; ni < 2; ++ni) {
        int col = n0 + wc * 32 + ni * 16 + l15;
        C[base + col] = acc[mi][ni][r] + Res[base + col];
      }
    }
  }
}

// ---------------- V transpose: V[B*S][H*64] -> Vt[bh][64][2048] ----------------
__global__ __launch_bounds__(256) void vtranspose(const short* __restrict__ V,
                                                  short* __restrict__ Vt) {
  __shared__ short T[64 * 72];
  int bh = blockIdx.y;
  int s0 = blockIdx.x * 64;
  int t = threadIdx.x;
  int r = t >> 2, cq = t & 3;
  const short* src = V + (size_t)((bh >> 4) * 2048 + s0 + r) * 1024 + (bh & 15) * 64 + cq * 16;
  *(int4*)(T + r * 72 + cq * 16) = *(const int4*)src;
  *(int4*)(T + r * 72 + cq * 16 + 8) = *(const int4*)(src + 8);
  __syncthreads();
  int d = t >> 2, sq = t & 3;
  short* dst = Vt + (size_t)bh * 131072 + (size_t)d * 2048 + s0 + sq * 16;
#pragma unroll
  for (int q = 0; q < 4; ++q) {
    short4v o;
#pragma unroll
    for (int j = 0; j < 4; ++j) o[j] = T[(sq * 16 + q * 4 + j) * 72 + d];
    *(short4v*)(dst + q * 4) = o;
  }
}

// ---------------- Flash attention v4: barrier-free, KVBLK=32, reg double-buffered K/V
// grid 1024 x 256; bh = bx&31; qt pairing balances heavy/light blocks per round.
// p = exp(s/8 - 24): ratio-exact vs true softmax. l via ones-MFMA.
__global__ __launch_bounds__(256) void attn4(const short* __restrict__ Q,
                                             const short* __restrict__ K,
                                             const short* __restrict__ Vt,
                                             short* __restrict__ O) {
  __shared__ __attribute__((aligned(16))) short Ptlds[4][32 * 20];
  int bx = blockIdx.x;
  int bh = bx & 31;
  int p = bx >> 5;
  int qt = (p & 1) ? (p >> 1) : (31 - (p >> 1));
  int tid = threadIdx.x;
  int w = tid >> 6, lane = tid & 63;
  int l15 = lane & 15, lg = lane >> 4;
  int qbase = qt * 64 + w * 16;
  size_t rowbase = (size_t)(bh >> 4) * 2048 * 1024 + (size_t)(bh & 15) * 64;
  const short* vtb = Vt + (size_t)bh * 131072;
  bf16x8 qf[2];
  {
    const short* qp = Q + rowbase + (size_t)(qbase + l15) * 1024 + lg * 8;
    qf[0] = *(const bf16x8*)qp;
    qf[1] = *(const bf16x8*)(qp + 32);
  }
  bf16x8 ones;
#pragma unroll
  for (int j = 0; j < 8; ++j) ones[j] = (short)0x3F80;
  f32x4 oacc[4] = {};
  f32x4 lacc = {};
  int nchunk = 2 * qt + 2;  // 32-key chunks
  short* pt = Ptlds[w];
  const short* Kb0 = K + rowbase;
  // register double-buffer: current chunk's K/V frags
  bf16x8 kf[2][2], vf[4];
#pragma unroll
  for (int g = 0; g < 2; ++g) {
    const short* kp = Kb0 + (size_t)(g * 16 + l15) * 1024 + lg * 8;
    kf[g][0] = *(const bf16x8*)kp;
    kf[g][1] = *(const bf16x8*)(kp + 32);
  }
#pragma unroll
  for (int t = 0; t < 4; ++t)
    vf[t] = *(const bf16x8*)(vtb + (size_t)(t * 16 + l15) * 2048 + lg * 8);
  for (int kt = 0; kt < nchunk; ++kt) {
    int kn = (kt + 1 < nchunk) ? kt + 1 : kt;
    int kstart = kt * 32;
    // QK^T on current K frags
    f32x4 s[2] = {};
#pragma unroll
    for (int g = 0; g < 2; ++g) {
      s[g] = MFMA16(qf[0], kf[g][0], s[g]);
      s[g] = MFMA16(qf[1], kf[g][1], s[g]);
    }
    // issue next-chunk K and V loads now; consumed next iteration (latency
    // hides under softmax+LDS+PV; compiler keeps them in flight via vmcnt)
    bf16x8 knf[2][2], vnf[4];
#pragma unroll
    for (int g = 0; g < 2; ++g) {
      const short* kp = Kb0 + (size_t)(kn * 32 + g * 16 + l15) * 1024 + lg * 8;
      knf[g][0] = *(const bf16x8*)kp;
      knf[g][1] = *(const bf16x8*)(kp + 32);
    }
#pragma unroll
    for (int t = 0; t < 4; ++t)
      vnf[t] = *(const bf16x8*)(vtb + (size_t)(t * 16 + l15) * 2048 + kn * 32 + lg * 8);
    // p = exp(s/8 - 24), causal mask -> 0
#pragma unroll
    for (int g = 0; g < 2; ++g) {
      short4v pk;
#pragma unroll
      for (int r = 0; r < 4; ++r) {
        int qg = qbase + lg * 4 + r;
        int kg = kstart + g * 16 + l15;
        float v = __expf(s[g][r] * 0.125f - 24.f);
        pk[r] = f2b((kg > qg) ? 0.f : v);
      }
      *(short4v*)(pt + (g * 16 + l15) * 20 + lg * 4) = pk;
    }
    // P^T read as A-frag (within-wave LDS RAW; in-order DS, no barrier)
    bf16x8 pa;
#pragma unroll
    for (int j = 0; j < 8; ++j) pa[j] = pt[(lg * 8 + j) * 20 + l15];
#pragma unroll
    for (int t = 0; t < 4; ++t) oacc[t] = MFMA16(pa, vf[t], oacc[t]);
    lacc = MFMA16(pa, ones, lacc);
    // rotate buffers (SSA'd by compiler)
#pragma unroll
    for (int g = 0; g < 2; ++g) { kf[g][0] = knf[g][0]; kf[g][1] = knf[g][1]; }
#pragma unroll
    for (int t = 0; t < 4; ++t) vf[t] = vnf[t];
  }
#pragma unroll
  for (int t = 0; t < 4; ++t) {
#pragma unroll
    for (int r = 0; r < 4; ++r) {
      int row = qbase + lg * 4 + r;
      float denom = fmaxf(lacc[r], 1e-30f);
      O[rowbase + (size_t)row * 1024 + t * 16 + l15] = f2b(oacc[t][r] / denom);
    }
  }
}

extern "C" void kernel_launch(void* const* d_in, const int* in_sizes, int n_in,
                              void* d_out, int out_size, void* d_ws, size_t ws_size,
                              hipStream_t stream) {
  const float* xf = (const float*)d_in[0];
  const float* G1f = (const float*)d_in[8];
  const float* G2f = (const float*)d_in[9];
  char* ws = (char*)d_ws;
  const size_t MB = 1048576;
  short* Wslot = (short*)(ws);            // [0,8): WOb early, then W1/W3/W2
  short* WOb   = (short*)(ws);
  short* Wcat  = (short*)(ws + 8 * MB);   // [8,14): fused QKV weights
  short* Vt    = (short*)(ws + 8 * MB);   // [8,16): V^T (after Wcat dead)
  short* h     = (short*)(ws + 16 * MB);  // [16,24)
  short* Qb    = (short*)(ws + 24 * MB);  // [24,32)
  short* Kb    = (short*)(ws + 32 * MB);  // [32,40)
  short* Vb    = (short*)(ws + 40 * MB);  // [40,48)
  short* att   = (short*)(ws + 48 * MB);  // [48,56)
  short* w1x   = Qb;                      // [24,56): Q/K/V/att dead by FFN time
  float* x1f   = (float*)d_out;
  float* outf  = (float*)d_out;

  dim3 blk(256);
  convert_kernel<<<512, blk, 0, stream>>>((const float*)d_in[1], Wcat, 1048576);
  convert_kernel<<<512, blk, 0, stream>>>((const float*)d_in[2], Wcat + 1048576, 1048576);
  convert_kernel<<<512, blk, 0, stream>>>((const float*)d_in[3], Wcat + 2097152, 1048576);
  convert_kernel<<<512, blk, 0, stream>>>((const float*)d_in[4], WOb, 1048576);

  rmsnorm_f32<<<4096, blk, 0, stream>>>(xf, G1f, h);
  dim3 gqkv(24, 32);
  gemm_bt<3><<<gqkv, blk, 0, stream>>>(h, Wcat, nullptr, Qb, Kb, Vb, 4096, 1024, 1024);
  dim3 gvt(32, 32);
  vtranspose<<<gvt, blk, 0, stream>>>(Vb, Vt);
  attn4<<<1024, blk, 0, stream>>>(Qb, Kb, Vt, att);
  dim3 g1(8, 32);
  gemm_wide<<<g1, dim3(512), 0, stream>>>(att, WOb, xf, x1f, 4096, 1024, 1024);
  rmsnorm_f32<<<4096, blk, 0, stream>>>(x1f, G2f, h);
  dim3 g2(32, 32);
  convert_kernel<<<2048, blk, 0, stream>>>((const float*)d_in[5], Wslot, 4194304);
  gemm_bt<0><<<g2, blk, 0, stream>>>(h, Wslot, nullptr, w1x, nullptr, nullptr, 4096, 4096, 1024);
  convert_kernel<<<2048, blk, 0, stream>>>((const float*)d_in[7], Wslot, 4194304);
  gemm_bt<2><<<g2, blk, 0, stream>>>(h, Wslot, w1x, w1x, nullptr, nullptr, 4096, 4096, 1024);
  convert_kernel<<<2048, blk, 0, stream>>>((const float*)d_in[6], Wslot, 4194304);
  gemm_wide<<<g1, dim3(512), 0, stream>>>(w1x, Wslot, x1f, outf, 4096, 1024, 4096);
}

// Round 9
// 460.768 us; speedup vs baseline: 1.1401x; 1.1401x over previous
//
#include <hip/hip_runtime.h>
#include <stdint.h>

typedef __attribute__((ext_vector_type(8))) short bf16x8;
typedef __attribute__((ext_vector_type(4))) short short4v;
typedef __attribute__((ext_vector_type(4))) float f32x4;

#define MFMA16(a, b, c) __builtin_amdgcn_mfma_f32_16x16x32_bf16((a), (b), (c), 0, 0, 0)

__device__ __forceinline__ float b2f(short s) {
  unsigned u = ((unsigned)(unsigned short)s) << 16;
  return __builtin_bit_cast(float, u);
}
__device__ __forceinline__ short f2b(float f) {
  unsigned u = __builtin_bit_cast(unsigned, f);
  u = (u + 0x7fffu + ((u >> 16) & 1u)) >> 16;
  return (short)u;
}

// async global->LDS, 16B per lane; lds dest is wave-uniform base (HW adds lane*16)
__device__ __forceinline__ void gl_lds16(const short* g, short* l) {
  __builtin_amdgcn_global_load_lds((const __attribute__((address_space(1))) void*)g,
                                   (__attribute__((address_space(3))) void*)l, 16, 0, 0);
}

// -------- convert f32 -> bf16 (8 elems/thread) --------
__global__ __launch_bounds__(256) void convert_kernel(const float* __restrict__ src,
                                                      short* __restrict__ dst, int n) {
  int i = (blockIdx.x * 256 + threadIdx.x) * 8;
  if (i >= n) return;
  f32x4 a = *(const f32x4*)(src + i);
  f32x4 b = *(const f32x4*)(src + i + 4);
  short4v o0, o1;
#pragma unroll
  for (int j = 0; j < 4; ++j) { o0[j] = f2b(a[j]); o1[j] = f2b(b[j]); }
  *(short4v*)(dst + i) = o0;
  *(short4v*)(dst + i + 4) = o1;
}

// -------- RMSNorm: f32 in, f32 gamma, bf16 out; one block per row of 1024 --------
__global__ __launch_bounds__(256) void rmsnorm_f32(const float* __restrict__ X,
                                                   const float* __restrict__ G,
                                                   short* __restrict__ O) {
  int row = blockIdx.x;
  int t = threadIdx.x;
  f32x4 v = *(const f32x4*)(X + (size_t)row * 1024 + t * 4);
  float ss = 0.f;
#pragma unroll
  for (int j = 0; j < 4; ++j) ss += v[j] * v[j];
#pragma unroll
  for (int d = 1; d < 64; d <<= 1) ss += __shfl_xor(ss, d, 64);
  __shared__ float red[4];
  if ((t & 63) == 0) red[t >> 6] = ss;
  __syncthreads();
  float tot = red[0] + red[1] + red[2] + red[3];
  float rinv = rsqrtf(tot * (1.0f / 1024.0f) + 1e-5f);
  f32x4 g = *(const f32x4*)(G + t * 4);
  short4v o;
#pragma unroll
  for (int j = 0; j < 4; ++j) o[j] = f2b(v[j] * rinv * g[j]);
  *(short4v*)(O + (size_t)row * 1024 + t * 4) = o;
}

// ---------------- GEMM 2-phase (T3 minimum recipe): 256 thr, 4 waves 2x2, 128x128,
// BK=32, double-buffered LDS; stage(t+1) issued BEFORE compute(t); ONE barrier/iter
// (compiler's vmcnt(0)+lgkmcnt(0) drain before s_barrier = "next tile ready").
// MODE 0: C = AB (bf16) | MODE 2: C = silu(Res)*AB (bf16, in-place ok)
// MODE 3: QKV-split + fused RoPE on segments 0,1
template <int MODE>
__global__ __launch_bounds__(256) void gemm_bt(const short* __restrict__ A,
                                               const short* __restrict__ Bt,
                                               const void* Res, void* C,
                                               void* C1, void* C2,
                                               int M, int N, int K) {
  __shared__ __attribute__((aligned(16))) short Alds[2][128 * 32];
  __shared__ __attribute__((aligned(16))) short Blds[2][128 * 32];
  int tid = threadIdx.x;
  int lane = tid & 63, w = tid >> 6;
  int wr = w >> 1, wc = w & 1;
  int l15 = lane & 15, lg = lane >> 4;
  int m0 = blockIdx.y * 128, n0 = blockIdx.x * 128;
  void* Cw = C;
  int ncol0 = n0;
  int seg = 0;
  if (MODE == 3) {
    seg = n0 >> 10;
    Cw = (seg == 0) ? C : (seg == 1) ? C1 : C2;
    ncol0 = n0 & 1023;
  }
  f32x4 acc[4][4] = {};
  int arow = tid >> 2, acol = (tid & 3) * 8;  // LDS byte off = 16*tid (linear)
  const short* Ap = A + (size_t)(m0 + arow) * K + acol;
  const short* Bp = Bt + (size_t)(n0 + arow) * K + acol;
  int wb = w * 512;
#define STAGE_BT(buf, k0s)                                   \
  {                                                          \
    gl_lds16(Ap + (k0s), &Alds[buf][0] + wb);                \
    gl_lds16(Ap + (size_t)64 * K + (k0s), &Alds[buf][0] + 2048 + wb); \
    gl_lds16(Bp + (k0s), &Blds[buf][0] + wb);                \
    gl_lds16(Bp + (size_t)64 * K + (k0s), &Blds[buf][0] + 2048 + wb); \
  }
  STAGE_BT(0, 0);
  __syncthreads();
  int cur = 0;
  for (int k0 = 0; k0 < K; k0 += 32) {
    if (k0 + 32 < K) STAGE_BT(cur ^ 1, k0 + 32);
    bf16x8 af[4], bfr[4];
#pragma unroll
    for (int i = 0; i < 4; ++i) {
      af[i] = *(const bf16x8*)(&Alds[cur][0] + (wr * 64 + i * 16 + l15) * 32 + lg * 8);
      bfr[i] = *(const bf16x8*)(&Blds[cur][0] + (wc * 64 + i * 16 + l15) * 32 + lg * 8);
    }
#pragma unroll
    for (int mi = 0; mi < 4; ++mi)
#pragma unroll
      for (int ni = 0; ni < 4; ++ni)
        acc[mi][ni] = MFMA16(af[mi], bfr[ni], acc[mi][ni]);
    __syncthreads();
    cur ^= 1;
  }
#undef STAGE_BT
#pragma unroll
  for (int mi = 0; mi < 4; ++mi) {
#pragma unroll
    for (int r = 0; r < 4; ++r) {
      int row = m0 + wr * 64 + mi * 16 + lg * 4 + r;
      size_t base = (size_t)row * N;
#pragma unroll
      for (int ni = 0; ni < 4; ++ni) {
        int col = ncol0 + wc * 64 + ni * 16 + l15;
        float v = acc[mi][ni][r];
        if (MODE == 3 && seg <= 1) {
          // fused RoPE: pair = adjacent cols; col parity == lane parity
          int pos = row & 2047;
          int ii = (col & 62) >> 1;
          float invf2 = exp2f(-(float)ii * 0.4152410118f) * 0.15915494309f;  // rev/pos
          float rev = (float)pos * invf2;
          rev -= rintf(rev);
          float angr = rev * 6.28318530718f;
          float sn = __sinf(angr), cs = __cosf(angr);
          float partner = __shfl_xor(v, 1, 64);
          float t = partner * sn;
          v = v * cs + (((l15 & 1) == 0) ? -t : t);
        }
        if (MODE == 2) {
          float rr = b2f(((const short*)Res)[base + col]);
          v = rr / (1.f + __expf(-rr)) * v;
          ((short*)Cw)[base + col] = f2b(v);
        } else {
          ((short*)Cw)[base + col] = f2b(v);
        }
      }
    }
  }
}

// ---------------- GEMM wide 2-phase: 512 thr, 8 waves 2x4, 128x128, C = AB + Resf
__global__ __launch_bounds__(512) void gemm_wide(const short* __restrict__ A,
                                                 const short* __restrict__ Bt,
                                                 const float* Res, float* C,
                                                 int M, int N, int K) {
  __shared__ __attribute__((aligned(16))) short Alds[2][128 * 32];
  __shared__ __attribute__((aligned(16))) short Blds[2][128 * 32];
  int tid = threadIdx.x;
  int lane = tid & 63, w = tid >> 6;       // 8 waves
  int wr = w >> 2, wc = w & 3;             // 2 x 4
  int l15 = lane & 15, lg = lane >> 4;
  int m0 = blockIdx.y * 128, n0 = blockIdx.x * 128;
  f32x4 acc[4][2] = {};
  int arow = tid >> 2, acol = (tid & 3) * 8;  // 512 thr cover 128x32: byte = 16*tid
  const short* Ap = A + (size_t)(m0 + arow) * K + acol;
  const short* Bp = Bt + (size_t)(n0 + arow) * K + acol;
  int wb = w * 512;
#define STAGE_W(buf, k0s)                       \
  {                                             \
    gl_lds16(Ap + (k0s), &Alds[buf][0] + wb);   \
    gl_lds16(Bp + (k0s), &Blds[buf][0] + wb);   \
  }
  STAGE_W(0, 0);
  __syncthreads();
  int cur = 0;
  for (int k0 = 0; k0 < K; k0 += 32) {
    if (k0 + 32 < K) STAGE_W(cur ^ 1, k0 + 32);
    bf16x8 af[4], bfr[2];
#pragma unroll
    for (int i = 0; i < 4; ++i)
      af[i] = *(const bf16x8*)(&Alds[cur][0] + (wr * 64 + i * 16 + l15) * 32 + lg * 8);
#pragma unroll
    for (int i = 0; i < 2; ++i)
      bfr[i] = *(const bf16x8*)(&Blds[cur][0] + (wc * 32 + i * 16 + l15) * 32 + lg * 8);
#pragma unroll
    for (int mi = 0; mi < 4; ++mi)
#pragma unroll
      for (int ni = 0; ni < 2; ++ni)
        acc[mi][ni] = MFMA16(af[mi], bfr[ni], acc[mi][ni]);
    __syncthreads();
    cur ^= 1;
  }
#undef STAGE_W
#pragma unroll
  for (int mi = 0; mi < 4; ++mi) {
#pragma unroll
    for (int r = 0; r < 4; ++r) {
      int row = m0 + wr * 64 + mi * 16 + lg * 4 + r;
      size_t base = (size_t)row * N;
#pragma unroll
      for (int ni = 0; ni < 2; ++ni) {
        int col = n0 + wc * 32 + ni * 16 + l15;
        C[base + col] = acc[mi][ni][r] + Res[base + col];
      }
    }
  }
}

// ---------------- V transpose: V[B*S][H*64] -> Vt[bh][64][2048] ----------------
__global__ __launch_bounds__(256) void vtranspose(const short* __restrict__ V,
                                                  short* __restrict__ Vt) {
  __shared__ short T[64 * 72];
  int bh = blockIdx.y;
  int s0 = blockIdx.x * 64;
  int t = threadIdx.x;
  int r = t >> 2, cq = t & 3;
  const short* src = V + (size_t)((bh >> 4) * 2048 + s0 + r) * 1024 + (bh & 15) * 64 + cq * 16;
  *(int4*)(T + r * 72 + cq * 16) = *(const int4*)src;
  *(int4*)(T + r * 72 + cq * 16 + 8) = *(const int4*)(src + 8);
  __syncthreads();
  int d = t >> 2, sq = t & 3;
  short* dst = Vt + (size_t)bh * 131072 + (size_t)d * 2048 + s0 + sq * 16;
#pragma unroll
  for (int q = 0; q < 4; ++q) {
    short4v o;
#pragma unroll
    for (int j = 0; j < 4; ++j) o[j] = T[(sq * 16 + q * 4 + j) * 72 + d];
    *(short4v*)(dst + q * 4) = o;
  }
}

// ---------------- Flash attention v3 (round-7 proven, 149us): barrier-free,
// KVBLK=64, fixed-offset softmax, l via ones-MFMA, heavy blocks first.
__global__ __launch_bounds__(256) void attn3(const short* __restrict__ Q,
                                             const short* __restrict__ K,
                                             const short* __restrict__ Vt,
                                             short* __restrict__ O) {
  __shared__ __attribute__((aligned(16))) short Ptlds[4][64 * 20];
  int bx = blockIdx.x;
  int bh = bx & 31;
  int qt = 31 - (bx >> 5);
  int tid = threadIdx.x;
  int w = tid >> 6, lane = tid & 63;
  int l15 = lane & 15, lg = lane >> 4;
  int qbase = qt * 64 + w * 16;
  size_t rowbase = (size_t)(bh >> 4) * 2048 * 1024 + (size_t)(bh & 15) * 64;
  const short* vtb = Vt + (size_t)bh * 131072;
  bf16x8 qf[2];
  {
    const short* qp = Q + rowbase + (size_t)(qbase + l15) * 1024 + lg * 8;
    qf[0] = *(const bf16x8*)qp;
    qf[1] = *(const bf16x8*)(qp + 32);
  }
  bf16x8 ones;
#pragma unroll
  for (int j = 0; j < 8; ++j) ones[j] = (short)0x3F80;
  f32x4 oacc[4] = {};
  f32x4 lacc = {};
  int nchunk = qt + 1;
  short* pt = Ptlds[w];
  const short* Kb0 = K + rowbase;
  for (int kt = 0; kt < nchunk; ++kt) {
    int kstart = kt * 64;
    f32x4 s[4] = {};
#pragma unroll
    for (int g = 0; g < 4; ++g) {
      const short* kp = Kb0 + (size_t)(kstart + g * 16 + l15) * 1024 + lg * 8;
      bf16x8 k0 = *(const bf16x8*)kp;
      bf16x8 k1 = *(const bf16x8*)(kp + 32);
      s[g] = MFMA16(qf[0], k0, s[g]);
      s[g] = MFMA16(qf[1], k1, s[g]);
    }
#pragma unroll
    for (int g = 0; g < 4; ++g) {
      short4v pk;
#pragma unroll
      for (int r = 0; r < 4; ++r) {
        int qg = qbase + lg * 4 + r;
        int kg = kstart + g * 16 + l15;
        float v = __expf(s[g][r] * 0.125f - 24.f);
        pk[r] = f2b((kg > qg) ? 0.f : v);
      }
      *(short4v*)(pt + (g * 16 + l15) * 20 + lg * 4) = pk;
    }
    bf16x8 pa0, pa1;
#pragma unroll
    for (int j = 0; j < 8; ++j) {
      pa0[j] = pt[(lg * 8 + j) * 20 + l15];
      pa1[j] = pt[(32 + lg * 8 + j) * 20 + l15];
    }
#pragma unroll
    for (int t = 0; t < 4; ++t) {
      const short* vp = vtb + (size_t)(t * 16 + l15) * 2048 + kstart + lg * 8;
      bf16x8 vf0 = *(const bf16x8*)vp;
      bf16x8 vf1 = *(const bf16x8*)(vp + 32);
      oacc[t] = MFMA16(pa0, vf0, oacc[t]);
      oacc[t] = MFMA16(pa1, vf1, oacc[t]);
    }
    lacc = MFMA16(pa0, ones, lacc);
    lacc = MFMA16(pa1, ones, lacc);
  }
#pragma unroll
  for (int t = 0; t < 4; ++t) {
#pragma unroll
    for (int r = 0; r < 4; ++r) {
      int row = qbase + lg * 4 + r;
      float denom = fmaxf(lacc[r], 1e-30f);
      O[rowbase + (size_t)row * 1024 + t * 16 + l15] = f2b(oacc[t][r] / denom);
    }
  }
}

extern "C" void kernel_launch(void* const* d_in, const int* in_sizes, int n_in,
                              void* d_out, int out_size, void* d_ws, size_t ws_size,
                              hipStream_t stream) {
  const float* xf = (const float*)d_in[0];
  const float* G1f = (const float*)d_in[8];
  const float* G2f = (const float*)d_in[9];
  char* ws = (char*)d_ws;
  const size_t MB = 1048576;
  short* Wslot = (short*)(ws);            // [0,8): WOb early, then W1/W3/W2
  short* WOb   = (short*)(ws);
  short* Wcat  = (short*)(ws + 8 * MB);   // [8,14): fused QKV weights
  short* Vt    = (short*)(ws + 8 * MB);   // [8,16): V^T (after Wcat dead)
  short* h     = (short*)(ws + 16 * MB);  // [16,24)
  short* Qb    = (short*)(ws + 24 * MB);  // [24,32)
  short* Kb    = (short*)(ws + 32 * MB);  // [32,40)
  short* Vb    = (short*)(ws + 40 * MB);  // [40,48)
  short* att   = (short*)(ws + 48 * MB);  // [48,56)
  short* w1x   = Qb;                      // [24,56): Q/K/V/att dead by FFN time
  float* x1f   = (float*)d_out;
  float* outf  = (float*)d_out;

  dim3 blk(256);
  convert_kernel<<<512, blk, 0, stream>>>((const float*)d_in[1], Wcat, 1048576);
  convert_kernel<<<512, blk, 0, stream>>>((const float*)d_in[2], Wcat + 1048576, 1048576);
  convert_kernel<<<512, blk, 0, stream>>>((const float*)d_in[3], Wcat + 2097152, 1048576);
  convert_kernel<<<512, blk, 0, stream>>>((const float*)d_in[4], WOb, 1048576);

  rmsnorm_f32<<<4096, blk, 0, stream>>>(xf, G1f, h);
  dim3 gqkv(24, 32);
  gemm_bt<3><<<gqkv, blk, 0, stream>>>(h, Wcat, nullptr, Qb, Kb, Vb, 4096, 1024, 1024);
  dim3 gvt(32, 32);
  vtranspose<<<gvt, blk, 0, stream>>>(Vb, Vt);
  attn3<<<1024, blk, 0, stream>>>(Qb, Kb, Vt, att);
  dim3 g1(8, 32);
  gemm_wide<<<g1, dim3(512), 0, stream>>>(att, WOb, xf, x1f, 4096, 1024, 1024);
  rmsnorm_f32<<<4096, blk, 0, stream>>>(x1f, G2f, h);
  dim3 g2(32, 32);
  convert_kernel<<<2048, blk, 0, stream>>>((const float*)d_in[5], Wslot, 4194304);
  gemm_bt<0><<<g2, blk, 0, stream>>>(h, Wslot, nullptr, w1x, nullptr, nullptr, 4096, 4096, 1024);
  convert_kernel<<<2048, blk, 0, stream>>>((const float*)d_in[7], Wslot, 4194304);
  gemm_bt<2><<<g2, blk, 0, stream>>>(h, Wslot, w1x, w1x, nullptr, nullptr, 4096, 4096, 1024);
  convert_kernel<<<2048, blk, 0, stream>>>((const float*)d_in[6], Wslot, 4194304);
  gemm_wide<<<g1, dim3(512), 0, stream>>>(w1x, Wslot, x1f, outf, 4096, 1024, 4096);
}

// Round 10
// 362.306 us; speedup vs baseline: 1.4499x; 1.2718x over previous
//
#include <hip/hip_runtime.h>
#include <stdint.h>

typedef __attribute__((ext_vector_type(8))) short bf16x8;
typedef __attribute__((ext_vector_type(4))) short short4v;
typedef __attribute__((ext_vector_type(4))) float f32x4;

#define MFMA16(a, b, c) __builtin_amdgcn_mfma_f32_16x16x32_bf16((a), (b), (c), 0, 0, 0)

__device__ __forceinline__ float b2f(short s) {
  unsigned u = ((unsigned)(unsigned short)s) << 16;
  return __builtin_bit_cast(float, u);
}
__device__ __forceinline__ short f2b(float f) {
  unsigned u = __builtin_bit_cast(unsigned, f);
  u = (u + 0x7fffu + ((u >> 16) & 1u)) >> 16;
  return (short)u;
}

// async global->LDS, 16B per lane; lds dest is wave-uniform base (HW adds lane*16)
__device__ __forceinline__ void gl_lds16(const short* g, short* l) {
  __builtin_amdgcn_global_load_lds((const __attribute__((address_space(1))) void*)g,
                                   (__attribute__((address_space(3))) void*)l, 16, 0, 0);
}

// -------- convert f32 -> bf16 (8 elems/thread) --------
__global__ __launch_bounds__(256) void convert_kernel(const float* __restrict__ src,
                                                      short* __restrict__ dst, int n) {
  int i = (blockIdx.x * 256 + threadIdx.x) * 8;
  if (i >= n) return;
  f32x4 a = *(const f32x4*)(src + i);
  f32x4 b = *(const f32x4*)(src + i + 4);
  short4v o0, o1;
#pragma unroll
  for (int j = 0; j < 4; ++j) { o0[j] = f2b(a[j]); o1[j] = f2b(b[j]); }
  *(short4v*)(dst + i) = o0;
  *(short4v*)(dst + i + 4) = o1;
}

// -------- RMSNorm: f32 in, f32 gamma, bf16 out; one block per row of 1024 --------
__global__ __launch_bounds__(256) void rmsnorm_f32(const float* __restrict__ X,
                                                   const float* __restrict__ G,
                                                   short* __restrict__ O) {
  int row = blockIdx.x;
  int t = threadIdx.x;
  f32x4 v = *(const f32x4*)(X + (size_t)row * 1024 + t * 4);
  float ss = 0.f;
#pragma unroll
  for (int j = 0; j < 4; ++j) ss += v[j] * v[j];
#pragma unroll
  for (int d = 1; d < 64; d <<= 1) ss += __shfl_xor(ss, d, 64);
  __shared__ float red[4];
  if ((t & 63) == 0) red[t >> 6] = ss;
  __syncthreads();
  float tot = red[0] + red[1] + red[2] + red[3];
  float rinv = rsqrtf(tot * (1.0f / 1024.0f) + 1e-5f);
  f32x4 g = *(const f32x4*)(G + t * 4);
  short4v o;
#pragma unroll
  for (int j = 0; j < 4; ++j) o[j] = f2b(v[j] * rinv * g[j]);
  *(short4v*)(O + (size_t)row * 1024 + t * 4) = o;
}

// ---------------- GEMM 2-phase: 256 thr, 4 waves 2x2, 128x128, BK=32, dbuf LDS
// MODE 0: C = AB | MODE 2: C = silu(Res)*AB | MODE 3: QKV-split + fused RoPE
template <int MODE>
__global__ __launch_bounds__(256) void gemm_bt(const short* __restrict__ A,
                                               const short* __restrict__ Bt,
                                               const void* Res, void* C,
                                               void* C1, void* C2,
                                               int M, int N, int K) {
  __shared__ __attribute__((aligned(16))) short Alds[2][128 * 32];
  __shared__ __attribute__((aligned(16))) short Blds[2][128 * 32];
  int tid = threadIdx.x;
  int lane = tid & 63, w = tid >> 6;
  int wr = w >> 1, wc = w & 1;
  int l15 = lane & 15, lg = lane >> 4;
  int m0 = blockIdx.y * 128, n0 = blockIdx.x * 128;
  void* Cw = C;
  int ncol0 = n0;
  int seg = 0;
  if (MODE == 3) {
    seg = n0 >> 10;
    Cw = (seg == 0) ? C : (seg == 1) ? C1 : C2;
    ncol0 = n0 & 1023;
  }
  f32x4 acc[4][4] = {};
  int arow = tid >> 2, acol = (tid & 3) * 8;
  const short* Ap = A + (size_t)(m0 + arow) * K + acol;
  const short* Bp = Bt + (size_t)(n0 + arow) * K + acol;
  int wb = w * 512;
#define STAGE_BT(buf, k0s)                                   \
  {                                                          \
    gl_lds16(Ap + (k0s), &Alds[buf][0] + wb);                \
    gl_lds16(Ap + (size_t)64 * K + (k0s), &Alds[buf][0] + 2048 + wb); \
    gl_lds16(Bp + (k0s), &Blds[buf][0] + wb);                \
    gl_lds16(Bp + (size_t)64 * K + (k0s), &Blds[buf][0] + 2048 + wb); \
  }
  STAGE_BT(0, 0);
  __syncthreads();
  int cur = 0;
  for (int k0 = 0; k0 < K; k0 += 32) {
    if (k0 + 32 < K) STAGE_BT(cur ^ 1, k0 + 32);
    bf16x8 af[4], bfr[4];
#pragma unroll
    for (int i = 0; i < 4; ++i) {
      af[i] = *(const bf16x8*)(&Alds[cur][0] + (wr * 64 + i * 16 + l15) * 32 + lg * 8);
      bfr[i] = *(const bf16x8*)(&Blds[cur][0] + (wc * 64 + i * 16 + l15) * 32 + lg * 8);
    }
#pragma unroll
    for (int mi = 0; mi < 4; ++mi)
#pragma unroll
      for (int ni = 0; ni < 4; ++ni)
        acc[mi][ni] = MFMA16(af[mi], bfr[ni], acc[mi][ni]);
    __syncthreads();
    cur ^= 1;
  }
#undef STAGE_BT
#pragma unroll
  for (int mi = 0; mi < 4; ++mi) {
#pragma unroll
    for (int r = 0; r < 4; ++r) {
      int row = m0 + wr * 64 + mi * 16 + lg * 4 + r;
      size_t base = (size_t)row * N;
#pragma unroll
      for (int ni = 0; ni < 4; ++ni) {
        int col = ncol0 + wc * 64 + ni * 16 + l15;
        float v = acc[mi][ni][r];
        if (MODE == 3 && seg <= 1) {
          int pos = row & 2047;
          int ii = (col & 62) >> 1;
          float invf2 = exp2f(-(float)ii * 0.4152410118f) * 0.15915494309f;
          float rev = (float)pos * invf2;
          rev -= rintf(rev);
          float angr = rev * 6.28318530718f;
          float sn = __sinf(angr), cs = __cosf(angr);
          float partner = __shfl_xor(v, 1, 64);
          float t = partner * sn;
          v = v * cs + (((l15 & 1) == 0) ? -t : t);
        }
        if (MODE == 2) {
          float rr = b2f(((const short*)Res)[base + col]);
          v = rr / (1.f + __expf(-rr)) * v;
          ((short*)Cw)[base + col] = f2b(v);
        } else {
          ((short*)Cw)[base + col] = f2b(v);
        }
      }
    }
  }
}

// ---------------- GEMM wide 2-phase: 512 thr, 8 waves 2x4, 128x128, C = AB + Resf
__global__ __launch_bounds__(512) void gemm_wide(const short* __restrict__ A,
                                                 const short* __restrict__ Bt,
                                                 const float* Res, float* C,
                                                 int M, int N, int K) {
  __shared__ __attribute__((aligned(16))) short Alds[2][128 * 32];
  __shared__ __attribute__((aligned(16))) short Blds[2][128 * 32];
  int tid = threadIdx.x;
  int lane = tid & 63, w = tid >> 6;
  int wr = w >> 2, wc = w & 3;
  int l15 = lane & 15, lg = lane >> 4;
  int m0 = blockIdx.y * 128, n0 = blockIdx.x * 128;
  f32x4 acc[4][2] = {};
  int arow = tid >> 2, acol = (tid & 3) * 8;
  const short* Ap = A + (size_t)(m0 + arow) * K + acol;
  const short* Bp = Bt + (size_t)(n0 + arow) * K + acol;
  int wb = w * 512;
#define STAGE_W(buf, k0s)                       \
  {                                             \
    gl_lds16(Ap + (k0s), &Alds[buf][0] + wb);   \
    gl_lds16(Bp + (k0s), &Blds[buf][0] + wb);   \
  }
  STAGE_W(0, 0);
  __syncthreads();
  int cur = 0;
  for (int k0 = 0; k0 < K; k0 += 32) {
    if (k0 + 32 < K) STAGE_W(cur ^ 1, k0 + 32);
    bf16x8 af[4], bfr[2];
#pragma unroll
    for (int i = 0; i < 4; ++i)
      af[i] = *(const bf16x8*)(&Alds[cur][0] + (wr * 64 + i * 16 + l15) * 32 + lg * 8);
#pragma unroll
    for (int i = 0; i < 2; ++i)
      bfr[i] = *(const bf16x8*)(&Blds[cur][0] + (wc * 32 + i * 16 + l15) * 32 + lg * 8);
#pragma unroll
    for (int mi = 0; mi < 4; ++mi)
#pragma unroll
      for (int ni = 0; ni < 2; ++ni)
        acc[mi][ni] = MFMA16(af[mi], bfr[ni], acc[mi][ni]);
    __syncthreads();
    cur ^= 1;
  }
#undef STAGE_W
#pragma unroll
  for (int mi = 0; mi < 4; ++mi) {
#pragma unroll
    for (int r = 0; r < 4; ++r) {
      int row = m0 + wr * 64 + mi * 16 + lg * 4 + r;
      size_t base = (size_t)row * N;
#pragma unroll
      for (int ni = 0; ni < 2; ++ni) {
        int col = n0 + wc * 32 + ni * 16 + l15;
        C[base + col] = acc[mi][ni][r] + Res[base + col];
      }
    }
  }
}

// ---------------- V transpose: V[B*S][H*64] -> Vt[bh][64][2048] ----------------
__global__ __launch_bounds__(256) void vtranspose(const short* __restrict__ V,
                                                  short* __restrict__ Vt) {
  __shared__ short T[64 * 72];
  int bh = blockIdx.y;
  int s0 = blockIdx.x * 64;
  int t = threadIdx.x;
  int r = t >> 2, cq = t & 3;
  const short* src = V + (size_t)((bh >> 4) * 2048 + s0 + r) * 1024 + (bh & 15) * 64 + cq * 16;
  *(int4*)(T + r * 72 + cq * 16) = *(const int4*)src;
  *(int4*)(T + r * 72 + cq * 16 + 8) = *(const int4*)(src + 8);
  __syncthreads();
  int d = t >> 2, sq = t & 3;
  short* dst = Vt + (size_t)bh * 131072 + (size_t)d * 2048 + s0 + sq * 16;
#pragma unroll
  for (int q = 0; q < 4; ++q) {
    short4v o;
#pragma unroll
    for (int j = 0; j < 4; ++j) o[j] = T[(sq * 16 + q * 4 + j) * 72 + d];
    *(short4v*)(dst + q * 4) = o;
  }
}

// ---------------- Flash attention v6: LDS-staged K/V shared by 4 waves,
// 2-phase double-buffer (same schedule as the GEMMs), stage_rc XOR swizzle
// (linear LDS dest for gl_lds + inverse-swizzled GLOBAL source + swizzled read).
// Softmax identical to green attn3: p = exp(s/8 - 24), l via ones-MFMA.
__global__ __launch_bounds__(256) void attn6(const short* __restrict__ Q,
                                             const short* __restrict__ K,
                                             const short* __restrict__ Vt,
                                             short* __restrict__ O) {
  __shared__ __attribute__((aligned(16))) short Klds[2][64 * 64];
  __shared__ __attribute__((aligned(16))) short Vlds[2][64 * 64];
  __shared__ __attribute__((aligned(16))) short Ptlds[4][64 * 20];
  int bx = blockIdx.x;
  int bh = bx & 31;
  int qt = 31 - (bx >> 5);  // heavy blocks first
  int tid = threadIdx.x;
  int w = tid >> 6, lane = tid & 63;
  int l15 = lane & 15, lg = lane >> 4;
  int qbase = qt * 64 + w * 16;
  size_t rowbase = (size_t)(bh >> 4) * 2048 * 1024 + (size_t)(bh & 15) * 64;
  const short* vtb = Vt + (size_t)bh * 131072;
  const short* Kb0 = K + rowbase;
  bf16x8 qf[2];
  {
    const short* qp = Q + rowbase + (size_t)(qbase + l15) * 1024 + lg * 8;
    qf[0] = *(const bf16x8*)qp;
    qf[1] = *(const bf16x8*)(qp + 32);
  }
  bf16x8 ones;
#pragma unroll
  for (int j = 0; j < 8; ++j) ones[j] = (short)0x3F80;
  f32x4 oacc[4] = {};
  f32x4 lacc = {};
  int nchunk = qt + 1;  // 64-key chunks, uniform across waves
  short* pt = Ptlds[w];
  // staging geometry: idx = s*256 + w*64 + lane; row = idx>>3 (0..63),
  // c = idx&7 (16B unit), swizzled source unit csw = c ^ (row&7).
  int i0 = w * 64 + lane;
  int r0 = i0 >> 3, c0 = i0 & 7, cs0 = c0 ^ (r0 & 7);
  int i1 = 256 + i0;
  int r1 = i1 >> 3, c1 = i1 & 7, cs1 = c1 ^ (r1 & 7);
#define STAGE_KV(buf, kt)                                                      \
  {                                                                            \
    int ks = (kt) * 64;                                                        \
    gl_lds16(Kb0 + (size_t)(ks + r0) * 1024 + cs0 * 8, &Klds[buf][0] + i0 * 8);\
    gl_lds16(Kb0 + (size_t)(ks + r1) * 1024 + cs1 * 8, &Klds[buf][0] + i1 * 8);\
    gl_lds16(vtb + (size_t)r0 * 2048 + ks + cs0 * 8, &Vlds[buf][0] + i0 * 8);  \
    gl_lds16(vtb + (size_t)r1 * 2048 + ks + cs1 * 8, &Vlds[buf][0] + i1 * 8);  \
  }
  STAGE_KV(0, 0);
  __syncthreads();
  int cur = 0;
  for (int kt = 0; kt < nchunk; ++kt) {
    if (kt + 1 < nchunk) STAGE_KV(cur ^ 1, kt + 1);
    int kstart = kt * 64;
    // QK^T from swizzled LDS: row=g*16+l15, data unit (4*half+lg) ^ (l15&7)
    f32x4 s[4] = {};
#pragma unroll
    for (int g = 0; g < 4; ++g) {
      int krow = g * 16 + l15;
      bf16x8 k0 = *(const bf16x8*)(&Klds[cur][0] + krow * 64 + ((lg ^ (l15 & 7)) * 8));
      bf16x8 k1 = *(const bf16x8*)(&Klds[cur][0] + krow * 64 + (((4 + lg) ^ (l15 & 7)) * 8));
      s[g] = MFMA16(qf[0], k0, s[g]);
      s[g] = MFMA16(qf[1], k1, s[g]);
    }
    // p = exp(s/8 - 24), causal mask -> 0 (identical to attn3)
#pragma unroll
    for (int g = 0; g < 4; ++g) {
      short4v pk;
#pragma unroll
      for (int r = 0; r < 4; ++r) {
        int qg = qbase + lg * 4 + r;
        int kg = kstart + g * 16 + l15;
        float v = __expf(s[g][r] * 0.125f - 24.f);
        pk[r] = f2b((kg > qg) ? 0.f : v);
      }
      *(short4v*)(pt + (g * 16 + l15) * 20 + lg * 4) = pk;
    }
    bf16x8 pa0, pa1;
#pragma unroll
    for (int j = 0; j < 8; ++j) {
      pa0[j] = pt[(lg * 8 + j) * 20 + l15];
      pa1[j] = pt[(32 + lg * 8 + j) * 20 + l15];
    }
    // PV from swizzled LDS: row d = t*16+l15, halves units lg / 4+lg
#pragma unroll
    for (int t = 0; t < 4; ++t) {
      int drow = t * 16 + l15;
      bf16x8 vf0 = *(const bf16x8*)(&Vlds[cur][0] + drow * 64 + ((lg ^ (l15 & 7)) * 8));
      bf16x8 vf1 = *(const bf16x8*)(&Vlds[cur][0] + drow * 64 + (((4 + lg) ^ (l15 & 7)) * 8));
      oacc[t] = MFMA16(pa0, vf0, oacc[t]);
      oacc[t] = MFMA16(pa1, vf1, oacc[t]);
    }
    lacc = MFMA16(pa0, ones, lacc);
    lacc = MFMA16(pa1, ones, lacc);
    __syncthreads();
    cur ^= 1;
  }
#undef STAGE_KV
#pragma unroll
  for (int t = 0; t < 4; ++t) {
#pragma unroll
    for (int r = 0; r < 4; ++r) {
      int row = qbase + lg * 4 + r;
      float denom = fmaxf(lacc[r], 1e-30f);
      O[rowbase + (size_t)row * 1024 + t * 16 + l15] = f2b(oacc[t][r] / denom);
    }
  }
}

extern "C" void kernel_launch(void* const* d_in, const int* in_sizes, int n_in,
                              void* d_out, int out_size, void* d_ws, size_t ws_size,
                              hipStream_t stream) {
  const float* xf = (const float*)d_in[0];
  const float* G1f = (const float*)d_in[8];
  const float* G2f = (const float*)d_in[9];
  char* ws = (char*)d_ws;
  const size_t MB = 1048576;
  short* Wslot = (short*)(ws);            // [0,8): WOb early, then W1/W3/W2
  short* WOb   = (short*)(ws);
  short* Wcat  = (short*)(ws + 8 * MB);   // [8,14): fused QKV weights
  short* Vt    = (short*)(ws + 8 * MB);   // [8,16): V^T (after Wcat dead)
  short* h     = (short*)(ws + 16 * MB);  // [16,24)
  short* Qb    = (short*)(ws + 24 * MB);  // [24,32)
  short* Kb    = (short*)(ws + 32 * MB);  // [32,40)
  short* Vb    = (short*)(ws + 40 * MB);  // [40,48)
  short* att   = (short*)(ws + 48 * MB);  // [48,56)
  short* w1x   = Qb;                      // [24,56): Q/K/V/att dead by FFN time
  float* x1f   = (float*)d_out;
  float* outf  = (float*)d_out;

  dim3 blk(256);
  convert_kernel<<<512, blk, 0, stream>>>((const float*)d_in[1], Wcat, 1048576);
  convert_kernel<<<512, blk, 0, stream>>>((const float*)d_in[2], Wcat + 1048576, 1048576);
  convert_kernel<<<512, blk, 0, stream>>>((const float*)d_in[3], Wcat + 2097152, 1048576);
  convert_kernel<<<512, blk, 0, stream>>>((const float*)d_in[4], WOb, 1048576);

  rmsnorm_f32<<<4096, blk, 0, stream>>>(xf, G1f, h);
  dim3 gqkv(24, 32);
  gemm_bt<3><<<gqkv, blk, 0, stream>>>(h, Wcat, nullptr, Qb, Kb, Vb, 4096, 1024, 1024);
  dim3 gvt(32, 32);
  vtranspose<<<gvt, blk, 0, stream>>>(Vb, Vt);
  attn6<<<1024, blk, 0, stream>>>(Qb, Kb, Vt, att);
  dim3 g1(8, 32);
  gemm_wide<<<g1, dim3(512), 0, stream>>>(att, WOb, xf, x1f, 4096, 1024, 1024);
  rmsnorm_f32<<<4096, blk, 0, stream>>>(x1f, G2f, h);
  dim3 g2(32, 32);
  convert_kernel<<<2048, blk, 0, stream>>>((const float*)d_in[5], Wslot, 4194304);
  gemm_bt<0><<<g2, blk, 0, stream>>>(h, Wslot, nullptr, w1x, nullptr, nullptr, 4096, 4096, 1024);
  convert_kernel<<<2048, blk, 0, stream>>>((const float*)d_in[7], Wslot, 4194304);
  gemm_bt<2><<<g2, blk, 0, stream>>>(h, Wslot, w1x, w1x, nullptr, nullptr, 4096, 4096, 1024);
  convert_kernel<<<2048, blk, 0, stream>>>((const float*)d_in[6], Wslot, 4194304);
  gemm_wide<<<g1, dim3(512), 0, stream>>>(w1x, Wslot, x1f, outf, 4096, 1024, 4096);
}

// Round 11
// 355.839 us; speedup vs baseline: 1.4763x; 1.0182x over previous
//
#include <hip/hip_runtime.h>
#include <stdint.h>

typedef __attribute__((ext_vector_type(8))) short bf16x8;
typedef __attribute__((ext_vector_type(4))) short short4v;
typedef __attribute__((ext_vector_type(4))) float f32x4;

#define MFMA16(a, b, c) __builtin_amdgcn_mfma_f32_16x16x32_bf16((a), (b), (c), 0, 0, 0)

__device__ __forceinline__ float b2f(short s) {
  unsigned u = ((unsigned)(unsigned short)s) << 16;
  return __builtin_bit_cast(float, u);
}
__device__ __forceinline__ short f2b(float f) {
  unsigned u = __builtin_bit_cast(unsigned, f);
  u = (u + 0x7fffu + ((u >> 16) & 1u)) >> 16;
  return (short)u;
}

// async global->LDS, 16B per lane; lds dest is wave-uniform base (HW adds lane*16)
__device__ __forceinline__ void gl_lds16(const short* g, short* l) {
  __builtin_amdgcn_global_load_lds((const __attribute__((address_space(1))) void*)g,
                                   (__attribute__((address_space(3))) void*)l, 16, 0, 0);
}

// -------- convert f32 -> bf16 (8 elems/thread) --------
__global__ __launch_bounds__(256) void convert_kernel(const float* __restrict__ src,
                                                      short* __restrict__ dst, int n) {
  int i = (blockIdx.x * 256 + threadIdx.x) * 8;
  if (i >= n) return;
  f32x4 a = *(const f32x4*)(src + i);
  f32x4 b = *(const f32x4*)(src + i + 4);
  short4v o0, o1;
#pragma unroll
  for (int j = 0; j < 4; ++j) { o0[j] = f2b(a[j]); o1[j] = f2b(b[j]); }
  *(short4v*)(dst + i) = o0;
  *(short4v*)(dst + i + 4) = o1;
}

// -------- RMSNorm: f32 in, f32 gamma, bf16 out; one block per row of 1024 --------
__global__ __launch_bounds__(256) void rmsnorm_f32(const float* __restrict__ X,
                                                   const float* __restrict__ G,
                                                   short* __restrict__ O) {
  int row = blockIdx.x;
  int t = threadIdx.x;
  f32x4 v = *(const f32x4*)(X + (size_t)row * 1024 + t * 4);
  float ss = 0.f;
#pragma unroll
  for (int j = 0; j < 4; ++j) ss += v[j] * v[j];
#pragma unroll
  for (int d = 1; d < 64; d <<= 1) ss += __shfl_xor(ss, d, 64);
  __shared__ float red[4];
  if ((t & 63) == 0) red[t >> 6] = ss;
  __syncthreads();
  float tot = red[0] + red[1] + red[2] + red[3];
  float rinv = rsqrtf(tot * (1.0f / 1024.0f) + 1e-5f);
  f32x4 g = *(const f32x4*)(G + t * 4);
  short4v o;
#pragma unroll
  for (int j = 0; j < 4; ++j) o[j] = f2b(v[j] * rinv * g[j]);
  *(short4v*)(O + (size_t)row * 1024 + t * 4) = o;
}

// ---------------- GEMM 2-phase: 256 thr, 4 waves 2x2, 128x128, BK=32, dbuf LDS
// MODE 0: C = AB | MODE 2: C = silu(Res)*AB | MODE 3: QKV-split + fused RoPE
template <int MODE>
__global__ __launch_bounds__(256) void gemm_bt(const short* __restrict__ A,
                                               const short* __restrict__ Bt,
                                               const void* Res, void* C,
                                               void* C1, void* C2,
                                               int M, int N, int K) {
  __shared__ __attribute__((aligned(16))) short Alds[2][128 * 32];
  __shared__ __attribute__((aligned(16))) short Blds[2][128 * 32];
  int tid = threadIdx.x;
  int lane = tid & 63, w = tid >> 6;
  int wr = w >> 1, wc = w & 1;
  int l15 = lane & 15, lg = lane >> 4;
  int m0 = blockIdx.y * 128, n0 = blockIdx.x * 128;
  void* Cw = C;
  int ncol0 = n0;
  int seg = 0;
  if (MODE == 3) {
    seg = n0 >> 10;
    Cw = (seg == 0) ? C : (seg == 1) ? C1 : C2;
    ncol0 = n0 & 1023;
  }
  f32x4 acc[4][4] = {};
  int arow = tid >> 2, acol = (tid & 3) * 8;
  const short* Ap = A + (size_t)(m0 + arow) * K + acol;
  const short* Bp = Bt + (size_t)(n0 + arow) * K + acol;
  int wb = w * 512;
#define STAGE_BT(buf, k0s)                                   \
  {                                                          \
    gl_lds16(Ap + (k0s), &Alds[buf][0] + wb);                \
    gl_lds16(Ap + (size_t)64 * K + (k0s), &Alds[buf][0] + 2048 + wb); \
    gl_lds16(Bp + (k0s), &Blds[buf][0] + wb);                \
    gl_lds16(Bp + (size_t)64 * K + (k0s), &Blds[buf][0] + 2048 + wb); \
  }
  STAGE_BT(0, 0);
  __syncthreads();
  int cur = 0;
  for (int k0 = 0; k0 < K; k0 += 32) {
    if (k0 + 32 < K) STAGE_BT(cur ^ 1, k0 + 32);
    bf16x8 af[4], bfr[4];
#pragma unroll
    for (int i = 0; i < 4; ++i) {
      af[i] = *(const bf16x8*)(&Alds[cur][0] + (wr * 64 + i * 16 + l15) * 32 + lg * 8);
      bfr[i] = *(const bf16x8*)(&Blds[cur][0] + (wc * 64 + i * 16 + l15) * 32 + lg * 8);
    }
#pragma unroll
    for (int mi = 0; mi < 4; ++mi)
#pragma unroll
      for (int ni = 0; ni < 4; ++ni)
        acc[mi][ni] = MFMA16(af[mi], bfr[ni], acc[mi][ni]);
    __syncthreads();
    cur ^= 1;
  }
#undef STAGE_BT
#pragma unroll
  for (int mi = 0; mi < 4; ++mi) {
#pragma unroll
    for (int r = 0; r < 4; ++r) {
      int row = m0 + wr * 64 + mi * 16 + lg * 4 + r;
      size_t base = (size_t)row * N;
#pragma unroll
      for (int ni = 0; ni < 4; ++ni) {
        int col = ncol0 + wc * 64 + ni * 16 + l15;
        float v = acc[mi][ni][r];
        if (MODE == 3 && seg <= 1) {
          int pos = row & 2047;
          int ii = (col & 62) >> 1;
          float invf2 = exp2f(-(float)ii * 0.4152410118f) * 0.15915494309f;
          float rev = (float)pos * invf2;
          rev -= rintf(rev);
          float angr = rev * 6.28318530718f;
          float sn = __sinf(angr), cs = __cosf(angr);
          float partner = __shfl_xor(v, 1, 64);
          float t = partner * sn;
          v = v * cs + (((l15 & 1) == 0) ? -t : t);
        }
        if (MODE == 2) {
          float rr = b2f(((const short*)Res)[base + col]);
          v = rr / (1.f + __expf(-rr)) * v;
          ((short*)Cw)[base + col] = f2b(v);
        } else {
          ((short*)Cw)[base + col] = f2b(v);
        }
      }
    }
  }
}

// ---------------- GEMM 256x256 2-phase: 512 thr, 8 waves 2x4, BK=32, dbuf LDS,
// stage_rc swizzle (linear LDS dest + inverse-swizzled global src + swizzled read),
// bijective XCD-chunked block swizzle. For W1 (MODE 0) / W3 (MODE 2), M=N=4096.
template <int MODE>
__global__ __launch_bounds__(512, 2) void gemm256(const short* __restrict__ A,
                                                  const short* __restrict__ Bt,
                                                  const void* Res, void* C,
                                                  int M, int N, int K) {
  __shared__ __attribute__((aligned(16))) short Alds[2][256 * 32];
  __shared__ __attribute__((aligned(16))) short Blds[2][256 * 32];
  int tid = threadIdx.x;
  int lane = tid & 63, w = tid >> 6;
  int wr = w >> 2, wc = w & 3;  // 2 x 4 waves
  int l15 = lane & 15, lg = lane >> 4;
  // XCD-chunked swizzle over 1D grid of 256 (256 % 8 == 0 -> bijective)
  int wg = blockIdx.x;
  int swz = (wg & 7) * 32 + (wg >> 3);
  int by = swz >> 4, bx = swz & 15;
  int m0 = by * 256, n0 = bx * 256;
  f32x4 acc[8][4] = {};
  // staging geometry: 16B unit o = j*512 + tid; row = o>>2, c = o&3,
  // source unit csw = c ^ ((row>>1)&3)  (read side applies the same XOR)
  int o0 = tid, o1 = 512 + tid;
  int r0 = o0 >> 2, cs0 = (o0 & 3) ^ ((r0 >> 1) & 3);
  int r1 = o1 >> 2, cs1 = (o1 & 3) ^ ((r1 >> 1) & 3);
  const short* Ap0 = A + (size_t)(m0 + r0) * K + cs0 * 8;
  const short* Ap1 = A + (size_t)(m0 + r1) * K + cs1 * 8;
  const short* Bp0 = Bt + (size_t)(n0 + r0) * K + cs0 * 8;
  const short* Bp1 = Bt + (size_t)(n0 + r1) * K + cs1 * 8;
  int wb = w * 512;  // wave-uniform LDS base (shorts) for instr j=0
#define STAGE_256(buf, k0s)                              \
  {                                                      \
    gl_lds16(Ap0 + (k0s), &Alds[buf][0] + wb);           \
    gl_lds16(Ap1 + (k0s), &Alds[buf][0] + 4096 + wb);    \
    gl_lds16(Bp0 + (k0s), &Blds[buf][0] + wb);           \
    gl_lds16(Bp1 + (k0s), &Blds[buf][0] + 4096 + wb);    \
  }
  STAGE_256(0, 0);
  __syncthreads();
  int cur = 0;
  for (int k0 = 0; k0 < K; k0 += 32) {
    if (k0 + 32 < K) STAGE_256(cur ^ 1, k0 + 32);
    bf16x8 af[8], bfr[4];
#pragma unroll
    for (int i = 0; i < 8; ++i) {
      int ra = wr * 128 + i * 16 + l15;
      int ua = lg ^ ((ra >> 1) & 3);
      af[i] = *(const bf16x8*)(&Alds[cur][0] + ra * 32 + ua * 8);
    }
#pragma unroll
    for (int n = 0; n < 4; ++n) {
      int rb = wc * 64 + n * 16 + l15;
      int ub = lg ^ ((rb >> 1) & 3);
      bfr[n] = *(const bf16x8*)(&Blds[cur][0] + rb * 32 + ub * 8);
    }
#pragma unroll
    for (int i = 0; i < 8; ++i)
#pragma unroll
      for (int n = 0; n < 4; ++n)
        acc[i][n] = MFMA16(af[i], bfr[n], acc[i][n]);
    __syncthreads();
    cur ^= 1;
  }
#undef STAGE_256
#pragma unroll
  for (int i = 0; i < 8; ++i) {
#pragma unroll
    for (int r = 0; r < 4; ++r) {
      int row = m0 + wr * 128 + i * 16 + lg * 4 + r;
      size_t base = (size_t)row * N;
#pragma unroll
      for (int n = 0; n < 4; ++n) {
        int col = n0 + wc * 64 + n * 16 + l15;
        float v = acc[i][n][r];
        if (MODE == 2) {
          float rr = b2f(((const short*)Res)[base + col]);
          v = rr / (1.f + __expf(-rr)) * v;
        }
        ((short*)C)[base + col] = f2b(v);
      }
    }
  }
}

// ---------------- GEMM wide 2-phase: 512 thr, 8 waves 2x4, 128x128, C = AB + Resf
__global__ __launch_bounds__(512) void gemm_wide(const short* __restrict__ A,
                                                 const short* __restrict__ Bt,
                                                 const float* Res, float* C,
                                                 int M, int N, int K) {
  __shared__ __attribute__((aligned(16))) short Alds[2][128 * 32];
  __shared__ __attribute__((aligned(16))) short Blds[2][128 * 32];
  int tid = threadIdx.x;
  int lane = tid & 63, w = tid >> 6;
  int wr = w >> 2, wc = w & 3;
  int l15 = lane & 15, lg = lane >> 4;
  int m0 = blockIdx.y * 128, n0 = blockIdx.x * 128;
  f32x4 acc[4][2] = {};
  int arow = tid >> 2, acol = (tid & 3) * 8;
  const short* Ap = A + (size_t)(m0 + arow) * K + acol;
  const short* Bp = Bt + (size_t)(n0 + arow) * K + acol;
  int wb = w * 512;
#define STAGE_W(buf, k0s)                       \
  {                                             \
    gl_lds16(Ap + (k0s), &Alds[buf][0] + wb);   \
    gl_lds16(Bp + (k0s), &Blds[buf][0] + wb);   \
  }
  STAGE_W(0, 0);
  __syncthreads();
  int cur = 0;
  for (int k0 = 0; k0 < K; k0 += 32) {
    if (k0 + 32 < K) STAGE_W(cur ^ 1, k0 + 32);
    bf16x8 af[4], bfr[2];
#pragma unroll
    for (int i = 0; i < 4; ++i)
      af[i] = *(const bf16x8*)(&Alds[cur][0] + (wr * 64 + i * 16 + l15) * 32 + lg * 8);
#pragma unroll
    for (int i = 0; i < 2; ++i)
      bfr[i] = *(const bf16x8*)(&Blds[cur][0] + (wc * 32 + i * 16 + l15) * 32 + lg * 8);
#pragma unroll
    for (int mi = 0; mi < 4; ++mi)
#pragma unroll
      for (int ni = 0; ni < 2; ++ni)
        acc[mi][ni] = MFMA16(af[mi], bfr[ni], acc[mi][ni]);
    __syncthreads();
    cur ^= 1;
  }
#undef STAGE_W
#pragma unroll
  for (int mi = 0; mi < 4; ++mi) {
#pragma unroll
    for (int r = 0; r < 4; ++r) {
      int row = m0 + wr * 64 + mi * 16 + lg * 4 + r;
      size_t base = (size_t)row * N;
#pragma unroll
      for (int ni = 0; ni < 2; ++ni) {
        int col = n0 + wc * 32 + ni * 16 + l15;
        C[base + col] = acc[mi][ni][r] + Res[base + col];
      }
    }
  }
}

// ---------------- V transpose: V[B*S][H*64] -> Vt[bh][64][2048] ----------------
__global__ __launch_bounds__(256) void vtranspose(const short* __restrict__ V,
                                                  short* __restrict__ Vt) {
  __shared__ short T[64 * 72];
  int bh = blockIdx.y;
  int s0 = blockIdx.x * 64;
  int t = threadIdx.x;
  int r = t >> 2, cq = t & 3;
  const short* src = V + (size_t)((bh >> 4) * 2048 + s0 + r) * 1024 + (bh & 15) * 64 + cq * 16;
  *(int4*)(T + r * 72 + cq * 16) = *(const int4*)src;
  *(int4*)(T + r * 72 + cq * 16 + 8) = *(const int4*)(src + 8);
  __syncthreads();
  int d = t >> 2, sq = t & 3;
  short* dst = Vt + (size_t)bh * 131072 + (size_t)d * 2048 + s0 + sq * 16;
#pragma unroll
  for (int q = 0; q < 4; ++q) {
    short4v o;
#pragma unroll
    for (int j = 0; j < 4; ++j) o[j] = T[(sq * 16 + q * 4 + j) * 72 + d];
    *(short4v*)(dst + q * 4) = o;
  }
}

// ---------------- Flash attention v6 (round-10 proven): LDS-staged K/V, 2-phase
// dbuf, stage_rc XOR swizzle. p = exp(s/8 - 24), l via ones-MFMA.
__global__ __launch_bounds__(256) void attn6(const short* __restrict__ Q,
                                             const short* __restrict__ K,
                                             const short* __restrict__ Vt,
                                             short* __restrict__ O) {
  __shared__ __attribute__((aligned(16))) short Klds[2][64 * 64];
  __shared__ __attribute__((aligned(16))) short Vlds[2][64 * 64];
  __shared__ __attribute__((aligned(16))) short Ptlds[4][64 * 20];
  int bx = blockIdx.x;
  int bh = bx & 31;
  int qt = 31 - (bx >> 5);
  int tid = threadIdx.x;
  int w = tid >> 6, lane = tid & 63;
  int l15 = lane & 15, lg = lane >> 4;
  int qbase = qt * 64 + w * 16;
  size_t rowbase = (size_t)(bh >> 4) * 2048 * 1024 + (size_t)(bh & 15) * 64;
  const short* vtb = Vt + (size_t)bh * 131072;
  const short* Kb0 = K + rowbase;
  bf16x8 qf[2];
  {
    const short* qp = Q + rowbase + (size_t)(qbase + l15) * 1024 + lg * 8;
    qf[0] = *(const bf16x8*)qp;
    qf[1] = *(const bf16x8*)(qp + 32);
  }
  bf16x8 ones;
#pragma unroll
  for (int j = 0; j < 8; ++j) ones[j] = (short)0x3F80;
  f32x4 oacc[4] = {};
  f32x4 lacc = {};
  int nchunk = qt + 1;
  short* pt = Ptlds[w];
  int i0 = w * 64 + lane;
  int r0 = i0 >> 3, c0 = i0 & 7, cs0 = c0 ^ (r0 & 7);
  int i1 = 256 + i0;
  int r1 = i1 >> 3, c1 = i1 & 7, cs1 = c1 ^ (r1 & 7);
#define STAGE_KV(buf, kt)                                                      \
  {                                                                            \
    int ks = (kt) * 64;                                                        \
    gl_lds16(Kb0 + (size_t)(ks + r0) * 1024 + cs0 * 8, &Klds[buf][0] + i0 * 8);\
    gl_lds16(Kb0 + (size_t)(ks + r1) * 1024 + cs1 * 8, &Klds[buf][0] + i1 * 8);\
    gl_lds16(vtb + (size_t)r0 * 2048 + ks + cs0 * 8, &Vlds[buf][0] + i0 * 8);  \
    gl_lds16(vtb + (size_t)r1 * 2048 + ks + cs1 * 8, &Vlds[buf][0] + i1 * 8);  \
  }
  STAGE_KV(0, 0);
  __syncthreads();
  int cur = 0;
  for (int kt = 0; kt < nchunk; ++kt) {
    if (kt + 1 < nchunk) STAGE_KV(cur ^ 1, kt + 1);
    int kstart = kt * 64;
    f32x4 s[4] = {};
#pragma unroll
    for (int g = 0; g < 4; ++g) {
      int krow = g * 16 + l15;
      bf16x8 k0 = *(const bf16x8*)(&Klds[cur][0] + krow * 64 + ((lg ^ (l15 & 7)) * 8));
      bf16x8 k1 = *(const bf16x8*)(&Klds[cur][0] + krow * 64 + (((4 + lg) ^ (l15 & 7)) * 8));
      s[g] = MFMA16(qf[0], k0, s[g]);
      s[g] = MFMA16(qf[1], k1, s[g]);
    }
#pragma unroll
    for (int g = 0; g < 4; ++g) {
      short4v pk;
#pragma unroll
      for (int r = 0; r < 4; ++r) {
        int qg = qbase + lg * 4 + r;
        int kg = kstart + g * 16 + l15;
        float v = __expf(s[g][r] * 0.125f - 24.f);
        pk[r] = f2b((kg > qg) ? 0.f : v);
      }
      *(short4v*)(pt + (g * 16 + l15) * 20 + lg * 4) = pk;
    }
    bf16x8 pa0, pa1;
#pragma unroll
    for (int j = 0; j < 8; ++j) {
      pa0[j] = pt[(lg * 8 + j) * 20 + l15];
      pa1[j] = pt[(32 + lg * 8 + j) * 20 + l15];
    }
#pragma unroll
    for (int t = 0; t < 4; ++t) {
      int drow = t * 16 + l15;
      bf16x8 vf0 = *(const bf16x8*)(&Vlds[cur][0] + drow * 64 + ((lg ^ (l15 & 7)) * 8));
      bf16x8 vf1 = *(const bf16x8*)(&Vlds[cur][0] + drow * 64 + (((4 + lg) ^ (l15 & 7)) * 8));
      oacc[t] = MFMA16(pa0, vf0, oacc[t]);
      oacc[t] = MFMA16(pa1, vf1, oacc[t]);
    }
    lacc = MFMA16(pa0, ones, lacc);
    lacc = MFMA16(pa1, ones, lacc);
    __syncthreads();
    cur ^= 1;
  }
#undef STAGE_KV
#pragma unroll
  for (int t = 0; t < 4; ++t) {
#pragma unroll
    for (int r = 0; r < 4; ++r) {
      int row = qbase + lg * 4 + r;
      float denom = fmaxf(lacc[r], 1e-30f);
      O[rowbase + (size_t)row * 1024 + t * 16 + l15] = f2b(oacc[t][r] / denom);
    }
  }
}

extern "C" void kernel_launch(void* const* d_in, const int* in_sizes, int n_in,
                              void* d_out, int out_size, void* d_ws, size_t ws_size,
                              hipStream_t stream) {
  const float* xf = (const float*)d_in[0];
  const float* G1f = (const float*)d_in[8];
  const float* G2f = (const float*)d_in[9];
  char* ws = (char*)d_ws;
  const size_t MB = 1048576;
  short* Wslot = (short*)(ws);            // [0,8): WOb early, then W1/W3/W2
  short* WOb   = (short*)(ws);
  short* Wcat  = (short*)(ws + 8 * MB);   // [8,14): fused QKV weights
  short* Vt    = (short*)(ws + 8 * MB);   // [8,16): V^T (after Wcat dead)
  short* h     = (short*)(ws + 16 * MB);  // [16,24)
  short* Qb    = (short*)(ws + 24 * MB);  // [24,32)
  short* Kb    = (short*)(ws + 32 * MB);  // [32,40)
  short* Vb    = (short*)(ws + 40 * MB);  // [40,48)
  short* att   = (short*)(ws + 48 * MB);  // [48,56)
  short* w1x   = Qb;                      // [24,56): Q/K/V/att dead by FFN time
  float* x1f   = (float*)d_out;
  float* outf  = (float*)d_out;

  dim3 blk(256);
  convert_kernel<<<512, blk, 0, stream>>>((const float*)d_in[1], Wcat, 1048576);
  convert_kernel<<<512, blk, 0, stream>>>((const float*)d_in[2], Wcat + 1048576, 1048576);
  convert_kernel<<<512, blk, 0, stream>>>((const float*)d_in[3], Wcat + 2097152, 1048576);
  convert_kernel<<<512, blk, 0, stream>>>((const float*)d_in[4], WOb, 1048576);

  rmsnorm_f32<<<4096, blk, 0, stream>>>(xf, G1f, h);
  dim3 gqkv(24, 32);
  gemm_bt<3><<<gqkv, blk, 0, stream>>>(h, Wcat, nullptr, Qb, Kb, Vb, 4096, 1024, 1024);
  dim3 gvt(32, 32);
  vtranspose<<<gvt, blk, 0, stream>>>(Vb, Vt);
  attn6<<<1024, blk, 0, stream>>>(Qb, Kb, Vt, att);
  dim3 g1(8, 32);
  gemm_wide<<<g1, dim3(512), 0, stream>>>(att, WOb, xf, x1f, 4096, 1024, 1024);
  rmsnorm_f32<<<4096, blk, 0, stream>>>(x1f, G2f, h);
  convert_kernel<<<2048, blk, 0, stream>>>((const float*)d_in[5], Wslot, 4194304);
  gemm256<0><<<256, dim3(512), 0, stream>>>(h, Wslot, nullptr, w1x, 4096, 4096, 1024);
  convert_kernel<<<2048, blk, 0, stream>>>((const float*)d_in[7], Wslot, 4194304);
  gemm256<2><<<256, dim3(512), 0, stream>>>(h, Wslot, w1x, w1x, 4096, 4096, 1024);
  convert_kernel<<<2048, blk, 0, stream>>>((const float*)d_in[6], Wslot, 4194304);
  gemm_wide<<<g1, dim3(512), 0, stream>>>(w1x, Wslot, x1f, outf, 4096, 1024, 4096);
}

// Round 12
// 346.750 us; speedup vs baseline: 1.5150x; 1.0262x over previous
//
#include <hip/hip_runtime.h>
#include <stdint.h>

typedef __attribute__((ext_vector_type(8))) short bf16x8;
typedef __attribute__((ext_vector_type(4))) short short4v;
typedef __attribute__((ext_vector_type(4))) float f32x4;

#define MFMA16(a, b, c) __builtin_amdgcn_mfma_f32_16x16x32_bf16((a), (b), (c), 0, 0, 0)

__device__ __forceinline__ float b2f(short s) {
  unsigned u = ((unsigned)(unsigned short)s) << 16;
  return __builtin_bit_cast(float, u);
}
__device__ __forceinline__ short f2b(float f) {
  unsigned u = __builtin_bit_cast(unsigned, f);
  u = (u + 0x7fffu + ((u >> 16) & 1u)) >> 16;
  return (short)u;
}

// async global->LDS, 16B per lane; lds dest is wave-uniform base (HW adds lane*16)
__device__ __forceinline__ void gl_lds16(const short* g, short* l) {
  __builtin_amdgcn_global_load_lds((const __attribute__((address_space(1))) void*)g,
                                   (__attribute__((address_space(3))) void*)l, 16, 0, 0);
}

// -------- convert f32 -> bf16 (8 elems/thread) --------
__global__ __launch_bounds__(256) void convert_kernel(const float* __restrict__ src,
                                                      short* __restrict__ dst, int n) {
  int i = (blockIdx.x * 256 + threadIdx.x) * 8;
  if (i >= n) return;
  f32x4 a = *(const f32x4*)(src + i);
  f32x4 b = *(const f32x4*)(src + i + 4);
  short4v o0, o1;
#pragma unroll
  for (int j = 0; j < 4; ++j) { o0[j] = f2b(a[j]); o1[j] = f2b(b[j]); }
  *(short4v*)(dst + i) = o0;
  *(short4v*)(dst + i + 4) = o1;
}

// -------- RMSNorm: f32 in, f32 gamma, bf16 out; one block per row of 1024 --------
__global__ __launch_bounds__(256) void rmsnorm_f32(const float* __restrict__ X,
                                                   const float* __restrict__ G,
                                                   short* __restrict__ O) {
  int row = blockIdx.x;
  int t = threadIdx.x;
  f32x4 v = *(const f32x4*)(X + (size_t)row * 1024 + t * 4);
  float ss = 0.f;
#pragma unroll
  for (int j = 0; j < 4; ++j) ss += v[j] * v[j];
#pragma unroll
  for (int d = 1; d < 64; d <<= 1) ss += __shfl_xor(ss, d, 64);
  __shared__ float red[4];
  if ((t & 63) == 0) red[t >> 6] = ss;
  __syncthreads();
  float tot = red[0] + red[1] + red[2] + red[3];
  float rinv = rsqrtf(tot * (1.0f / 1024.0f) + 1e-5f);
  f32x4 g = *(const f32x4*)(G + t * 4);
  short4v o;
#pragma unroll
  for (int j = 0; j < 4; ++j) o[j] = f2b(v[j] * rinv * g[j]);
  *(short4v*)(O + (size_t)row * 1024 + t * 4) = o;
}

// ---------------- GEMM 2-phase: 256 thr, 4 waves 2x2, 128x128, BK=32, dbuf LDS
// MODE 0: C = AB | MODE 2: C = silu(Res)*AB | MODE 3: QKV-split + fused RoPE
template <int MODE>
__global__ __launch_bounds__(256) void gemm_bt(const short* __restrict__ A,
                                               const short* __restrict__ Bt,
                                               const void* Res, void* C,
                                               void* C1, void* C2,
                                               int M, int N, int K) {
  __shared__ __attribute__((aligned(16))) short Alds[2][128 * 32];
  __shared__ __attribute__((aligned(16))) short Blds[2][128 * 32];
  int tid = threadIdx.x;
  int lane = tid & 63, w = tid >> 6;
  int wr = w >> 1, wc = w & 1;
  int l15 = lane & 15, lg = lane >> 4;
  int m0 = blockIdx.y * 128, n0 = blockIdx.x * 128;
  void* Cw = C;
  int ncol0 = n0;
  int seg = 0;
  if (MODE == 3) {
    seg = n0 >> 10;
    Cw = (seg == 0) ? C : (seg == 1) ? C1 : C2;
    ncol0 = n0 & 1023;
  }
  f32x4 acc[4][4] = {};
  int arow = tid >> 2, acol = (tid & 3) * 8;
  const short* Ap = A + (size_t)(m0 + arow) * K + acol;
  const short* Bp = Bt + (size_t)(n0 + arow) * K + acol;
  int wb = w * 512;
#define STAGE_BT(buf, k0s)                                   \
  {                                                          \
    gl_lds16(Ap + (k0s), &Alds[buf][0] + wb);                \
    gl_lds16(Ap + (size_t)64 * K + (k0s), &Alds[buf][0] + 2048 + wb); \
    gl_lds16(Bp + (k0s), &Blds[buf][0] + wb);                \
    gl_lds16(Bp + (size_t)64 * K + (k0s), &Blds[buf][0] + 2048 + wb); \
  }
  STAGE_BT(0, 0);
  __syncthreads();
  int cur = 0;
  for (int k0 = 0; k0 < K; k0 += 32) {
    if (k0 + 32 < K) STAGE_BT(cur ^ 1, k0 + 32);
    bf16x8 af[4], bfr[4];
#pragma unroll
    for (int i = 0; i < 4; ++i) {
      af[i] = *(const bf16x8*)(&Alds[cur][0] + (wr * 64 + i * 16 + l15) * 32 + lg * 8);
      bfr[i] = *(const bf16x8*)(&Blds[cur][0] + (wc * 64 + i * 16 + l15) * 32 + lg * 8);
    }
#pragma unroll
    for (int mi = 0; mi < 4; ++mi)
#pragma unroll
      for (int ni = 0; ni < 4; ++ni)
        acc[mi][ni] = MFMA16(af[mi], bfr[ni], acc[mi][ni]);
    __syncthreads();
    cur ^= 1;
  }
#undef STAGE_BT
#pragma unroll
  for (int mi = 0; mi < 4; ++mi) {
#pragma unroll
    for (int r = 0; r < 4; ++r) {
      int row = m0 + wr * 64 + mi * 16 + lg * 4 + r;
      size_t base = (size_t)row * N;
#pragma unroll
      for (int ni = 0; ni < 4; ++ni) {
        int col = ncol0 + wc * 64 + ni * 16 + l15;
        float v = acc[mi][ni][r];
        if (MODE == 3 && seg <= 1) {
          int pos = row & 2047;
          int ii = (col & 62) >> 1;
          float invf2 = exp2f(-(float)ii * 0.4152410118f) * 0.15915494309f;
          float rev = (float)pos * invf2;
          rev -= rintf(rev);
          float angr = rev * 6.28318530718f;
          float sn = __sinf(angr), cs = __cosf(angr);
          float partner = __shfl_xor(v, 1, 64);
          float t = partner * sn;
          v = v * cs + (((l15 & 1) == 0) ? -t : t);
        }
        if (MODE == 2) {
          float rr = b2f(((const short*)Res)[base + col]);
          v = rr / (1.f + __expf(-rr)) * v;
          ((short*)Cw)[base + col] = f2b(v);
        } else {
          ((short*)Cw)[base + col] = f2b(v);
        }
      }
    }
  }
}

// ---------------- GEMM 256x256, 4-buf counted-vmcnt pipeline (T4): 512 thr,
// 8 waves 2x4, BK=32, 2-deep prefetch, s_waitcnt vmcnt(4) steady state.
// stage_rc swizzle + bijective XCD-chunked block swizzle. W1 (MODE 0) / W3 (MODE 2).
template <int MODE>
__global__ __launch_bounds__(512) void gemm256(const short* __restrict__ A,
                                               const short* __restrict__ Bt,
                                               const void* Res, void* C,
                                               int M, int N, int K) {
  __shared__ __attribute__((aligned(16))) short Alds[4][256 * 32];
  __shared__ __attribute__((aligned(16))) short Blds[4][256 * 32];
  int tid = threadIdx.x;
  int lane = tid & 63, w = tid >> 6;
  int wr = w >> 2, wc = w & 3;  // 2 x 4 waves
  int l15 = lane & 15, lg = lane >> 4;
  int wg = blockIdx.x;
  int swz = (wg & 7) * 32 + (wg >> 3);  // 256 % 8 == 0 -> bijective
  int by = swz >> 4, bx = swz & 15;
  int m0 = by * 256, n0 = bx * 256;
  f32x4 acc[8][4] = {};
  int o0 = tid, o1 = 512 + tid;
  int r0 = o0 >> 2, cs0 = (o0 & 3) ^ ((r0 >> 1) & 3);
  int r1 = o1 >> 2, cs1 = (o1 & 3) ^ ((r1 >> 1) & 3);
  const short* Ap0 = A + (size_t)(m0 + r0) * K + cs0 * 8;
  const short* Ap1 = A + (size_t)(m0 + r1) * K + cs1 * 8;
  const short* Bp0 = Bt + (size_t)(n0 + r0) * K + cs0 * 8;
  const short* Bp1 = Bt + (size_t)(n0 + r1) * K + cs1 * 8;
  int wb = w * 512;
#define STAGE_256(buf, k0s)                              \
  {                                                      \
    gl_lds16(Ap0 + (k0s), &Alds[buf][0] + wb);           \
    gl_lds16(Ap1 + (k0s), &Alds[buf][0] + 4096 + wb);    \
    gl_lds16(Bp0 + (k0s), &Blds[buf][0] + wb);           \
    gl_lds16(Bp1 + (k0s), &Blds[buf][0] + 4096 + wb);    \
  }
  int nk = K >> 5;
  STAGE_256(0, 0);
  STAGE_256(1, 32);
  asm volatile("s_waitcnt vmcnt(4)" ::: "memory");
  __builtin_amdgcn_s_barrier();
  asm volatile("" ::: "memory");
  for (int kt = 0; kt < nk; ++kt) {
    int buf = kt & 3;
    if (kt + 2 < nk) STAGE_256((kt + 2) & 3, (kt + 2) * 32);
    bf16x8 af[8], bfr[4];
#pragma unroll
    for (int i = 0; i < 8; ++i) {
      int ra = wr * 128 + i * 16 + l15;
      int ua = lg ^ ((ra >> 1) & 3);
      af[i] = *(const bf16x8*)(&Alds[buf][0] + ra * 32 + ua * 8);
    }
#pragma unroll
    for (int n = 0; n < 4; ++n) {
      int rb = wc * 64 + n * 16 + l15;
      int ub = lg ^ ((rb >> 1) & 3);
      bfr[n] = *(const bf16x8*)(&Blds[buf][0] + rb * 32 + ub * 8);
    }
#pragma unroll
    for (int i = 0; i < 8; ++i)
#pragma unroll
      for (int n = 0; n < 4; ++n)
        acc[i][n] = MFMA16(af[i], bfr[n], acc[i][n]);
    if (kt + 2 < nk) {
      asm volatile("s_waitcnt vmcnt(4)" ::: "memory");
    } else {
      asm volatile("s_waitcnt vmcnt(0)" ::: "memory");
    }
    __builtin_amdgcn_s_barrier();
    asm volatile("" ::: "memory");
  }
#undef STAGE_256
#pragma unroll
  for (int i = 0; i < 8; ++i) {
#pragma unroll
    for (int r = 0; r < 4; ++r) {
      int row = m0 + wr * 128 + i * 16 + lg * 4 + r;
      size_t base = (size_t)row * N;
#pragma unroll
      for (int n = 0; n < 4; ++n) {
        int col = n0 + wc * 64 + n * 16 + l15;
        float v = acc[i][n][r];
        if (MODE == 2) {
          float rr = b2f(((const short*)Res)[base + col]);
          v = rr / (1.f + __expf(-rr)) * v;
        }
        ((short*)C)[base + col] = f2b(v);
      }
    }
  }
}

// ---------------- GEMM wide, 4-buf counted-vmcnt pipeline (T4): 512 thr, 8 waves
// 2x4, 128x128, BK=64, stage_rc swizzle, 2-deep prefetch, C = AB + Resf (f32 out).
__global__ __launch_bounds__(512) void gemm_wide(const short* __restrict__ A,
                                                 const short* __restrict__ Bt,
                                                 const float* Res, float* C,
                                                 int M, int N, int K) {
  __shared__ __attribute__((aligned(16))) short Alds[4][128 * 64];
  __shared__ __attribute__((aligned(16))) short Blds[4][128 * 64];
  int tid = threadIdx.x;
  int lane = tid & 63, w = tid >> 6;
  int wr = w >> 2, wc = w & 3;
  int l15 = lane & 15, lg = lane >> 4;
  int m0 = blockIdx.y * 128, n0 = blockIdx.x * 128;
  f32x4 acc[4][2] = {};
  // staging: 16B units over [128 rows][8 units]; src unit = c ^ (row&7)
  int o0 = tid, o1 = 512 + tid;
  int r0 = o0 >> 3, cs0 = (o0 & 7) ^ (r0 & 7);
  int r1 = o1 >> 3, cs1 = (o1 & 7) ^ (r1 & 7);
  const short* Ap0 = A + (size_t)(m0 + r0) * K + cs0 * 8;
  const short* Ap1 = A + (size_t)(m0 + r1) * K + cs1 * 8;
  const short* Bp0 = Bt + (size_t)(n0 + r0) * K + cs0 * 8;
  const short* Bp1 = Bt + (size_t)(n0 + r1) * K + cs1 * 8;
  int wb = w * 512;
#define STG_W(buf, k0s)                                  \
  {                                                      \
    gl_lds16(Ap0 + (k0s), &Alds[buf][0] + wb);           \
    gl_lds16(Ap1 + (k0s), &Alds[buf][0] + 4096 + wb);    \
    gl_lds16(Bp0 + (k0s), &Blds[buf][0] + wb);           \
    gl_lds16(Bp1 + (k0s), &Blds[buf][0] + 4096 + wb);    \
  }
  int nk = K >> 6;
  STG_W(0, 0);
  STG_W(1, 64);
  asm volatile("s_waitcnt vmcnt(4)" ::: "memory");
  __builtin_amdgcn_s_barrier();
  asm volatile("" ::: "memory");
  for (int kt = 0; kt < nk; ++kt) {
    int buf = kt & 3;
    if (kt + 2 < nk) STG_W((kt + 2) & 3, (kt + 2) * 64);
    bf16x8 af[4][2], bfr[2][2];
#pragma unroll
    for (int i = 0; i < 4; ++i) {
      int ra = wr * 64 + i * 16 + l15;
#pragma unroll
      for (int kk = 0; kk < 2; ++kk) {
        int ua = (kk * 4 + lg) ^ (ra & 7);
        af[i][kk] = *(const bf16x8*)(&Alds[buf][0] + ra * 64 + ua * 8);
      }
    }
#pragma unroll
    for (int i = 0; i < 2; ++i) {
      int rb = wc * 32 + i * 16 + l15;
#pragma unroll
      for (int kk = 0; kk < 2; ++kk) {
        int ub = (kk * 4 + lg) ^ (rb & 7);
        bfr[i][kk] = *(const bf16x8*)(&Blds[buf][0] + rb * 64 + ub * 8);
      }
    }
#pragma unroll
    for (int kk = 0; kk < 2; ++kk)
#pragma unroll
      for (int mi = 0; mi < 4; ++mi)
#pragma unroll
        for (int ni = 0; ni < 2; ++ni)
          acc[mi][ni] = MFMA16(af[mi][kk], bfr[ni][kk], acc[mi][ni]);
    if (kt + 2 < nk) {
      asm volatile("s_waitcnt vmcnt(4)" ::: "memory");
    } else {
      asm volatile("s_waitcnt vmcnt(0)" ::: "memory");
    }
    __builtin_amdgcn_s_barrier();
    asm volatile("" ::: "memory");
  }
#undef STG_W
#pragma unroll
  for (int mi = 0; mi < 4; ++mi) {
#pragma unroll
    for (int r = 0; r < 4; ++r) {
      int row = m0 + wr * 64 + mi * 16 + lg * 4 + r;
      size_t base = (size_t)row * N;
#pragma unroll
      for (int ni = 0; ni < 2; ++ni) {
        int col = n0 + wc * 32 + ni * 16 + l15;
        C[base + col] = acc[mi][ni][r] + Res[base + col];
      }
    }
  }
}

// ---------------- V transpose: V[B*S][H*64] -> Vt[bh][64][2048] ----------------
__global__ __launch_bounds__(256) void vtranspose(const short* __restrict__ V,
                                                  short* __restrict__ Vt) {
  __shared__ short T[64 * 72];
  int bh = blockIdx.y;
  int s0 = blockIdx.x * 64;
  int t = threadIdx.x;
  int r = t >> 2, cq = t & 3;
  const short* src = V + (size_t)((bh >> 4) * 2048 + s0 + r) * 1024 + (bh & 15) * 64 + cq * 16;
  *(int4*)(T + r * 72 + cq * 16) = *(const int4*)src;
  *(int4*)(T + r * 72 + cq * 16 + 8) = *(const int4*)(src + 8);
  __syncthreads();
  int d = t >> 2, sq = t & 3;
  short* dst = Vt + (size_t)bh * 131072 + (size_t)d * 2048 + s0 + sq * 16;
#pragma unroll
  for (int q = 0; q < 4; ++q) {
    short4v o;
#pragma unroll
    for (int j = 0; j < 4; ++j) o[j] = T[(sq * 16 + q * 4 + j) * 72 + d];
    *(short4v*)(dst + q * 4) = o;
  }
}

// ---------------- Flash attention v6 (round-10 proven): LDS-staged K/V, 2-phase
// dbuf, stage_rc XOR swizzle. p = exp(s/8 - 24), l via ones-MFMA.
__global__ __launch_bounds__(256) void attn6(const short* __restrict__ Q,
                                             const short* __restrict__ K,
                                             const short* __restrict__ Vt,
                                             short* __restrict__ O) {
  __shared__ __attribute__((aligned(16))) short Klds[2][64 * 64];
  __shared__ __attribute__((aligned(16))) short Vlds[2][64 * 64];
  __shared__ __attribute__((aligned(16))) short Ptlds[4][64 * 20];
  int bx = blockIdx.x;
  int bh = bx & 31;
  int qt = 31 - (bx >> 5);
  int tid = threadIdx.x;
  int w = tid >> 6, lane = tid & 63;
  int l15 = lane & 15, lg = lane >> 4;
  int qbase = qt * 64 + w * 16;
  size_t rowbase = (size_t)(bh >> 4) * 2048 * 1024 + (size_t)(bh & 15) * 64;
  const short* vtb = Vt + (size_t)bh * 131072;
  const short* Kb0 = K + rowbase;
  bf16x8 qf[2];
  {
    const short* qp = Q + rowbase + (size_t)(qbase + l15) * 1024 + lg * 8;
    qf[0] = *(const bf16x8*)qp;
    qf[1] = *(const bf16x8*)(qp + 32);
  }
  bf16x8 ones;
#pragma unroll
  for (int j = 0; j < 8; ++j) ones[j] = (short)0x3F80;
  f32x4 oacc[4] = {};
  f32x4 lacc = {};
  int nchunk = qt + 1;
  short* pt = Ptlds[w];
  int i0 = w * 64 + lane;
  int r0 = i0 >> 3, c0 = i0 & 7, cs0 = c0 ^ (r0 & 7);
  int i1 = 256 + i0;
  int r1 = i1 >> 3, c1 = i1 & 7, cs1 = c1 ^ (r1 & 7);
#define STAGE_KV(buf, kt)                                                      \
  {                                                                            \
    int ks = (kt) * 64;                                                        \
    gl_lds16(Kb0 + (size_t)(ks + r0) * 1024 + cs0 * 8, &Klds[buf][0] + i0 * 8);\
    gl_lds16(Kb0 + (size_t)(ks + r1) * 1024 + cs1 * 8, &Klds[buf][0] + i1 * 8);\
    gl_lds16(vtb + (size_t)r0 * 2048 + ks + cs0 * 8, &Vlds[buf][0] + i0 * 8);  \
    gl_lds16(vtb + (size_t)r1 * 2048 + ks + cs1 * 8, &Vlds[buf][0] + i1 * 8);  \
  }
  STAGE_KV(0, 0);
  __syncthreads();
  int cur = 0;
  for (int kt = 0; kt < nchunk; ++kt) {
    if (kt + 1 < nchunk) STAGE_KV(cur ^ 1, kt + 1);
    int kstart = kt * 64;
    f32x4 s[4] = {};
#pragma unroll
    for (int g = 0; g < 4; ++g) {
      int krow = g * 16 + l15;
      bf16x8 k0 = *(const bf16x8*)(&Klds[cur][0] + krow * 64 + ((lg ^ (l15 & 7)) * 8));
      bf16x8 k1 = *(const bf16x8*)(&Klds[cur][0] + krow * 64 + (((4 + lg) ^ (l15 & 7)) * 8));
      s[g] = MFMA16(qf[0], k0, s[g]);
      s[g] = MFMA16(qf[1], k1, s[g]);
    }
#pragma unroll
    for (int g = 0; g < 4; ++g) {
      short4v pk;
#pragma unroll
      for (int r = 0; r < 4; ++r) {
        int qg = qbase + lg * 4 + r;
        int kg = kstart + g * 16 + l15;
        float v = __expf(s[g][r] * 0.125f - 24.f);
        pk[r] = f2b((kg > qg) ? 0.f : v);
      }
      *(short4v*)(pt + (g * 16 + l15) * 20 + lg * 4) = pk;
    }
    bf16x8 pa0, pa1;
#pragma unroll
    for (int j = 0; j < 8; ++j) {
      pa0[j] = pt[(lg * 8 + j) * 20 + l15];
      pa1[j] = pt[(32 + lg * 8 + j) * 20 + l15];
    }
#pragma unroll
    for (int t = 0; t < 4; ++t) {
      int drow = t * 16 + l15;
      bf16x8 vf0 = *(const bf16x8*)(&Vlds[cur][0] + drow * 64 + ((lg ^ (l15 & 7)) * 8));
      bf16x8 vf1 = *(const bf16x8*)(&Vlds[cur][0] + drow * 64 + (((4 + lg) ^ (l15 & 7)) * 8));
      oacc[t] = MFMA16(pa0, vf0, oacc[t]);
      oacc[t] = MFMA16(pa1, vf1, oacc[t]);
    }
    lacc = MFMA16(pa0, ones, lacc);
    lacc = MFMA16(pa1, ones, lacc);
    __syncthreads();
    cur ^= 1;
  }
#undef STAGE_KV
#pragma unroll
  for (int t = 0; t < 4; ++t) {
#pragma unroll
    for (int r = 0; r < 4; ++r) {
      int row = qbase + lg * 4 + r;
      float denom = fmaxf(lacc[r], 1e-30f);
      O[rowbase + (size_t)row * 1024 + t * 16 + l15] = f2b(oacc[t][r] / denom);
    }
  }
}

extern "C" void kernel_launch(void* const* d_in, const int* in_sizes, int n_in,
                              void* d_out, int out_size, void* d_ws, size_t ws_size,
                              hipStream_t stream) {
  const float* xf = (const float*)d_in[0];
  const float* G1f = (const float*)d_in[8];
  const float* G2f = (const float*)d_in[9];
  char* ws = (char*)d_ws;
  const size_t MB = 1048576;
  short* Wslot = (short*)(ws);            // [0,8): WOb early, then W1/W3/W2
  short* WOb   = (short*)(ws);
  short* Wcat  = (short*)(ws + 8 * MB);   // [8,14): fused QKV weights
  short* Vt    = (short*)(ws + 8 * MB);   // [8,16): V^T (after Wcat dead)
  short* h     = (short*)(ws + 16 * MB);  // [16,24)
  short* Qb    = (short*)(ws + 24 * MB);  // [24,32)
  short* Kb    = (short*)(ws + 32 * MB);  // [32,40)
  short* Vb    = (short*)(ws + 40 * MB);  // [40,48)
  short* att   = (short*)(ws + 48 * MB);  // [48,56)
  short* w1x   = Qb;                      // [24,56): Q/K/V/att dead by FFN time
  float* x1f   = (float*)d_out;
  float* outf  = (float*)d_out;

  dim3 blk(256);
  convert_kernel<<<512, blk, 0, stream>>>((const float*)d_in[1], Wcat, 1048576);
  convert_kernel<<<512, blk, 0, stream>>>((const float*)d_in[2], Wcat + 1048576, 1048576);
  convert_kernel<<<512, blk, 0, stream>>>((const float*)d_in[3], Wcat + 2097152, 1048576);
  convert_kernel<<<512, blk, 0, stream>>>((const float*)d_in[4], WOb, 1048576);

  rmsnorm_f32<<<4096, blk, 0, stream>>>(xf, G1f, h);
  dim3 gqkv(24, 32);
  gemm_bt<3><<<gqkv, blk, 0, stream>>>(h, Wcat, nullptr, Qb, Kb, Vb, 4096, 1024, 1024);
  dim3 gvt(32, 32);
  vtranspose<<<gvt, blk, 0, stream>>>(Vb, Vt);
  attn6<<<1024, blk, 0, stream>>>(Qb, Kb, Vt, att);
  dim3 g1(8, 32);
  gemm_wide<<<g1, dim3(512), 0, stream>>>(att, WOb, xf, x1f, 4096, 1024, 1024);
  rmsnorm_f32<<<4096, blk, 0, stream>>>(x1f, G2f, h);
  convert_kernel<<<2048, blk, 0, stream>>>((const float*)d_in[5], Wslot, 4194304);
  gemm256<0><<<256, dim3(512), 0, stream>>>(h, Wslot, nullptr, w1x, 4096, 4096, 1024);
  convert_kernel<<<2048, blk, 0, stream>>>((const float*)d_in[7], Wslot, 4194304);
  gemm256<2><<<256, dim3(512), 0, stream>>>(h, Wslot, w1x, w1x, 4096, 4096, 1024);
  convert_kernel<<<2048, blk, 0, stream>>>((const float*)d_in[6], Wslot, 4194304);
  gemm_wide<<<g1, dim3(512), 0, stream>>>(w1x, Wslot, x1f, outf, 4096, 1024, 4096);
}

// Round 13
// 331.653 us; speedup vs baseline: 1.5840x; 1.0455x over previous
//
#include <hip/hip_runtime.h>
#include <stdint.h>

typedef __attribute__((ext_vector_type(8))) short bf16x8;
typedef __attribute__((ext_vector_type(4))) short short4v;
typedef __attribute__((ext_vector_type(4))) float f32x4;

#define MFMA16(a, b, c) __builtin_amdgcn_mfma_f32_16x16x32_bf16((a), (b), (c), 0, 0, 0)

__device__ __forceinline__ float b2f(short s) {
  unsigned u = ((unsigned)(unsigned short)s) << 16;
  return __builtin_bit_cast(float, u);
}
__device__ __forceinline__ short f2b(float f) {
  unsigned u = __builtin_bit_cast(unsigned, f);
  u = (u + 0x7fffu + ((u >> 16) & 1u)) >> 16;
  return (short)u;
}

// async global->LDS, 16B per lane; lds dest is wave-uniform base (HW adds lane*16)
__device__ __forceinline__ void gl_lds16(const short* g, short* l) {
  __builtin_amdgcn_global_load_lds((const __attribute__((address_space(1))) void*)g,
                                   (__attribute__((address_space(3))) void*)l, 16, 0, 0);
}

// -------- convert f32 -> bf16 (8 elems/thread) --------
__global__ __launch_bounds__(256) void convert_kernel(const float* __restrict__ src,
                                                      short* __restrict__ dst, int n) {
  int i = (blockIdx.x * 256 + threadIdx.x) * 8;
  if (i >= n) return;
  f32x4 a = *(const f32x4*)(src + i);
  f32x4 b = *(const f32x4*)(src + i + 4);
  short4v o0, o1;
#pragma unroll
  for (int j = 0; j < 4; ++j) { o0[j] = f2b(a[j]); o1[j] = f2b(b[j]); }
  *(short4v*)(dst + i) = o0;
  *(short4v*)(dst + i + 4) = o1;
}

// -------- RMSNorm: f32 in, f32 gamma, bf16 out; one block per row of 1024 --------
__global__ __launch_bounds__(256) void rmsnorm_f32(const float* __restrict__ X,
                                                   const float* __restrict__ G,
                                                   short* __restrict__ O) {
  int row = blockIdx.x;
  int t = threadIdx.x;
  f32x4 v = *(const f32x4*)(X + (size_t)row * 1024 + t * 4);
  float ss = 0.f;
#pragma unroll
  for (int j = 0; j < 4; ++j) ss += v[j] * v[j];
#pragma unroll
  for (int d = 1; d < 64; d <<= 1) ss += __shfl_xor(ss, d, 64);
  __shared__ float red[4];
  if ((t & 63) == 0) red[t >> 6] = ss;
  __syncthreads();
  float tot = red[0] + red[1] + red[2] + red[3];
  float rinv = rsqrtf(tot * (1.0f / 1024.0f) + 1e-5f);
  f32x4 g = *(const f32x4*)(G + t * 4);
  short4v o;
#pragma unroll
  for (int j = 0; j < 4; ++j) o[j] = f2b(v[j] * rinv * g[j]);
  *(short4v*)(O + (size_t)row * 1024 + t * 4) = o;
}

// ---------------- GEMM 2-phase: 256 thr, 4 waves 2x2, 128x128, BK=32, dbuf LDS
// MODE 0: C = AB | MODE 2: C = silu(Res)*AB | MODE 3: QKV-split + fused RoPE
template <int MODE>
__global__ __launch_bounds__(256) void gemm_bt(const short* __restrict__ A,
                                               const short* __restrict__ Bt,
                                               const void* Res, void* C,
                                               void* C1, void* C2,
                                               int M, int N, int K) {
  __shared__ __attribute__((aligned(16))) short Alds[2][128 * 32];
  __shared__ __attribute__((aligned(16))) short Blds[2][128 * 32];
  int tid = threadIdx.x;
  int lane = tid & 63, w = tid >> 6;
  int wr = w >> 1, wc = w & 1;
  int l15 = lane & 15, lg = lane >> 4;
  int m0 = blockIdx.y * 128, n0 = blockIdx.x * 128;
  void* Cw = C;
  int ncol0 = n0;
  int seg = 0;
  if (MODE == 3) {
    seg = n0 >> 10;
    Cw = (seg == 0) ? C : (seg == 1) ? C1 : C2;
    ncol0 = n0 & 1023;
  }
  f32x4 acc[4][4] = {};
  int arow = tid >> 2, acol = (tid & 3) * 8;
  const short* Ap = A + (size_t)(m0 + arow) * K + acol;
  const short* Bp = Bt + (size_t)(n0 + arow) * K + acol;
  int wb = w * 512;
#define STAGE_BT(buf, k0s)                                   \
  {                                                          \
    gl_lds16(Ap + (k0s), &Alds[buf][0] + wb);                \
    gl_lds16(Ap + (size_t)64 * K + (k0s), &Alds[buf][0] + 2048 + wb); \
    gl_lds16(Bp + (k0s), &Blds[buf][0] + wb);                \
    gl_lds16(Bp + (size_t)64 * K + (k0s), &Blds[buf][0] + 2048 + wb); \
  }
  STAGE_BT(0, 0);
  __syncthreads();
  int cur = 0;
  for (int k0 = 0; k0 < K; k0 += 32) {
    if (k0 + 32 < K) STAGE_BT(cur ^ 1, k0 + 32);
    bf16x8 af[4], bfr[4];
#pragma unroll
    for (int i = 0; i < 4; ++i) {
      af[i] = *(const bf16x8*)(&Alds[cur][0] + (wr * 64 + i * 16 + l15) * 32 + lg * 8);
      bfr[i] = *(const bf16x8*)(&Blds[cur][0] + (wc * 64 + i * 16 + l15) * 32 + lg * 8);
    }
#pragma unroll
    for (int mi = 0; mi < 4; ++mi)
#pragma unroll
      for (int ni = 0; ni < 4; ++ni)
        acc[mi][ni] = MFMA16(af[mi], bfr[ni], acc[mi][ni]);
    __syncthreads();
    cur ^= 1;
  }
#undef STAGE_BT
#pragma unroll
  for (int mi = 0; mi < 4; ++mi) {
#pragma unroll
    for (int r = 0; r < 4; ++r) {
      int row = m0 + wr * 64 + mi * 16 + lg * 4 + r;
      size_t base = (size_t)row * N;
#pragma unroll
      for (int ni = 0; ni < 4; ++ni) {
        int col = ncol0 + wc * 64 + ni * 16 + l15;
        float v = acc[mi][ni][r];
        if (MODE == 3 && seg <= 1) {
          int pos = row & 2047;
          int ii = (col & 62) >> 1;
          float invf2 = exp2f(-(float)ii * 0.4152410118f) * 0.15915494309f;
          float rev = (float)pos * invf2;
          rev -= rintf(rev);
          float angr = rev * 6.28318530718f;
          float sn = __sinf(angr), cs = __cosf(angr);
          float partner = __shfl_xor(v, 1, 64);
          float t = partner * sn;
          v = v * cs + (((l15 & 1) == 0) ? -t : t);
        }
        if (MODE == 2) {
          float rr = b2f(((const short*)Res)[base + col]);
          v = rr / (1.f + __expf(-rr)) * v;
          ((short*)Cw)[base + col] = f2b(v);
        } else {
          ((short*)Cw)[base + col] = f2b(v);
        }
      }
    }
  }
}

// ---------------- GEMM 256x256, BK=64, minimum-2-phase (proven recipe): 512 thr,
// 8 waves 2x4, 2 LDS buffers (128KB), stage(t+1)-then-compute, one syncthreads/iter.
// stage_rc swizzle: src unit c^(r&7); read unit (kk*4+lg)^(row&7). XCD-chunked grid.
// W1 (MODE 0) / W3 (MODE 2), M=N=4096, K=1024.
template <int MODE>
__global__ __launch_bounds__(512) void gemm256(const short* __restrict__ A,
                                               const short* __restrict__ Bt,
                                               const void* Res, void* C,
                                               int M, int N, int K) {
  __shared__ __attribute__((aligned(16))) short Alds[2][256 * 64];
  __shared__ __attribute__((aligned(16))) short Blds[2][256 * 64];
  int tid = threadIdx.x;
  int lane = tid & 63, w = tid >> 6;
  int wr = w >> 2, wc = w & 3;  // 2 x 4 waves
  int l15 = lane & 15, lg = lane >> 4;
  int wg = blockIdx.x;
  int swz = (wg & 7) * 32 + (wg >> 3);  // 256 % 8 == 0 -> bijective
  int by = swz >> 4, bx = swz & 15;
  int m0 = by * 256, n0 = bx * 256;
  f32x4 acc[8][4] = {};
  // staging: 16B units over [256 rows][8 units]; instr j covers rows j*64..+63.
  // o = j*512 + tid; r = j*64 + (tid>>3); c = tid&7; src unit cs = c ^ (r&7)
  // (j*64 % 8 == 0 so cs is j-independent).
  int rr = tid >> 3;
  int cs = (tid & 7) ^ (rr & 7);
  const short* Apt = A + (size_t)(m0 + rr) * K + cs * 8;
  const short* Bpt = Bt + (size_t)(n0 + rr) * K + cs * 8;
#define STAGE_256(buf, kt)                                                     \
  {                                                                            \
    int ko = (kt) * 64;                                                        \
    _Pragma("unroll")                                                          \
    for (int j = 0; j < 4; ++j) {                                              \
      gl_lds16(Apt + (size_t)(j * 64) * K + ko, &Alds[buf][0] + j * 4096 + w * 512); \
      gl_lds16(Bpt + (size_t)(j * 64) * K + ko, &Blds[buf][0] + j * 4096 + w * 512); \
    }                                                                          \
  }
  int nt = K >> 6;  // 16
  STAGE_256(0, 0);
  __syncthreads();
  int cur = 0;
  for (int kt = 0; kt < nt; ++kt) {
    if (kt + 1 < nt) STAGE_256(cur ^ 1, kt + 1);
#pragma unroll
    for (int kk = 0; kk < 2; ++kk) {
      bf16x8 af[8], bfr[4];
#pragma unroll
      for (int i = 0; i < 8; ++i) {
        int ra = wr * 128 + i * 16 + l15;
        int ua = (kk * 4 + lg) ^ (ra & 7);
        af[i] = *(const bf16x8*)(&Alds[cur][0] + ra * 64 + ua * 8);
      }
#pragma unroll
      for (int n = 0; n < 4; ++n) {
        int rb = wc * 64 + n * 16 + l15;
        int ub = (kk * 4 + lg) ^ (rb & 7);
        bfr[n] = *(const bf16x8*)(&Blds[cur][0] + rb * 64 + ub * 8);
      }
#pragma unroll
      for (int i = 0; i < 8; ++i)
#pragma unroll
        for (int n = 0; n < 4; ++n)
          acc[i][n] = MFMA16(af[i], bfr[n], acc[i][n]);
    }
    __syncthreads();
    cur ^= 1;
  }
#undef STAGE_256
#pragma unroll
  for (int i = 0; i < 8; ++i) {
#pragma unroll
    for (int r = 0; r < 4; ++r) {
      int row = m0 + wr * 128 + i * 16 + lg * 4 + r;
      size_t base = (size_t)row * N;
#pragma unroll
      for (int n = 0; n < 4; ++n) {
        int col = n0 + wc * 64 + n * 16 + l15;
        float v = acc[i][n][r];
        if (MODE == 2) {
          float rr2 = b2f(((const short*)Res)[base + col]);
          v = rr2 / (1.f + __expf(-rr2)) * v;
        }
        ((short*)C)[base + col] = f2b(v);
      }
    }
  }
}

// ---------------- GEMM wide, 4-buf counted-vmcnt pipeline: 512 thr, 8 waves
// 2x4, 128x128, BK=64, stage_rc swizzle, 2-deep prefetch, C = AB + Resf (f32 out).
__global__ __launch_bounds__(512) void gemm_wide(const short* __restrict__ A,
                                                 const short* __restrict__ Bt,
                                                 const float* Res, float* C,
                                                 int M, int N, int K) {
  __shared__ __attribute__((aligned(16))) short Alds[4][128 * 64];
  __shared__ __attribute__((aligned(16))) short Blds[4][128 * 64];
  int tid = threadIdx.x;
  int lane = tid & 63, w = tid >> 6;
  int wr = w >> 2, wc = w & 3;
  int l15 = lane & 15, lg = lane >> 4;
  int m0 = blockIdx.y * 128, n0 = blockIdx.x * 128;
  f32x4 acc[4][2] = {};
  int o0 = tid, o1 = 512 + tid;
  int r0 = o0 >> 3, cs0 = (o0 & 7) ^ (r0 & 7);
  int r1 = o1 >> 3, cs1 = (o1 & 7) ^ (r1 & 7);
  const short* Ap0 = A + (size_t)(m0 + r0) * K + cs0 * 8;
  const short* Ap1 = A + (size_t)(m0 + r1) * K + cs1 * 8;
  const short* Bp0 = Bt + (size_t)(n0 + r0) * K + cs0 * 8;
  const short* Bp1 = Bt + (size_t)(n0 + r1) * K + cs1 * 8;
  int wb = w * 512;
#define STG_W(buf, k0s)                                  \
  {                                                      \
    gl_lds16(Ap0 + (k0s), &Alds[buf][0] + wb);           \
    gl_lds16(Ap1 + (k0s), &Alds[buf][0] + 4096 + wb);    \
    gl_lds16(Bp0 + (k0s), &Blds[buf][0] + wb);           \
    gl_lds16(Bp1 + (k0s), &Blds[buf][0] + 4096 + wb);    \
  }
  int nk = K >> 6;
  STG_W(0, 0);
  STG_W(1, 64);
  asm volatile("s_waitcnt vmcnt(4)" ::: "memory");
  __builtin_amdgcn_s_barrier();
  asm volatile("" ::: "memory");
  for (int kt = 0; kt < nk; ++kt) {
    int buf = kt & 3;
    if (kt + 2 < nk) STG_W((kt + 2) & 3, (kt + 2) * 64);
    bf16x8 af[4][2], bfr[2][2];
#pragma unroll
    for (int i = 0; i < 4; ++i) {
      int ra = wr * 64 + i * 16 + l15;
#pragma unroll
      for (int kk = 0; kk < 2; ++kk) {
        int ua = (kk * 4 + lg) ^ (ra & 7);
        af[i][kk] = *(const bf16x8*)(&Alds[buf][0] + ra * 64 + ua * 8);
      }
    }
#pragma unroll
    for (int i = 0; i < 2; ++i) {
      int rb = wc * 32 + i * 16 + l15;
#pragma unroll
      for (int kk = 0; kk < 2; ++kk) {
        int ub = (kk * 4 + lg) ^ (rb & 7);
        bfr[i][kk] = *(const bf16x8*)(&Blds[buf][0] + rb * 64 + ub * 8);
      }
    }
#pragma unroll
    for (int kk = 0; kk < 2; ++kk)
#pragma unroll
      for (int mi = 0; mi < 4; ++mi)
#pragma unroll
        for (int ni = 0; ni < 2; ++ni)
          acc[mi][ni] = MFMA16(af[mi][kk], bfr[ni][kk], acc[mi][ni]);
    if (kt + 2 < nk) {
      asm volatile("s_waitcnt vmcnt(4)" ::: "memory");
    } else {
      asm volatile("s_waitcnt vmcnt(0)" ::: "memory");
    }
    __builtin_amdgcn_s_barrier();
    asm volatile("" ::: "memory");
  }
#undef STG_W
#pragma unroll
  for (int mi = 0; mi < 4; ++mi) {
#pragma unroll
    for (int r = 0; r < 4; ++r) {
      int row = m0 + wr * 64 + mi * 16 + lg * 4 + r;
      size_t base = (size_t)row * N;
#pragma unroll
      for (int ni = 0; ni < 2; ++ni) {
        int col = n0 + wc * 32 + ni * 16 + l15;
        C[base + col] = acc[mi][ni][r] + Res[base + col];
      }
    }
  }
}

// ---------------- V transpose: V[B*S][H*64] -> Vt[bh][64][2048] ----------------
__global__ __launch_bounds__(256) void vtranspose(const short* __restrict__ V,
                                                  short* __restrict__ Vt) {
  __shared__ short T[64 * 72];
  int bh = blockIdx.y;
  int s0 = blockIdx.x * 64;
  int t = threadIdx.x;
  int r = t >> 2, cq = t & 3;
  const short* src = V + (size_t)((bh >> 4) * 2048 + s0 + r) * 1024 + (bh & 15) * 64 + cq * 16;
  *(int4*)(T + r * 72 + cq * 16) = *(const int4*)src;
  *(int4*)(T + r * 72 + cq * 16 + 8) = *(const int4*)(src + 8);
  __syncthreads();
  int d = t >> 2, sq = t & 3;
  short* dst = Vt + (size_t)bh * 131072 + (size_t)d * 2048 + s0 + sq * 16;
#pragma unroll
  for (int q = 0; q < 4; ++q) {
    short4v o;
#pragma unroll
    for (int j = 0; j < 4; ++j) o[j] = T[(sq * 16 + q * 4 + j) * 72 + d];
    *(short4v*)(dst + q * 4) = o;
  }
}

// ---------------- Flash attention v6 (round-10 proven): LDS-staged K/V, 2-phase
// dbuf, stage_rc XOR swizzle. p = exp(s/8 - 24), l via ones-MFMA.
__global__ __launch_bounds__(256) void attn6(const short* __restrict__ Q,
                                             const short* __restrict__ K,
                                             const short* __restrict__ Vt,
                                             short* __restrict__ O) {
  __shared__ __attribute__((aligned(16))) short Klds[2][64 * 64];
  __shared__ __attribute__((aligned(16))) short Vlds[2][64 * 64];
  __shared__ __attribute__((aligned(16))) short Ptlds[4][64 * 20];
  int bx = blockIdx.x;
  int bh = bx & 31;
  int qt = 31 - (bx >> 5);
  int tid = threadIdx.x;
  int w = tid >> 6, lane = tid & 63;
  int l15 = lane & 15, lg = lane >> 4;
  int qbase = qt * 64 + w * 16;
  size_t rowbase = (size_t)(bh >> 4) * 2048 * 1024 + (size_t)(bh & 15) * 64;
  const short* vtb = Vt + (size_t)bh * 131072;
  const short* Kb0 = K + rowbase;
  bf16x8 qf[2];
  {
    const short* qp = Q + rowbase + (size_t)(qbase + l15) * 1024 + lg * 8;
    qf[0] = *(const bf16x8*)qp;
    qf[1] = *(const bf16x8*)(qp + 32);
  }
  bf16x8 ones;
#pragma unroll
  for (int j = 0; j < 8; ++j) ones[j] = (short)0x3F80;
  f32x4 oacc[4] = {};
  f32x4 lacc = {};
  int nchunk = qt + 1;
  short* pt = Ptlds[w];
  int i0 = w * 64 + lane;
  int r0 = i0 >> 3, c0 = i0 & 7, cs0 = c0 ^ (r0 & 7);
  int i1 = 256 + i0;
  int r1 = i1 >> 3, c1 = i1 & 7, cs1 = c1 ^ (r1 & 7);
#define STAGE_KV(buf, kt)                                                      \
  {                                                                            \
    int ks = (kt) * 64;                                                        \
    gl_lds16(Kb0 + (size_t)(ks + r0) * 1024 + cs0 * 8, &Klds[buf][0] + i0 * 8);\
    gl_lds16(Kb0 + (size_t)(ks + r1) * 1024 + cs1 * 8, &Klds[buf][0] + i1 * 8);\
    gl_lds16(vtb + (size_t)r0 * 2048 + ks + cs0 * 8, &Vlds[buf][0] + i0 * 8);  \
    gl_lds16(vtb + (size_t)r1 * 2048 + ks + cs1 * 8, &Vlds[buf][0] + i1 * 8);  \
  }
  STAGE_KV(0, 0);
  __syncthreads();
  int cur = 0;
  for (int kt = 0; kt < nchunk; ++kt) {
    if (kt + 1 < nchunk) STAGE_KV(cur ^ 1, kt + 1);
    int kstart = kt * 64;
    f32x4 s[4] = {};
#pragma unroll
    for (int g = 0; g < 4; ++g) {
      int krow = g * 16 + l15;
      bf16x8 k0 = *(const bf16x8*)(&Klds[cur][0] + krow * 64 + ((lg ^ (l15 & 7)) * 8));
      bf16x8 k1 = *(const bf16x8*)(&Klds[cur][0] + krow * 64 + (((4 + lg) ^ (l15 & 7)) * 8));
      s[g] = MFMA16(qf[0], k0, s[g]);
      s[g] = MFMA16(qf[1], k1, s[g]);
    }
#pragma unroll
    for (int g = 0; g < 4; ++g) {
      short4v pk;
#pragma unroll
      for (int r = 0; r < 4; ++r) {
        int qg = qbase + lg * 4 + r;
        int kg = kstart + g * 16 + l15;
        float v = __expf(s[g][r] * 0.125f - 24.f);
        pk[r] = f2b((kg > qg) ? 0.f : v);
      }
      *(short4v*)(pt + (g * 16 + l15) * 20 + lg * 4) = pk;
    }
    bf16x8 pa0, pa1;
#pragma unroll
    for (int j = 0; j < 8; ++j) {
      pa0[j] = pt[(lg * 8 + j) * 20 + l15];
      pa1[j] = pt[(32 + lg * 8 + j) * 20 + l15];
    }
#pragma unroll
    for (int t = 0; t < 4; ++t) {
      int drow = t * 16 + l15;
      bf16x8 vf0 = *(const bf16x8*)(&Vlds[cur][0] + drow * 64 + ((lg ^ (l15 & 7)) * 8));
      bf16x8 vf1 = *(const bf16x8*)(&Vlds[cur][0] + drow * 64 + (((4 + lg) ^ (l15 & 7)) * 8));
      oacc[t] = MFMA16(pa0, vf0, oacc[t]);
      oacc[t] = MFMA16(pa1, vf1, oacc[t]);
    }
    lacc = MFMA16(pa0, ones, lacc);
    lacc = MFMA16(pa1, ones, lacc);
    __syncthreads();
    cur ^= 1;
  }
#undef STAGE_KV
#pragma unroll
  for (int t = 0; t < 4; ++t) {
#pragma unroll
    for (int r = 0; r < 4; ++r) {
      int row = qbase + lg * 4 + r;
      float denom = fmaxf(lacc[r], 1e-30f);
      O[rowbase + (size_t)row * 1024 + t * 16 + l15] = f2b(oacc[t][r] / denom);
    }
  }
}

extern "C" void kernel_launch(void* const* d_in, const int* in_sizes, int n_in,
                              void* d_out, int out_size, void* d_ws, size_t ws_size,
                              hipStream_t stream) {
  const float* xf = (const float*)d_in[0];
  const float* G1f = (const float*)d_in[8];
  const float* G2f = (const float*)d_in[9];
  char* ws = (char*)d_ws;
  const size_t MB = 1048576;
  short* Wslot = (short*)(ws);            // [0,8): WOb early, then W1/W3/W2
  short* WOb   = (short*)(ws);
  short* Wcat  = (short*)(ws + 8 * MB);   // [8,14): fused QKV weights
  short* Vt    = (short*)(ws + 8 * MB);   // [8,16): V^T (after Wcat dead)
  short* h     = (short*)(ws + 16 * MB);  // [16,24)
  short* Qb    = (short*)(ws + 24 * MB);  // [24,32)
  short* Kb    = (short*)(ws + 32 * MB);  // [32,40)
  short* Vb    = (short*)(ws + 40 * MB);  // [40,48)
  short* att   = (short*)(ws + 48 * MB);  // [48,56)
  short* w1x   = Qb;                      // [24,56): Q/K/V/att dead by FFN time
  float* x1f   = (float*)d_out;
  float* outf  = (float*)d_out;

  dim3 blk(256);
  convert_kernel<<<512, blk, 0, stream>>>((const float*)d_in[1], Wcat, 1048576);
  convert_kernel<<<512, blk, 0, stream>>>((const float*)d_in[2], Wcat + 1048576, 1048576);
  convert_kernel<<<512, blk, 0, stream>>>((const float*)d_in[3], Wcat + 2097152, 1048576);
  convert_kernel<<<512, blk, 0, stream>>>((const float*)d_in[4], WOb, 1048576);

  rmsnorm_f32<<<4096, blk, 0, stream>>>(xf, G1f, h);
  dim3 gqkv(24, 32);
  gemm_bt<3><<<gqkv, blk, 0, stream>>>(h, Wcat, nullptr, Qb, Kb, Vb, 4096, 1024, 1024);
  dim3 gvt(32, 32);
  vtranspose<<<gvt, blk, 0, stream>>>(Vb, Vt);
  attn6<<<1024, blk, 0, stream>>>(Qb, Kb, Vt, att);
  dim3 g1(8, 32);
  gemm_wide<<<g1, dim3(512), 0, stream>>>(att, WOb, xf, x1f, 4096, 1024, 1024);
  rmsnorm_f32<<<4096, blk, 0, stream>>>(x1f, G2f, h);
  convert_kernel<<<2048, blk, 0, stream>>>((const float*)d_in[5], Wslot, 4194304);
  gemm256<0><<<256, dim3(512), 0, stream>>>(h, Wslot, nullptr, w1x, 4096, 4096, 1024);
  convert_kernel<<<2048, blk, 0, stream>>>((const float*)d_in[7], Wslot, 4194304);
  gemm256<2><<<256, dim3(512), 0, stream>>>(h, Wslot, w1x, w1x, 4096, 4096, 1024);
  convert_kernel<<<2048, blk, 0, stream>>>((const float*)d_in[6], Wslot, 4194304);
  gemm_wide<<<g1, dim3(512), 0, stream>>>(w1x, Wslot, x1f, outf, 4096, 1024, 4096);
}

// Round 14
// 331.314 us; speedup vs baseline: 1.5856x; 1.0010x over previous
//
#include <hip/hip_runtime.h>
#include <stdint.h>

typedef __attribute__((ext_vector_type(8))) short bf16x8;
typedef __attribute__((ext_vector_type(4))) short short4v;
typedef __attribute__((ext_vector_type(4))) float f32x4;

#define MFMA16(a, b, c) __builtin_amdgcn_mfma_f32_16x16x32_bf16((a), (b), (c), 0, 0, 0)

__device__ __forceinline__ float b2f(short s) {
  unsigned u = ((unsigned)(unsigned short)s) << 16;
  return __builtin_bit_cast(float, u);
}
__device__ __forceinline__ short f2b(float f) {
  unsigned u = __builtin_bit_cast(unsigned, f);
  u = (u + 0x7fffu + ((u >> 16) & 1u)) >> 16;
  return (short)u;
}

// async global->LDS, 16B per lane; lds dest is wave-uniform base (HW adds lane*16)
__device__ __forceinline__ void gl_lds16(const short* g, short* l) {
  __builtin_amdgcn_global_load_lds((const __attribute__((address_space(1))) void*)g,
                                   (__attribute__((address_space(3))) void*)l, 16, 0, 0);
}

// -------- convert f32 -> bf16 (8 elems/thread) --------
__global__ __launch_bounds__(256) void convert_kernel(const float* __restrict__ src,
                                                      short* __restrict__ dst, int n) {
  int i = (blockIdx.x * 256 + threadIdx.x) * 8;
  if (i >= n) return;
  f32x4 a = *(const f32x4*)(src + i);
  f32x4 b = *(const f32x4*)(src + i + 4);
  short4v o0, o1;
#pragma unroll
  for (int j = 0; j < 4; ++j) { o0[j] = f2b(a[j]); o1[j] = f2b(b[j]); }
  *(short4v*)(dst + i) = o0;
  *(short4v*)(dst + i + 4) = o1;
}

// -------- RMSNorm: f32 in, f32 gamma, bf16 out; one block per row of 1024 --------
__global__ __launch_bounds__(256) void rmsnorm_f32(const float* __restrict__ X,
                                                   const float* __restrict__ G,
                                                   short* __restrict__ O) {
  int row = blockIdx.x;
  int t = threadIdx.x;
  f32x4 v = *(const f32x4*)(X + (size_t)row * 1024 + t * 4);
  float ss = 0.f;
#pragma unroll
  for (int j = 0; j < 4; ++j) ss += v[j] * v[j];
#pragma unroll
  for (int d = 1; d < 64; d <<= 1) ss += __shfl_xor(ss, d, 64);
  __shared__ float red[4];
  if ((t & 63) == 0) red[t >> 6] = ss;
  __syncthreads();
  float tot = red[0] + red[1] + red[2] + red[3];
  float rinv = rsqrtf(tot * (1.0f / 1024.0f) + 1e-5f);
  f32x4 g = *(const f32x4*)(G + t * 4);
  short4v o;
#pragma unroll
  for (int j = 0; j < 4; ++j) o[j] = f2b(v[j] * rinv * g[j]);
  *(short4v*)(O + (size_t)row * 1024 + t * 4) = o;
}

// ---------------- GEMM 2-phase: 256 thr, 4 waves 2x2, 128x128, BK=32, dbuf LDS
// MODE 0: C = AB | MODE 2: C = silu(Res)*AB | MODE 3: QKV-split + fused RoPE
template <int MODE>
__global__ __launch_bounds__(256) void gemm_bt(const short* __restrict__ A,
                                               const short* __restrict__ Bt,
                                               const void* Res, void* C,
                                               void* C1, void* C2,
                                               int M, int N, int K) {
  __shared__ __attribute__((aligned(16))) short Alds[2][128 * 32];
  __shared__ __attribute__((aligned(16))) short Blds[2][128 * 32];
  int tid = threadIdx.x;
  int lane = tid & 63, w = tid >> 6;
  int wr = w >> 1, wc = w & 1;
  int l15 = lane & 15, lg = lane >> 4;
  int m0 = blockIdx.y * 128, n0 = blockIdx.x * 128;
  void* Cw = C;
  int ncol0 = n0;
  int seg = 0;
  if (MODE == 3) {
    seg = n0 >> 10;
    Cw = (seg == 0) ? C : (seg == 1) ? C1 : C2;
    ncol0 = n0 & 1023;
  }
  f32x4 acc[4][4] = {};
  int arow = tid >> 2, acol = (tid & 3) * 8;
  const short* Ap = A + (size_t)(m0 + arow) * K + acol;
  const short* Bp = Bt + (size_t)(n0 + arow) * K + acol;
  int wb = w * 512;
#define STAGE_BT(buf, k0s)                                   \
  {                                                          \
    gl_lds16(Ap + (k0s), &Alds[buf][0] + wb);                \
    gl_lds16(Ap + (size_t)64 * K + (k0s), &Alds[buf][0] + 2048 + wb); \
    gl_lds16(Bp + (k0s), &Blds[buf][0] + wb);                \
    gl_lds16(Bp + (size_t)64 * K + (k0s), &Blds[buf][0] + 2048 + wb); \
  }
  STAGE_BT(0, 0);
  __syncthreads();
  int cur = 0;
  for (int k0 = 0; k0 < K; k0 += 32) {
    if (k0 + 32 < K) STAGE_BT(cur ^ 1, k0 + 32);
    bf16x8 af[4], bfr[4];
#pragma unroll
    for (int i = 0; i < 4; ++i) {
      af[i] = *(const bf16x8*)(&Alds[cur][0] + (wr * 64 + i * 16 + l15) * 32 + lg * 8);
      bfr[i] = *(const bf16x8*)(&Blds[cur][0] + (wc * 64 + i * 16 + l15) * 32 + lg * 8);
    }
#pragma unroll
    for (int mi = 0; mi < 4; ++mi)
#pragma unroll
      for (int ni = 0; ni < 4; ++ni)
        acc[mi][ni] = MFMA16(af[mi], bfr[ni], acc[mi][ni]);
    __syncthreads();
    cur ^= 1;
  }
#undef STAGE_BT
#pragma unroll
  for (int mi = 0; mi < 4; ++mi) {
#pragma unroll
    for (int r = 0; r < 4; ++r) {
      int row = m0 + wr * 64 + mi * 16 + lg * 4 + r;
      size_t base = (size_t)row * N;
#pragma unroll
      for (int ni = 0; ni < 4; ++ni) {
        int col = ncol0 + wc * 64 + ni * 16 + l15;
        float v = acc[mi][ni][r];
        if (MODE == 3 && seg <= 1) {
          int pos = row & 2047;
          int ii = (col & 62) >> 1;
          float invf2 = exp2f(-(float)ii * 0.4152410118f) * 0.15915494309f;
          float rev = (float)pos * invf2;
          rev -= rintf(rev);
          float angr = rev * 6.28318530718f;
          float sn = __sinf(angr), cs = __cosf(angr);
          float partner = __shfl_xor(v, 1, 64);
          float t = partner * sn;
          v = v * cs + (((l15 & 1) == 0) ? -t : t);
        }
        if (MODE == 2) {
          float rr = b2f(((const short*)Res)[base + col]);
          v = rr / (1.f + __expf(-rr)) * v;
          ((short*)Cw)[base + col] = f2b(v);
        } else {
          ((short*)Cw)[base + col] = f2b(v);
        }
      }
    }
  }
}

// ---------------- GEMM 256x256 8-PHASE (T3+T4+T2+T5): 512 thr, 8 waves 2x4, BK=64.
// LDS: 2 slots/matrix x [2 half][128 rows][64 k] = 128 KB. Per K-tile: 4 quadrant
// phases {ds_reads | stage 1 half-tile | s_barrier | lgkmcnt(0)+sched_barrier |
// setprio(1) 16 MFMA setprio(0) | s_barrier}; one vmcnt(0) per K-tile group.
// stage_rc swizzle (src unit c^(r&7); read unit (kk*4+lg)^(l15&7)). XCD-chunked grid.
template <int MODE>
__global__ __launch_bounds__(512) void gemm256(const short* __restrict__ A,
                                               const short* __restrict__ Bt,
                                               const void* Res, void* C,
                                               int M, int N, int K) {
  __shared__ __attribute__((aligned(16))) short Al[2][2][128 * 64];
  __shared__ __attribute__((aligned(16))) short Bl[2][2][128 * 64];
  int tid = threadIdx.x;
  int lane = tid & 63, w = tid >> 6;
  int wr = w >> 2, wc = w & 3;  // 2 x 4 waves
  int l15 = lane & 15, lg = lane >> 4;
  int wg = blockIdx.x;
  int swz = (wg & 7) * 32 + (wg >> 3);  // 256 % 8 == 0 -> bijective
  int by = swz >> 4, bx = swz & 15;
  int m0 = by * 256, n0 = bx * 256;
  f32x4 acc[8][4] = {};
  // staging: per half-tile 1024 16B-units; thread covers units tid and 512+tid
  int r0 = tid >> 3, c0 = tid & 7;
  int cs0 = c0 ^ (r0 & 7);
  int r1 = 64 + r0;
  int cs1 = c0 ^ (r1 & 7);
  int wso = w * 512;  // wave-uniform LDS short-offset for load j=0 (j=1: +4096)

#define STG_HALF(dsth, srcp, x0, hh, ktile)                                        \
  {                                                                                \
    gl_lds16((srcp) + (size_t)((x0) + (hh) * 128 + r0) * K + (ktile) * 64 + cs0 * 8, \
             (dsth) + wso);                                                        \
    gl_lds16((srcp) + (size_t)((x0) + (hh) * 128 + r1) * K + (ktile) * 64 + cs1 * 8, \
             (dsth) + 4096 + wso);                                                 \
  }
#define DSR_A(qb)                                                                  \
  _Pragma("unroll") for (int i = 0; i < 4; ++i) {                                  \
    int rl = ((qb) + i) * 16 + l15;                                                \
    _Pragma("unroll") for (int kk = 0; kk < 2; ++kk)                               \
      af[i][kk] = *(const bf16x8*)(Asl + rl * 64 + (((kk * 4 + lg) ^ (l15 & 7)) * 8)); \
  }
#define DSR_B(nb)                                                                  \
  _Pragma("unroll") for (int n = 0; n < 2; ++n) {                                  \
    int rl = (wc & 1) * 64 + ((nb) + n) * 16 + l15;                                \
    _Pragma("unroll") for (int kk = 0; kk < 2; ++kk)                               \
      bfv[n][kk] = *(const bf16x8*)(Bsl + rl * 64 + (((kk * 4 + lg) ^ (l15 & 7)) * 8)); \
  }
#define MM(ib, nb)                                                                 \
  _Pragma("unroll") for (int kk = 0; kk < 2; ++kk)                                 \
  _Pragma("unroll") for (int i = 0; i < 4; ++i)                                    \
  _Pragma("unroll") for (int n = 0; n < 2; ++n)                                    \
    acc[(ib) + i][(nb) + n] = MFMA16(af[i][kk], bfv[n][kk], acc[(ib) + i][(nb) + n]);
#define BAR asm volatile("s_barrier" ::: "memory")
#define LGK0                                        \
  asm volatile("s_waitcnt lgkmcnt(0)" ::: "memory"); \
  __builtin_amdgcn_sched_barrier(0)

  // prologue: stage K-tile 0 into slot 0, drain, barrier
  STG_HALF(&Al[0][0][0], A, m0, 0, 0);
  STG_HALF(&Al[0][1][0], A, m0, 1, 0);
  STG_HALF(&Bl[0][0][0], Bt, n0, 0, 0);
  STG_HALF(&Bl[0][1][0], Bt, n0, 1, 0);
  asm volatile("s_waitcnt vmcnt(0)" ::: "memory");
  BAR;

  int nkt = K >> 6;  // 16
  for (int kt = 0; kt < nkt; ++kt) {
    int s = kt & 1;
    const short* Asl = &Al[s][wr][0];
    const short* Bsl = &Bl[s][wc >> 1][0];
    short* Ad0 = &Al[s ^ 1][0][0];
    short* Ad1 = &Al[s ^ 1][1][0];
    short* Bd0 = &Bl[s ^ 1][0][0];
    short* Bd1 = &Bl[s ^ 1][1][0];
    bool st = (kt + 1 < nkt);
    bf16x8 af[4][2], bfv[2][2];
    // --- phase q0: A0-3 + B0-1; stage A(kt+1) h0 ---
    DSR_A(0);
    DSR_B(0);
    if (st) STG_HALF(Ad0, A, m0, 0, kt + 1);
    BAR;
    LGK0;
    __builtin_amdgcn_s_setprio(1);
    MM(0, 0);
    __builtin_amdgcn_s_setprio(0);
    BAR;
    // --- phase q1: B2-3; stage A(kt+1) h1 ---
    DSR_B(2);
    if (st) STG_HALF(Ad1, A, m0, 1, kt + 1);
    BAR;
    LGK0;
    __builtin_amdgcn_s_setprio(1);
    MM(0, 2);
    __builtin_amdgcn_s_setprio(0);
    BAR;
    // --- phase q2: A4-7 (B2-3 live); stage B(kt+1) h0 ---
    DSR_A(4);
    if (st) STG_HALF(Bd0, Bt, n0, 0, kt + 1);
    BAR;
    LGK0;
    __builtin_amdgcn_s_setprio(1);
    MM(4, 2);
    __builtin_amdgcn_s_setprio(0);
    BAR;
    // --- phase q3: B0-1 (A4-7 live); stage B(kt+1) h1; group-end vmcnt ---
    DSR_B(0);
    if (st) STG_HALF(Bd1, Bt, n0, 1, kt + 1);
    BAR;
    LGK0;
    __builtin_amdgcn_s_setprio(1);
    MM(4, 0);
    __builtin_amdgcn_s_setprio(0);
    if (st) asm volatile("s_waitcnt vmcnt(0)" ::: "memory");
    BAR;
  }
#undef STG_HALF
#undef DSR_A
#undef DSR_B
#undef MM
#undef BAR
#undef LGK0
#pragma unroll
  for (int i = 0; i < 8; ++i) {
#pragma unroll
    for (int r = 0; r < 4; ++r) {
      int row = m0 + wr * 128 + i * 16 + lg * 4 + r;
      size_t base = (size_t)row * N;
#pragma unroll
      for (int n = 0; n < 4; ++n) {
        int col = n0 + wc * 64 + n * 16 + l15;
        float v = acc[i][n][r];
        if (MODE == 2) {
          float rr2 = b2f(((const short*)Res)[base + col]);
          v = rr2 / (1.f + __expf(-rr2)) * v;
        }
        ((short*)C)[base + col] = f2b(v);
      }
    }
  }
}

// ---------------- GEMM wide, 4-buf counted-vmcnt pipeline: 512 thr, 8 waves
// 2x4, 128x128, BK=64, stage_rc swizzle, 2-deep prefetch, C = AB + Resf (f32 out).
__global__ __launch_bounds__(512) void gemm_wide(const short* __restrict__ A,
                                                 const short* __restrict__ Bt,
                                                 const float* Res, float* C,
                                                 int M, int N, int K) {
  __shared__ __attribute__((aligned(16))) short Alds[4][128 * 64];
  __shared__ __attribute__((aligned(16))) short Blds[4][128 * 64];
  int tid = threadIdx.x;
  int lane = tid & 63, w = tid >> 6;
  int wr = w >> 2, wc = w & 3;
  int l15 = lane & 15, lg = lane >> 4;
  int m0 = blockIdx.y * 128, n0 = blockIdx.x * 128;
  f32x4 acc[4][2] = {};
  int o0 = tid, o1 = 512 + tid;
  int r0 = o0 >> 3, cs0 = (o0 & 7) ^ (r0 & 7);
  int r1 = o1 >> 3, cs1 = (o1 & 7) ^ (r1 & 7);
  const short* Ap0 = A + (size_t)(m0 + r0) * K + cs0 * 8;
  const short* Ap1 = A + (size_t)(m0 + r1) * K + cs1 * 8;
  const short* Bp0 = Bt + (size_t)(n0 + r0) * K + cs0 * 8;
  const short* Bp1 = Bt + (size_t)(n0 + r1) * K + cs1 * 8;
  int wb = w * 512;
#define STG_W(buf, k0s)                                  \
  {                                                      \
    gl_lds16(Ap0 + (k0s), &Alds[buf][0] + wb);           \
    gl_lds16(Ap1 + (k0s), &Alds[buf][0] + 4096 + wb);    \
    gl_lds16(Bp0 + (k0s), &Blds[buf][0] + wb);           \
    gl_lds16(Bp1 + (k0s), &Blds[buf][0] + 4096 + wb);    \
  }
  int nk = K >> 6;
  STG_W(0, 0);
  STG_W(1, 64);
  asm volatile("s_waitcnt vmcnt(4)" ::: "memory");
  __builtin_amdgcn_s_barrier();
  asm volatile("" ::: "memory");
  for (int kt = 0; kt < nk; ++kt) {
    int buf = kt & 3;
    if (kt + 2 < nk) STG_W((kt + 2) & 3, (kt + 2) * 64);
    bf16x8 af[4][2], bfr[2][2];
#pragma unroll
    for (int i = 0; i < 4; ++i) {
      int ra = wr * 64 + i * 16 + l15;
#pragma unroll
      for (int kk = 0; kk < 2; ++kk) {
        int ua = (kk * 4 + lg) ^ (ra & 7);
        af[i][kk] = *(const bf16x8*)(&Alds[buf][0] + ra * 64 + ua * 8);
      }
    }
#pragma unroll
    for (int i = 0; i < 2; ++i) {
      int rb = wc * 32 + i * 16 + l15;
#pragma unroll
      for (int kk = 0; kk < 2; ++kk) {
        int ub = (kk * 4 + lg) ^ (rb & 7);
        bfr[i][kk] = *(const bf16x8*)(&Blds[buf][0] + rb * 64 + ub * 8);
      }
    }
#pragma unroll
    for (int kk = 0; kk < 2; ++kk)
#pragma unroll
      for (int mi = 0; mi < 4; ++mi)
#pragma unroll
        for (int ni = 0; ni < 2; ++ni)
          acc[mi][ni] = MFMA16(af[mi][kk], bfr[ni][kk], acc[mi][ni]);
    if (kt + 2 < nk) {
      asm volatile("s_waitcnt vmcnt(4)" ::: "memory");
    } else {
      asm volatile("s_waitcnt vmcnt(0)" ::: "memory");
    }
    __builtin_amdgcn_s_barrier();
    asm volatile("" ::: "memory");
  }
#undef STG_W
#pragma unroll
  for (int mi = 0; mi < 4; ++mi) {
#pragma unroll
    for (int r = 0; r < 4; ++r) {
      int row = m0 + wr * 64 + mi * 16 + lg * 4 + r;
      size_t base = (size_t)row * N;
#pragma unroll
      for (int ni = 0; ni < 2; ++ni) {
        int col = n0 + wc * 32 + ni * 16 + l15;
        C[base + col] = acc[mi][ni][r] + Res[base + col];
      }
    }
  }
}

// ---------------- V transpose: V[B*S][H*64] -> Vt[bh][64][2048] ----------------
__global__ __launch_bounds__(256) void vtranspose(const short* __restrict__ V,
                                                  short* __restrict__ Vt) {
  __shared__ short T[64 * 72];
  int bh = blockIdx.y;
  int s0 = blockIdx.x * 64;
  int t = threadIdx.x;
  int r = t >> 2, cq = t & 3;
  const short* src = V + (size_t)((bh >> 4) * 2048 + s0 + r) * 1024 + (bh & 15) * 64 + cq * 16;
  *(int4*)(T + r * 72 + cq * 16) = *(const int4*)src;
  *(int4*)(T + r * 72 + cq * 16 + 8) = *(const int4*)(src + 8);
  __syncthreads();
  int d = t >> 2, sq = t & 3;
  short* dst = Vt + (size_t)bh * 131072 + (size_t)d * 2048 + s0 + sq * 16;
#pragma unroll
  for (int q = 0; q < 4; ++q) {
    short4v o;
#pragma unroll
    for (int j = 0; j < 4; ++j) o[j] = T[(sq * 16 + q * 4 + j) * 72 + d];
    *(short4v*)(dst + q * 4) = o;
  }
}

// ---------------- Flash attention v6 (round-10 proven): LDS-staged K/V, 2-phase
// dbuf, stage_rc XOR swizzle. p = exp(s/8 - 24), l via ones-MFMA.
__global__ __launch_bounds__(256) void attn6(const short* __restrict__ Q,
                                             const short* __restrict__ K,
                                             const short* __restrict__ Vt,
                                             short* __restrict__ O) {
  __shared__ __attribute__((aligned(16))) short Klds[2][64 * 64];
  __shared__ __attribute__((aligned(16))) short Vlds[2][64 * 64];
  __shared__ __attribute__((aligned(16))) short Ptlds[4][64 * 20];
  int bx = blockIdx.x;
  int bh = bx & 31;
  int qt = 31 - (bx >> 5);
  int tid = threadIdx.x;
  int w = tid >> 6, lane = tid & 63;
  int l15 = lane & 15, lg = lane >> 4;
  int qbase = qt * 64 + w * 16;
  size_t rowbase = (size_t)(bh >> 4) * 2048 * 1024 + (size_t)(bh & 15) * 64;
  const short* vtb = Vt + (size_t)bh * 131072;
  const short* Kb0 = K + rowbase;
  bf16x8 qf[2];
  {
    const short* qp = Q + rowbase + (size_t)(qbase + l15) * 1024 + lg * 8;
    qf[0] = *(const bf16x8*)qp;
    qf[1] = *(const bf16x8*)(qp + 32);
  }
  bf16x8 ones;
#pragma unroll
  for (int j = 0; j < 8; ++j) ones[j] = (short)0x3F80;
  f32x4 oacc[4] = {};
  f32x4 lacc = {};
  int nchunk = qt + 1;
  short* pt = Ptlds[w];
  int i0 = w * 64 + lane;
  int r0 = i0 >> 3, c0 = i0 & 7, cs0 = c0 ^ (r0 & 7);
  int i1 = 256 + i0;
  int r1 = i1 >> 3, c1 = i1 & 7, cs1 = c1 ^ (r1 & 7);
#define STAGE_KV(buf, kt)                                                      \
  {                                                                            \
    int ks = (kt) * 64;                                                        \
    gl_lds16(Kb0 + (size_t)(ks + r0) * 1024 + cs0 * 8, &Klds[buf][0] + i0 * 8);\
    gl_lds16(Kb0 + (size_t)(ks + r1) * 1024 + cs1 * 8, &Klds[buf][0] + i1 * 8);\
    gl_lds16(vtb + (size_t)r0 * 2048 + ks + cs0 * 8, &Vlds[buf][0] + i0 * 8);  \
    gl_lds16(vtb + (size_t)r1 * 2048 + ks + cs1 * 8, &Vlds[buf][0] + i1 * 8);  \
  }
  STAGE_KV(0, 0);
  __syncthreads();
  int cur = 0;
  for (int kt = 0; kt < nchunk; ++kt) {
    if (kt + 1 < nchunk) STAGE_KV(cur ^ 1, kt + 1);
    int kstart = kt * 64;
    f32x4 s[4] = {};
#pragma unroll
    for (int g = 0; g < 4; ++g) {
      int krow = g * 16 + l15;
      bf16x8 k0 = *(const bf16x8*)(&Klds[cur][0] + krow * 64 + ((lg ^ (l15 & 7)) * 8));
      bf16x8 k1 = *(const bf16x8*)(&Klds[cur][0] + krow * 64 + (((4 + lg) ^ (l15 & 7)) * 8));
      s[g] = MFMA16(qf[0], k0, s[g]);
      s[g] = MFMA16(qf[1], k1, s[g]);
    }
#pragma unroll
    for (int g = 0; g < 4; ++g) {
      short4v pk;
#pragma unroll
      for (int r = 0; r < 4; ++r) {
        int qg = qbase + lg * 4 + r;
        int kg = kstart + g * 16 + l15;
        float v = __expf(s[g][r] * 0.125f - 24.f);
        pk[r] = f2b((kg > qg) ? 0.f : v);
      }
      *(short4v*)(pt + (g * 16 + l15) * 20 + lg * 4) = pk;
    }
    bf16x8 pa0, pa1;
#pragma unroll
    for (int j = 0; j < 8; ++j) {
      pa0[j] = pt[(lg * 8 + j) * 20 + l15];
      pa1[j] = pt[(32 + lg * 8 + j) * 20 + l15];
    }
#pragma unroll
    for (int t = 0; t < 4; ++t) {
      int drow = t * 16 + l15;
      bf16x8 vf0 = *(const bf16x8*)(&Vlds[cur][0] + drow * 64 + ((lg ^ (l15 & 7)) * 8));
      bf16x8 vf1 = *(const bf16x8*)(&Vlds[cur][0] + drow * 64 + (((4 + lg) ^ (l15 & 7)) * 8));
      oacc[t] = MFMA16(pa0, vf0, oacc[t]);
      oacc[t] = MFMA16(pa1, vf1, oacc[t]);
    }
    lacc = MFMA16(pa0, ones, lacc);
    lacc = MFMA16(pa1, ones, lacc);
    __syncthreads();
    cur ^= 1;
  }
#undef STAGE_KV
#pragma unroll
  for (int t = 0; t < 4; ++t) {
#pragma unroll
    for (int r = 0; r < 4; ++r) {
      int row = qbase + lg * 4 + r;
      float denom = fmaxf(lacc[r], 1e-30f);
      O[rowbase + (size_t)row * 1024 + t * 16 + l15] = f2b(oacc[t][r] / denom);
    }
  }
}

extern "C" void kernel_launch(void* const* d_in, const int* in_sizes, int n_in,
                              void* d_out, int out_size, void* d_ws, size_t ws_size,
                              hipStream_t stream) {
  const float* xf = (const float*)d_in[0];
  const float* G1f = (const float*)d_in[8];
  const float* G2f = (const float*)d_in[9];
  char* ws = (char*)d_ws;
  const size_t MB = 1048576;
  short* Wslot = (short*)(ws);            // [0,8): WOb early, then W1/W3/W2
  short* WOb   = (short*)(ws);
  short* Wcat  = (short*)(ws + 8 * MB);   // [8,14): fused QKV weights
  short* Vt    = (short*)(ws + 8 * MB);   // [8,16): V^T (after Wcat dead)
  short* h     = (short*)(ws + 16 * MB);  // [16,24)
  short* Qb    = (short*)(ws + 24 * MB);  // [24,32)
  short* Kb    = (short*)(ws + 32 * MB);  // [32,40)
  short* Vb    = (short*)(ws + 40 * MB);  // [40,48)
  short* att   = (short*)(ws + 48 * MB);  // [48,56)
  short* w1x   = Qb;                      // [24,56): Q/K/V/att dead by FFN time
  float* x1f   = (float*)d_out;
  float* outf  = (float*)d_out;

  dim3 blk(256);
  convert_kernel<<<512, blk, 0, stream>>>((const float*)d_in[1], Wcat, 1048576);
  convert_kernel<<<512, blk, 0, stream>>>((const float*)d_in[2], Wcat + 1048576, 1048576);
  convert_kernel<<<512, blk, 0, stream>>>((const float*)d_in[3], Wcat + 2097152, 1048576);
  convert_kernel<<<512, blk, 0, stream>>>((const float*)d_in[4], WOb, 1048576);

  rmsnorm_f32<<<4096, blk, 0, stream>>>(xf, G1f, h);
  dim3 gqkv(24, 32);
  gemm_bt<3><<<gqkv, blk, 0, stream>>>(h, Wcat, nullptr, Qb, Kb, Vb, 4096, 1024, 1024);
  dim3 gvt(32, 32);
  vtranspose<<<gvt, blk, 0, stream>>>(Vb, Vt);
  attn6<<<1024, blk, 0, stream>>>(Qb, Kb, Vt, att);
  dim3 g1(8, 32);
  gemm_wide<<<g1, dim3(512), 0, stream>>>(att, WOb, xf, x1f, 4096, 1024, 1024);
  rmsnorm_f32<<<4096, blk, 0, stream>>>(x1f, G2f, h);
  convert_kernel<<<2048, blk, 0, stream>>>((const float*)d_in[5], Wslot, 4194304);
  gemm256<0><<<256, dim3(512), 0, stream>>>(h, Wslot, nullptr, w1x, 4096, 4096, 1024);
  convert_kernel<<<2048, blk, 0, stream>>>((const float*)d_in[7], Wslot, 4194304);
  gemm256<2><<<256, dim3(512), 0, stream>>>(h, Wslot, w1x, w1x, 4096, 4096, 1024);
  convert_kernel<<<2048, blk, 0, stream>>>((const float*)d_in[6], Wslot, 4194304);
  gemm_wide<<<g1, dim3(512), 0, stream>>>(w1x, Wslot, x1f, outf, 4096, 1024, 4096);
}

// Round 15
// 303.281 us; speedup vs baseline: 1.7321x; 1.0924x over previous
//
#include <hip/hip_runtime.h>
#include <stdint.h>

typedef __attribute__((ext_vector_type(8))) short bf16x8;
typedef __attribute__((ext_vector_type(4))) short short4v;
typedef __attribute__((ext_vector_type(4))) float f32x4;

#define MFMA16(a, b, c) __builtin_amdgcn_mfma_f32_16x16x32_bf16((a), (b), (c), 0, 0, 0)

__device__ __forceinline__ float b2f(short s) {
  unsigned u = ((unsigned)(unsigned short)s) << 16;
  return __builtin_bit_cast(float, u);
}
__device__ __forceinline__ short f2b(float f) {
  unsigned u = __builtin_bit_cast(unsigned, f);
  u = (u + 0x7fffu + ((u >> 16) & 1u)) >> 16;
  return (short)u;
}

// async global->LDS, 16B per lane; lds dest is wave-uniform base (HW adds lane*16)
__device__ __forceinline__ void gl_lds16(const short* g, short* l) {
  __builtin_amdgcn_global_load_lds((const __attribute__((address_space(1))) void*)g,
                                   (__attribute__((address_space(3))) void*)l, 16, 0, 0);
}

// -------- convert f32 -> bf16 (8 elems/thread) --------
__global__ __launch_bounds__(256) void convert_kernel(const float* __restrict__ src,
                                                      short* __restrict__ dst, int n) {
  int i = (blockIdx.x * 256 + threadIdx.x) * 8;
  if (i >= n) return;
  f32x4 a = *(const f32x4*)(src + i);
  f32x4 b = *(const f32x4*)(src + i + 4);
  short4v o0, o1;
#pragma unroll
  for (int j = 0; j < 4; ++j) { o0[j] = f2b(a[j]); o1[j] = f2b(b[j]); }
  *(short4v*)(dst + i) = o0;
  *(short4v*)(dst + i + 4) = o1;
}

// -------- RMSNorm: f32 in, f32 gamma, bf16 out; one block per row of 1024 --------
__global__ __launch_bounds__(256) void rmsnorm_f32(const float* __restrict__ X,
                                                   const float* __restrict__ G,
                                                   short* __restrict__ O) {
  int row = blockIdx.x;
  int t = threadIdx.x;
  f32x4 v = *(const f32x4*)(X + (size_t)row * 1024 + t * 4);
  float ss = 0.f;
#pragma unroll
  for (int j = 0; j < 4; ++j) ss += v[j] * v[j];
#pragma unroll
  for (int d = 1; d < 64; d <<= 1) ss += __shfl_xor(ss, d, 64);
  __shared__ float red[4];
  if ((t & 63) == 0) red[t >> 6] = ss;
  __syncthreads();
  float tot = red[0] + red[1] + red[2] + red[3];
  float rinv = rsqrtf(tot * (1.0f / 1024.0f) + 1e-5f);
  f32x4 g = *(const f32x4*)(G + t * 4);
  short4v o;
#pragma unroll
  for (int j = 0; j < 4; ++j) o[j] = f2b(v[j] * rinv * g[j]);
  *(short4v*)(O + (size_t)row * 1024 + t * 4) = o;
}

// ---------------- GEMM 2-phase: 256 thr, 4 waves 2x2, 128x128, BK=32, dbuf LDS
// MODE 0: C = AB | MODE 3: QKV-split + fused RoPE
template <int MODE>
__global__ __launch_bounds__(256) void gemm_bt(const short* __restrict__ A,
                                               const short* __restrict__ Bt,
                                               const void* Res, void* C,
                                               void* C1, void* C2,
                                               int M, int N, int K) {
  __shared__ __attribute__((aligned(16))) short Alds[2][128 * 32];
  __shared__ __attribute__((aligned(16))) short Blds[2][128 * 32];
  int tid = threadIdx.x;
  int lane = tid & 63, w = tid >> 6;
  int wr = w >> 1, wc = w & 1;
  int l15 = lane & 15, lg = lane >> 4;
  int m0 = blockIdx.y * 128, n0 = blockIdx.x * 128;
  void* Cw = C;
  int ncol0 = n0;
  int seg = 0;
  if (MODE == 3) {
    seg = n0 >> 10;
    Cw = (seg == 0) ? C : (seg == 1) ? C1 : C2;
    ncol0 = n0 & 1023;
  }
  f32x4 acc[4][4] = {};
  int arow = tid >> 2, acol = (tid & 3) * 8;
  const short* Ap = A + (size_t)(m0 + arow) * K + acol;
  const short* Bp = Bt + (size_t)(n0 + arow) * K + acol;
  int wb = w * 512;
#define STAGE_BT(buf, k0s)                                   \
  {                                                          \
    gl_lds16(Ap + (k0s), &Alds[buf][0] + wb);                \
    gl_lds16(Ap + (size_t)64 * K + (k0s), &Alds[buf][0] + 2048 + wb); \
    gl_lds16(Bp + (k0s), &Blds[buf][0] + wb);                \
    gl_lds16(Bp + (size_t)64 * K + (k0s), &Blds[buf][0] + 2048 + wb); \
  }
  STAGE_BT(0, 0);
  __syncthreads();
  int cur = 0;
  for (int k0 = 0; k0 < K; k0 += 32) {
    if (k0 + 32 < K) STAGE_BT(cur ^ 1, k0 + 32);
    bf16x8 af[4], bfr[4];
#pragma unroll
    for (int i = 0; i < 4; ++i) {
      af[i] = *(const bf16x8*)(&Alds[cur][0] + (wr * 64 + i * 16 + l15) * 32 + lg * 8);
      bfr[i] = *(const bf16x8*)(&Blds[cur][0] + (wc * 64 + i * 16 + l15) * 32 + lg * 8);
    }
#pragma unroll
    for (int mi = 0; mi < 4; ++mi)
#pragma unroll
      for (int ni = 0; ni < 4; ++ni)
        acc[mi][ni] = MFMA16(af[mi], bfr[ni], acc[mi][ni]);
    __syncthreads();
    cur ^= 1;
  }
#undef STAGE_BT
#pragma unroll
  for (int mi = 0; mi < 4; ++mi) {
#pragma unroll
    for (int r = 0; r < 4; ++r) {
      int row = m0 + wr * 64 + mi * 16 + lg * 4 + r;
      size_t base = (size_t)row * N;
#pragma unroll
      for (int ni = 0; ni < 4; ++ni) {
        int col = ncol0 + wc * 64 + ni * 16 + l15;
        float v = acc[mi][ni][r];
        if (MODE == 3 && seg <= 1) {
          int pos = row & 2047;
          int ii = (col & 62) >> 1;
          float invf2 = exp2f(-(float)ii * 0.4152410118f) * 0.15915494309f;
          float rev = (float)pos * invf2;
          rev -= rintf(rev);
          float angr = rev * 6.28318530718f;
          float sn = __sinf(angr), cs = __cosf(angr);
          float partner = __shfl_xor(v, 1, 64);
          float t = partner * sn;
          v = v * cs + (((l15 & 1) == 0) ? -t : t);
        }
        ((short*)Cw)[base + col] = f2b(v);
      }
    }
  }
}

// ---------------- Fused W1+W3 GEMM: 256x256, BK=64, 2-phase dbuf (r13-proven),
// pass1 acc over B1 (W1), stash f2b(acc) in regs (numerically = old w1x store),
// pass2 acc over B3 (W3), epilogue C = silu(stash) * acc3 (bf16 out).
// stage_rc swizzle; XCD-chunked grid (256 % 8 == 0 -> bijective).
__global__ __launch_bounds__(512) void gemm256_fused(const short* __restrict__ A,
                                                     const short* __restrict__ B1,
                                                     const short* __restrict__ B3,
                                                     short* __restrict__ C,
                                                     int M, int N, int K) {
  __shared__ __attribute__((aligned(16))) short Alds[2][256 * 64];
  __shared__ __attribute__((aligned(16))) short Blds[2][256 * 64];
  int tid = threadIdx.x;
  int lane = tid & 63, w = tid >> 6;
  int wr = w >> 2, wc = w & 3;  // 2 x 4 waves
  int l15 = lane & 15, lg = lane >> 4;
  int wg = blockIdx.x;
  int swz = (wg & 7) * 32 + (wg >> 3);
  int by = swz >> 4, bx = swz & 15;
  int m0 = by * 256, n0 = bx * 256;
  int rr = tid >> 3;
  int cs = (tid & 7) ^ (rr & 7);
  const short* Apt = A + (size_t)(m0 + rr) * K + cs * 8;
  const short* Bpt1 = B1 + (size_t)(n0 + rr) * K + cs * 8;
  const short* Bpt3 = B3 + (size_t)(n0 + rr) * K + cs * 8;
  int nt = K >> 6;
  f32x4 acc[8][4];
  short4v stash[8][4];
#define STAGE_A(buf, kt)                                                             \
  {                                                                                  \
    int ko = (kt) * 64;                                                              \
    _Pragma("unroll") for (int j = 0; j < 4; ++j)                                    \
        gl_lds16(Apt + (size_t)(j * 64) * K + ko, &Alds[buf][0] + j * 4096 + w * 512); \
  }
#define STAGE_B(buf, kt, Bp)                                                         \
  {                                                                                  \
    int ko = (kt) * 64;                                                              \
    _Pragma("unroll") for (int j = 0; j < 4; ++j)                                    \
        gl_lds16((Bp) + (size_t)(j * 64) * K + ko, &Blds[buf][0] + j * 4096 + w * 512); \
  }
#define KLOOP(Bp)                                                                    \
  {                                                                                  \
    STAGE_A(0, 0);                                                                   \
    STAGE_B(0, 0, Bp);                                                               \
    __syncthreads();                                                                 \
    int cur = 0;                                                                     \
    for (int kt = 0; kt < nt; ++kt) {                                                \
      if (kt + 1 < nt) { STAGE_A(cur ^ 1, kt + 1); STAGE_B(cur ^ 1, kt + 1, Bp); }   \
      _Pragma("unroll") for (int kk = 0; kk < 2; ++kk) {                             \
        bf16x8 af[8], bfr[4];                                                        \
        _Pragma("unroll") for (int i = 0; i < 8; ++i) {                              \
          int ra = wr * 128 + i * 16 + l15;                                          \
          int ua = (kk * 4 + lg) ^ (ra & 7);                                         \
          af[i] = *(const bf16x8*)(&Alds[cur][0] + ra * 64 + ua * 8);                \
        }                                                                            \
        _Pragma("unroll") for (int n = 0; n < 4; ++n) {                              \
          int rb = wc * 64 + n * 16 + l15;                                           \
          int ub = (kk * 4 + lg) ^ (rb & 7);                                         \
          bfr[n] = *(const bf16x8*)(&Blds[cur][0] + rb * 64 + ub * 8);               \
        }                                                                            \
        _Pragma("unroll") for (int i = 0; i < 8; ++i)                                \
        _Pragma("unroll") for (int n = 0; n < 4; ++n)                                \
            acc[i][n] = MFMA16(af[i], bfr[n], acc[i][n]);                            \
      }                                                                              \
      __syncthreads();                                                               \
      cur ^= 1;                                                                      \
    }                                                                                \
  }
  // ---- pass 1: W1 ----
#pragma unroll
  for (int i = 0; i < 8; ++i)
#pragma unroll
    for (int n = 0; n < 4; ++n) acc[i][n] = (f32x4){0.f, 0.f, 0.f, 0.f};
  KLOOP(Bpt1);
#pragma unroll
  for (int i = 0; i < 8; ++i)
#pragma unroll
    for (int n = 0; n < 4; ++n)
#pragma unroll
      for (int r = 0; r < 4; ++r) stash[i][n][r] = f2b(acc[i][n][r]);
  // ---- pass 2: W3 ----
#pragma unroll
  for (int i = 0; i < 8; ++i)
#pragma unroll
    for (int n = 0; n < 4; ++n) acc[i][n] = (f32x4){0.f, 0.f, 0.f, 0.f};
  KLOOP(Bpt3);
#undef KLOOP
#undef STAGE_A
#undef STAGE_B
  // ---- epilogue: C = silu(w1x) * w3x ----
#pragma unroll
  for (int i = 0; i < 8; ++i) {
#pragma unroll
    for (int r = 0; r < 4; ++r) {
      int row = m0 + wr * 128 + i * 16 + lg * 4 + r;
      size_t base = (size_t)row * N;
#pragma unroll
      for (int n = 0; n < 4; ++n) {
        int col = n0 + wc * 64 + n * 16 + l15;
        float w1v = b2f(stash[i][n][r]);
        float v = w1v / (1.f + __expf(-w1v)) * acc[i][n][r];
        C[base + col] = f2b(v);
      }
    }
  }
}

// ---------------- GEMM wide, 4-buf counted-vmcnt: 512 thr, 8 waves 2x4, 128x128,
// BK=64, stage_rc swizzle, C = AB + Resf (f32 out). XCD m-chunk remap: XCD i owns
// 4 contiguous m-panels x all n (matches gemm256_fused's m-ownership for W2's A).
__global__ __launch_bounds__(512) void gemm_wide(const short* __restrict__ A,
                                                 const short* __restrict__ Bt,
                                                 const float* Res, float* C,
                                                 int M, int N, int K) {
  __shared__ __attribute__((aligned(16))) short Alds[4][128 * 64];
  __shared__ __attribute__((aligned(16))) short Blds[4][128 * 64];
  int tid = threadIdx.x;
  int lane = tid & 63, w = tid >> 6;
  int wr = w >> 2, wc = w & 3;
  int l15 = lane & 15, lg = lane >> 4;
  // XCD m-chunk: lin&7 -> xcd (assumed round-robin); xcd owns mpX m-panels x all n
  int lin = blockIdx.y * gridDim.x + blockIdx.x;
  int nx = gridDim.x;
  int xcd = lin & 7, idx = lin >> 3;
  int mpX = (gridDim.y >> 3);
  int m0 = (xcd * mpX + idx / nx) * 128;
  int n0 = (idx % nx) * 128;
  f32x4 acc[4][2] = {};
  int o0 = tid, o1 = 512 + tid;
  int r0 = o0 >> 3, cs0 = (o0 & 7) ^ (r0 & 7);
  int r1 = o1 >> 3, cs1 = (o1 & 7) ^ (r1 & 7);
  const short* Ap0 = A + (size_t)(m0 + r0) * K + cs0 * 8;
  const short* Ap1 = A + (size_t)(m0 + r1) * K + cs1 * 8;
  const short* Bp0 = Bt + (size_t)(n0 + r0) * K + cs0 * 8;
  const short* Bp1 = Bt + (size_t)(n0 + r1) * K + cs1 * 8;
  int wb = w * 512;
#define STG_W(buf, k0s)                                  \
  {                                                      \
    gl_lds16(Ap0 + (k0s), &Alds[buf][0] + wb);           \
    gl_lds16(Ap1 + (k0s), &Alds[buf][0] + 4096 + wb);    \
    gl_lds16(Bp0 + (k0s), &Blds[buf][0] + wb);           \
    gl_lds16(Bp1 + (k0s), &Blds[buf][0] + 4096 + wb);    \
  }
  int nk = K >> 6;
  STG_W(0, 0);
  STG_W(1, 64);
  asm volatile("s_waitcnt vmcnt(4)" ::: "memory");
  __builtin_amdgcn_s_barrier();
  asm volatile("" ::: "memory");
  for (int kt = 0; kt < nk; ++kt) {
    int buf = kt & 3;
    if (kt + 2 < nk) STG_W((kt + 2) & 3, (kt + 2) * 64);
    bf16x8 af[4][2], bfr[2][2];
#pragma unroll
    for (int i = 0; i < 4; ++i) {
      int ra = wr * 64 + i * 16 + l15;
#pragma unroll
      for (int kk = 0; kk < 2; ++kk) {
        int ua = (kk * 4 + lg) ^ (ra & 7);
        af[i][kk] = *(const bf16x8*)(&Alds[buf][0] + ra * 64 + ua * 8);
      }
    }
#pragma unroll
    for (int i = 0; i < 2; ++i) {
      int rb = wc * 32 + i * 16 + l15;
#pragma unroll
      for (int kk = 0; kk < 2; ++kk) {
        int ub = (kk * 4 + lg) ^ (rb & 7);
        bfr[i][kk] = *(const bf16x8*)(&Blds[buf][0] + rb * 64 + ub * 8);
      }
    }
#pragma unroll
    for (int kk = 0; kk < 2; ++kk)
#pragma unroll
      for (int mi = 0; mi < 4; ++mi)
#pragma unroll
        for (int ni = 0; ni < 2; ++ni)
          acc[mi][ni] = MFMA16(af[mi][kk], bfr[ni][kk], acc[mi][ni]);
    if (kt + 2 < nk) {
      asm volatile("s_waitcnt vmcnt(4)" ::: "memory");
    } else {
      asm volatile("s_waitcnt vmcnt(0)" ::: "memory");
    }
    __builtin_amdgcn_s_barrier();
    asm volatile("" ::: "memory");
  }
#undef STG_W
#pragma unroll
  for (int mi = 0; mi < 4; ++mi) {
#pragma unroll
    for (int r = 0; r < 4; ++r) {
      int row = m0 + wr * 64 + mi * 16 + lg * 4 + r;
      size_t base = (size_t)row * N;
#pragma unroll
      for (int ni = 0; ni < 2; ++ni) {
        int col = n0 + wc * 32 + ni * 16 + l15;
        C[base + col] = acc[mi][ni][r] + Res[base + col];
      }
    }
  }
}

// ---------------- V transpose: V[B*S][H*64] -> Vt[bh][64][2048] ----------------
__global__ __launch_bounds__(256) void vtranspose(const short* __restrict__ V,
                                                  short* __restrict__ Vt) {
  __shared__ short T[64 * 72];
  int bh = blockIdx.y;
  int s0 = blockIdx.x * 64;
  int t = threadIdx.x;
  int r = t >> 2, cq = t & 3;
  const short* src = V + (size_t)((bh >> 4) * 2048 + s0 + r) * 1024 + (bh & 15) * 64 + cq * 16;
  *(int4*)(T + r * 72 + cq * 16) = *(const int4*)src;
  *(int4*)(T + r * 72 + cq * 16 + 8) = *(const int4*)(src + 8);
  __syncthreads();
  int d = t >> 2, sq = t & 3;
  short* dst = Vt + (size_t)bh * 131072 + (size_t)d * 2048 + s0 + sq * 16;
#pragma unroll
  for (int q = 0; q < 4; ++q) {
    short4v o;
#pragma unroll
    for (int j = 0; j < 4; ++j) o[j] = T[(sq * 16 + q * 4 + j) * 72 + d];
    *(short4v*)(dst + q * 4) = o;
  }
}

// ---------------- Flash attention v6 (round-10 proven): LDS-staged K/V, 2-phase
// dbuf, stage_rc XOR swizzle. p = exp(s/8 - 24), l via ones-MFMA.
__global__ __launch_bounds__(256) void attn6(const short* __restrict__ Q,
                                             const short* __restrict__ K,
                                             const short* __restrict__ Vt,
                                             short* __restrict__ O) {
  __shared__ __attribute__((aligned(16))) short Klds[2][64 * 64];
  __shared__ __attribute__((aligned(16))) short Vlds[2][64 * 64];
  __shared__ __attribute__((aligned(16))) short Ptlds[4][64 * 20];
  int bx = blockIdx.x;
  int bh = bx & 31;
  int qt = 31 - (bx >> 5);
  int tid = threadIdx.x;
  int w = tid >> 6, lane = tid & 63;
  int l15 = lane & 15, lg = lane >> 4;
  int qbase = qt * 64 + w * 16;
  size_t rowbase = (size_t)(bh >> 4) * 2048 * 1024 + (size_t)(bh & 15) * 64;
  const short* vtb = Vt + (size_t)bh * 131072;
  const short* Kb0 = K + rowbase;
  bf16x8 qf[2];
  {
    const short* qp = Q + rowbase + (size_t)(qbase + l15) * 1024 + lg * 8;
    qf[0] = *(const bf16x8*)qp;
    qf[1] = *(const bf16x8*)(qp + 32);
  }
  bf16x8 ones;
#pragma unroll
  for (int j = 0; j < 8; ++j) ones[j] = (short)0x3F80;
  f32x4 oacc[4] = {};
  f32x4 lacc = {};
  int nchunk = qt + 1;
  short* pt = Ptlds[w];
  int i0 = w * 64 + lane;
  int r0 = i0 >> 3, c0 = i0 & 7, cs0 = c0 ^ (r0 & 7);
  int i1 = 256 + i0;
  int r1 = i1 >> 3, c1 = i1 & 7, cs1 = c1 ^ (r1 & 7);
#define STAGE_KV(buf, kt)                                                      \
  {                                                                            \
    int ks = (kt) * 64;                                                        \
    gl_lds16(Kb0 + (size_t)(ks + r0) * 1024 + cs0 * 8, &Klds[buf][0] + i0 * 8);\
    gl_lds16(Kb0 + (size_t)(ks + r1) * 1024 + cs1 * 8, &Klds[buf][0] + i1 * 8);\
    gl_lds16(vtb + (size_t)r0 * 2048 + ks + cs0 * 8, &Vlds[buf][0] + i0 * 8);  \
    gl_lds16(vtb + (size_t)r1 * 2048 + ks + cs1 * 8, &Vlds[buf][0] + i1 * 8);  \
  }
  STAGE_KV(0, 0);
  __syncthreads();
  int cur = 0;
  for (int kt = 0; kt < nchunk; ++kt) {
    if (kt + 1 < nchunk) STAGE_KV(cur ^ 1, kt + 1);
    int kstart = kt * 64;
    f32x4 s[4] = {};
#pragma unroll
    for (int g = 0; g < 4; ++g) {
      int krow = g * 16 + l15;
      bf16x8 k0 = *(const bf16x8*)(&Klds[cur][0] + krow * 64 + ((lg ^ (l15 & 7)) * 8));
      bf16x8 k1 = *(const bf16x8*)(&Klds[cur][0] + krow * 64 + (((4 + lg) ^ (l15 & 7)) * 8));
      s[g] = MFMA16(qf[0], k0, s[g]);
      s[g] = MFMA16(qf[1], k1, s[g]);
    }
#pragma unroll
    for (int g = 0; g < 4; ++g) {
      short4v pk;
#pragma unroll
      for (int r = 0; r < 4; ++r) {
        int qg = qbase + lg * 4 + r;
        int kg = kstart + g * 16 + l15;
        float v = __expf(s[g][r] * 0.125f - 24.f);
        pk[r] = f2b((kg > qg) ? 0.f : v);
      }
      *(short4v*)(pt + (g * 16 + l15) * 20 + lg * 4) = pk;
    }
    bf16x8 pa0, pa1;
#pragma unroll
    for (int j = 0; j < 8; ++j) {
      pa0[j] = pt[(lg * 8 + j) * 20 + l15];
      pa1[j] = pt[(32 + lg * 8 + j) * 20 + l15];
    }
#pragma unroll
    for (int t = 0; t < 4; ++t) {
      int drow = t * 16 + l15;
      bf16x8 vf0 = *(const bf16x8*)(&Vlds[cur][0] + drow * 64 + ((lg ^ (l15 & 7)) * 8));
      bf16x8 vf1 = *(const bf16x8*)(&Vlds[cur][0] + drow * 64 + (((4 + lg) ^ (l15 & 7)) * 8));
      oacc[t] = MFMA16(pa0, vf0, oacc[t]);
      oacc[t] = MFMA16(pa1, vf1, oacc[t]);
    }
    lacc = MFMA16(pa0, ones, lacc);
    lacc = MFMA16(pa1, ones, lacc);
    __syncthreads();
    cur ^= 1;
  }
#undef STAGE_KV
#pragma unroll
  for (int t = 0; t < 4; ++t) {
#pragma unroll
    for (int r = 0; r < 4; ++r) {
      int row = qbase + lg * 4 + r;
      float denom = fmaxf(lacc[r], 1e-30f);
      O[rowbase + (size_t)row * 1024 + t * 16 + l15] = f2b(oacc[t][r] / denom);
    }
  }
}

extern "C" void kernel_launch(void* const* d_in, const int* in_sizes, int n_in,
                              void* d_out, int out_size, void* d_ws, size_t ws_size,
                              hipStream_t stream) {
  const float* xf = (const float*)d_in[0];
  const float* G1f = (const float*)d_in[8];
  const float* G2f = (const float*)d_in[9];
  char* ws = (char*)d_ws;
  const size_t MB = 1048576;
  short* Wslot = (short*)(ws);            // [0,8): WOb early, then W1, then W2
  short* WOb   = (short*)(ws);
  short* Wcat  = (short*)(ws + 8 * MB);   // [8,14): fused QKV weights
  short* Vt    = (short*)(ws + 8 * MB);   // [8,16): V^T (after Wcat dead)
  short* h     = (short*)(ws + 16 * MB);  // [16,24)
  short* Qb    = (short*)(ws + 24 * MB);  // [24,32)
  short* Kb    = (short*)(ws + 32 * MB);  // [32,40)
  short* Vb    = (short*)(ws + 40 * MB);  // [40,48)
  short* att   = (short*)(ws + 48 * MB);  // [48,56)
  short* W3b   = (short*)(ws + 56 * MB);  // [56,64): W3 bf16
  short* w1x   = Qb;                      // [24,56): Q/K/V/att dead by FFN time
  float* x1f   = (float*)d_out;
  float* outf  = (float*)d_out;

  dim3 blk(256);
  convert_kernel<<<512, blk, 0, stream>>>((const float*)d_in[1], Wcat, 1048576);
  convert_kernel<<<512, blk, 0, stream>>>((const float*)d_in[2], Wcat + 1048576, 1048576);
  convert_kernel<<<512, blk, 0, stream>>>((const float*)d_in[3], Wcat + 2097152, 1048576);
  convert_kernel<<<512, blk, 0, stream>>>((const float*)d_in[4], WOb, 1048576);

  rmsnorm_f32<<<4096, blk, 0, stream>>>(xf, G1f, h);
  dim3 gqkv(24, 32);
  gemm_bt<3><<<gqkv, blk, 0, stream>>>(h, Wcat, nullptr, Qb, Kb, Vb, 4096, 1024, 1024);
  dim3 gvt(32, 32);
  vtranspose<<<gvt, blk, 0, stream>>>(Vb, Vt);
  attn6<<<1024, blk, 0, stream>>>(Qb, Kb, Vt, att);
  dim3 g1(8, 32);
  gemm_wide<<<g1, dim3(512), 0, stream>>>(att, WOb, xf, x1f, 4096, 1024, 1024);
  rmsnorm_f32<<<4096, blk, 0, stream>>>(x1f, G2f, h);
  convert_kernel<<<2048, blk, 0, stream>>>((const float*)d_in[5], Wslot, 4194304);
  convert_kernel<<<2048, blk, 0, stream>>>((const float*)d_in[7], W3b, 4194304);
  gemm256_fused<<<256, dim3(512), 0, stream>>>(h, Wslot, W3b, w1x, 4096, 4096, 1024);
  convert_kernel<<<2048, blk, 0, stream>>>((const float*)d_in[6], Wslot, 4194304);
  gemm_wide<<<g1, dim3(512), 0, stream>>>(w1x, Wslot, x1f, outf, 4096, 1024, 4096);
}

// Round 19
// 302.932 us; speedup vs baseline: 1.7341x; 1.0011x over previous
//
#include <hip/hip_runtime.h>
#include <stdint.h>

typedef __attribute__((ext_vector_type(8))) short bf16x8;
typedef __attribute__((ext_vector_type(4))) short short4v;
typedef __attribute__((ext_vector_type(4))) float f32x4;

#define MFMA16(a, b, c) __builtin_amdgcn_mfma_f32_16x16x32_bf16((a), (b), (c), 0, 0, 0)

__device__ __forceinline__ float b2f(short s) {
  unsigned u = ((unsigned)(unsigned short)s) << 16;
  return __builtin_bit_cast(float, u);
}
__device__ __forceinline__ short f2b(float f) {
  unsigned u = __builtin_bit_cast(unsigned, f);
  u = (u + 0x7fffu + ((u >> 16) & 1u)) >> 16;
  return (short)u;
}

// async global->LDS, 16B per lane; lds dest is wave-uniform base (HW adds lane*16)
__device__ __forceinline__ void gl_lds16(const short* g, short* l) {
  __builtin_amdgcn_global_load_lds((const __attribute__((address_space(1))) void*)g,
                                   (__attribute__((address_space(3))) void*)l, 16, 0, 0);
}

// -------- convert f32 -> bf16 (8 elems/thread) --------
__global__ __launch_bounds__(256) void convert_kernel(const float* __restrict__ src,
                                                      short* __restrict__ dst, int n) {
  int i = (blockIdx.x * 256 + threadIdx.x) * 8;
  if (i >= n) return;
  f32x4 a = *(const f32x4*)(src + i);
  f32x4 b = *(const f32x4*)(src + i + 4);
  short4v o0, o1;
#pragma unroll
  for (int j = 0; j < 4; ++j) { o0[j] = f2b(a[j]); o1[j] = f2b(b[j]); }
  *(short4v*)(dst + i) = o0;
  *(short4v*)(dst + i + 4) = o1;
}

// -------- RMSNorm: f32 in, f32 gamma, bf16 out; one block per row of 1024 --------
__global__ __launch_bounds__(256) void rmsnorm_f32(const float* __restrict__ X,
                                                   const float* __restrict__ G,
                                                   short* __restrict__ O) {
  int row = blockIdx.x;
  int t = threadIdx.x;
  f32x4 v = *(const f32x4*)(X + (size_t)row * 1024 + t * 4);
  float ss = 0.f;
#pragma unroll
  for (int j = 0; j < 4; ++j) ss += v[j] * v[j];
#pragma unroll
  for (int d = 1; d < 64; d <<= 1) ss += __shfl_xor(ss, d, 64);
  __shared__ float red[4];
  if ((t & 63) == 0) red[t >> 6] = ss;
  __syncthreads();
  float tot = red[0] + red[1] + red[2] + red[3];
  float rinv = rsqrtf(tot * (1.0f / 1024.0f) + 1e-5f);
  f32x4 g = *(const f32x4*)(G + t * 4);
  short4v o;
#pragma unroll
  for (int j = 0; j < 4; ++j) o[j] = f2b(v[j] * rinv * g[j]);
  *(short4v*)(O + (size_t)row * 1024 + t * 4) = o;
}

// ---------------- GEMM 2-phase: 256 thr, 4 waves 2x2, 128x128, BK=32, dbuf LDS
// MODE 0: C = AB | MODE 3: QKV-split + fused RoPE
template <int MODE>
__global__ __launch_bounds__(256) void gemm_bt(const short* __restrict__ A,
                                               const short* __restrict__ Bt,
                                               const void* Res, void* C,
                                               void* C1, void* C2,
                                               int M, int N, int K) {
  __shared__ __attribute__((aligned(16))) short Alds[2][128 * 32];
  __shared__ __attribute__((aligned(16))) short Blds[2][128 * 32];
  int tid = threadIdx.x;
  int lane = tid & 63, w = tid >> 6;
  int wr = w >> 1, wc = w & 1;
  int l15 = lane & 15, lg = lane >> 4;
  int m0 = blockIdx.y * 128, n0 = blockIdx.x * 128;
  void* Cw = C;
  int ncol0 = n0;
  int seg = 0;
  if (MODE == 3) {
    seg = n0 >> 10;
    Cw = (seg == 0) ? C : (seg == 1) ? C1 : C2;
    ncol0 = n0 & 1023;
  }
  f32x4 acc[4][4] = {};
  int arow = tid >> 2, acol = (tid & 3) * 8;
  const short* Ap = A + (size_t)(m0 + arow) * K + acol;
  const short* Bp = Bt + (size_t)(n0 + arow) * K + acol;
  int wb = w * 512;
#define STAGE_BT(buf, k0s)                                   \
  {                                                          \
    gl_lds16(Ap + (k0s), &Alds[buf][0] + wb);                \
    gl_lds16(Ap + (size_t)64 * K + (k0s), &Alds[buf][0] + 2048 + wb); \
    gl_lds16(Bp + (k0s), &Blds[buf][0] + wb);                \
    gl_lds16(Bp + (size_t)64 * K + (k0s), &Blds[buf][0] + 2048 + wb); \
  }
  STAGE_BT(0, 0);
  __syncthreads();
  int cur = 0;
  for (int k0 = 0; k0 < K; k0 += 32) {
    if (k0 + 32 < K) STAGE_BT(cur ^ 1, k0 + 32);
    bf16x8 af[4], bfr[4];
#pragma unroll
    for (int i = 0; i < 4; ++i) {
      af[i] = *(const bf16x8*)(&Alds[cur][0] + (wr * 64 + i * 16 + l15) * 32 + lg * 8);
      bfr[i] = *(const bf16x8*)(&Blds[cur][0] + (wc * 64 + i * 16 + l15) * 32 + lg * 8);
    }
#pragma unroll
    for (int mi = 0; mi < 4; ++mi)
#pragma unroll
      for (int ni = 0; ni < 4; ++ni)
        acc[mi][ni] = MFMA16(af[mi], bfr[ni], acc[mi][ni]);
    __syncthreads();
    cur ^= 1;
  }
#undef STAGE_BT
#pragma unroll
  for (int mi = 0; mi < 4; ++mi) {
#pragma unroll
    for (int r = 0; r < 4; ++r) {
      int row = m0 + wr * 64 + mi * 16 + lg * 4 + r;
      size_t base = (size_t)row * N;
#pragma unroll
      for (int ni = 0; ni < 4; ++ni) {
        int col = ncol0 + wc * 64 + ni * 16 + l15;
        float v = acc[mi][ni][r];
        if (MODE == 3 && seg <= 1) {
          int pos = row & 2047;
          int ii = (col & 62) >> 1;
          float invf2 = exp2f(-(float)ii * 0.4152410118f) * 0.15915494309f;
          float rev = (float)pos * invf2;
          rev -= rintf(rev);
          float angr = rev * 6.28318530718f;
          float sn = __sinf(angr), cs = __cosf(angr);
          float partner = __shfl_xor(v, 1, 64);
          float t = partner * sn;
          v = v * cs + (((l15 & 1) == 0) ? -t : t);
        }
        ((short*)Cw)[base + col] = f2b(v);
      }
    }
  }
}

// ---------------- Fused W1+W3 GEMM (r15-proven, 717 TF): 256x256, BK=64, 2-phase.
__global__ __launch_bounds__(512) void gemm256_fused(const short* __restrict__ A,
                                                     const short* __restrict__ B1,
                                                     const short* __restrict__ B3,
                                                     short* __restrict__ C,
                                                     int M, int N, int K) {
  __shared__ __attribute__((aligned(16))) short Alds[2][256 * 64];
  __shared__ __attribute__((aligned(16))) short Blds[2][256 * 64];
  int tid = threadIdx.x;
  int lane = tid & 63, w = tid >> 6;
  int wr = w >> 2, wc = w & 3;  // 2 x 4 waves
  int l15 = lane & 15, lg = lane >> 4;
  int wg = blockIdx.x;
  int swz = (wg & 7) * 32 + (wg >> 3);
  int by = swz >> 4, bx = swz & 15;
  int m0 = by * 256, n0 = bx * 256;
  int rr = tid >> 3;
  int cs = (tid & 7) ^ (rr & 7);
  const short* Apt = A + (size_t)(m0 + rr) * K + cs * 8;
  const short* Bpt1 = B1 + (size_t)(n0 + rr) * K + cs * 8;
  const short* Bpt3 = B3 + (size_t)(n0 + rr) * K + cs * 8;
  int nt = K >> 6;
  f32x4 acc[8][4];
  short4v stash[8][4];
#define STAGE_A(buf, kt)                                                             \
  {                                                                                  \
    int ko = (kt) * 64;                                                              \
    _Pragma("unroll") for (int j = 0; j < 4; ++j)                                    \
        gl_lds16(Apt + (size_t)(j * 64) * K + ko, &Alds[buf][0] + j * 4096 + w * 512); \
  }
#define STAGE_B(buf, kt, Bp)                                                         \
  {                                                                                  \
    int ko = (kt) * 64;                                                              \
    _Pragma("unroll") for (int j = 0; j < 4; ++j)                                    \
        gl_lds16((Bp) + (size_t)(j * 64) * K + ko, &Blds[buf][0] + j * 4096 + w * 512); \
  }
#define KLOOP(Bp)                                                                    \
  {                                                                                  \
    STAGE_A(0, 0);                                                                   \
    STAGE_B(0, 0, Bp);                                                               \
    __syncthreads();                                                                 \
    int cur = 0;                                                                     \
    for (int kt = 0; kt < nt; ++kt) {                                                \
      if (kt + 1 < nt) { STAGE_A(cur ^ 1, kt + 1); STAGE_B(cur ^ 1, kt + 1, Bp); }   \
      _Pragma("unroll") for (int kk = 0; kk < 2; ++kk) {                             \
        bf16x8 af[8], bfr[4];                                                        \
        _Pragma("unroll") for (int i = 0; i < 8; ++i) {                              \
          int ra = wr * 128 + i * 16 + l15;                                          \
          int ua = (kk * 4 + lg) ^ (ra & 7);                                         \
          af[i] = *(const bf16x8*)(&Alds[cur][0] + ra * 64 + ua * 8);                \
        }                                                                            \
        _Pragma("unroll") for (int n = 0; n < 4; ++n) {                              \
          int rb = wc * 64 + n * 16 + l15;                                           \
          int ub = (kk * 4 + lg) ^ (rb & 7);                                         \
          bfr[n] = *(const bf16x8*)(&Blds[cur][0] + rb * 64 + ub * 8);               \
        }                                                                            \
        _Pragma("unroll") for (int i = 0; i < 8; ++i)                                \
        _Pragma("unroll") for (int n = 0; n < 4; ++n)                                \
            acc[i][n] = MFMA16(af[i], bfr[n], acc[i][n]);                            \
      }                                                                              \
      __syncthreads();                                                               \
      cur ^= 1;                                                                      \
    }                                                                                \
  }
  // ---- pass 1: W1 ----
#pragma unroll
  for (int i = 0; i < 8; ++i)
#pragma unroll
    for (int n = 0; n < 4; ++n) acc[i][n] = (f32x4){0.f, 0.f, 0.f, 0.f};
  KLOOP(Bpt1);
#pragma unroll
  for (int i = 0; i < 8; ++i)
#pragma unroll
    for (int n = 0; n < 4; ++n)
#pragma unroll
      for (int r = 0; r < 4; ++r) stash[i][n][r] = f2b(acc[i][n][r]);
  // ---- pass 2: W3 ----
#pragma unroll
  for (int i = 0; i < 8; ++i)
#pragma unroll
    for (int n = 0; n < 4; ++n) acc[i][n] = (f32x4){0.f, 0.f, 0.f, 0.f};
  KLOOP(Bpt3);
#undef KLOOP
#undef STAGE_A
#undef STAGE_B
  // ---- epilogue: C = silu(w1x) * w3x ----
#pragma unroll
  for (int i = 0; i < 8; ++i) {
#pragma unroll
    for (int r = 0; r < 4; ++r) {
      int row = m0 + wr * 128 + i * 16 + lg * 4 + r;
      size_t base = (size_t)row * N;
#pragma unroll
      for (int n = 0; n < 4; ++n) {
        int col = n0 + wc * 64 + n * 16 + l15;
        float w1v = b2f(stash[i][n][r]);
        float v = w1v / (1.f + __expf(-w1v)) * acc[i][n][r];
        C[base + col] = f2b(v);
      }
    }
  }
}

// ---------------- GEMM wide (r15-green): 4-buf counted-vmcnt, 512 thr, 8 waves
// 2x4, 128x128, BK=64, stage_rc swizzle, C = AB + Resf (f32 out). XCD m-chunk remap.
__global__ __launch_bounds__(512) void gemm_wide(const short* __restrict__ A,
                                                 const short* __restrict__ Bt,
                                                 const float* Res, float* C,
                                                 int M, int N, int K) {
  __shared__ __attribute__((aligned(16))) short Alds[4][128 * 64];
  __shared__ __attribute__((aligned(16))) short Blds[4][128 * 64];
  int tid = threadIdx.x;
  int lane = tid & 63, w = tid >> 6;
  int wr = w >> 2, wc = w & 3;
  int l15 = lane & 15, lg = lane >> 4;
  int lin = blockIdx.y * gridDim.x + blockIdx.x;
  int nx = gridDim.x;
  int xcd = lin & 7, idx = lin >> 3;
  int mpX = (gridDim.y >> 3);
  int m0 = (xcd * mpX + idx / nx) * 128;
  int n0 = (idx % nx) * 128;
  f32x4 acc[4][2] = {};
  int o0 = tid, o1 = 512 + tid;
  int r0 = o0 >> 3, cs0 = (o0 & 7) ^ (r0 & 7);
  int r1 = o1 >> 3, cs1 = (o1 & 7) ^ (r1 & 7);
  const short* Ap0 = A + (size_t)(m0 + r0) * K + cs0 * 8;
  const short* Ap1 = A + (size_t)(m0 + r1) * K + cs1 * 8;
  const short* Bp0 = Bt + (size_t)(n0 + r0) * K + cs0 * 8;
  const short* Bp1 = Bt + (size_t)(n0 + r1) * K + cs1 * 8;
  int wb = w * 512;
#define STG_W(buf, k0s)                                  \
  {                                                      \
    gl_lds16(Ap0 + (k0s), &Alds[buf][0] + wb);           \
    gl_lds16(Ap1 + (k0s), &Alds[buf][0] + 4096 + wb);    \
    gl_lds16(Bp0 + (k0s), &Blds[buf][0] + wb);           \
    gl_lds16(Bp1 + (k0s), &Blds[buf][0] + 4096 + wb);    \
  }
  int nk = K >> 6;
  STG_W(0, 0);
  STG_W(1, 64);
  asm volatile("s_waitcnt vmcnt(4)" ::: "memory");
  __builtin_amdgcn_s_barrier();
  asm volatile("" ::: "memory");
  for (int kt = 0; kt < nk; ++kt) {
    int buf = kt & 3;
    if (kt + 2 < nk) STG_W((kt + 2) & 3, (kt + 2) * 64);
    bf16x8 af[4][2], bfr[2][2];
#pragma unroll
    for (int i = 0; i < 4; ++i) {
      int ra = wr * 64 + i * 16 + l15;
#pragma unroll
      for (int kk = 0; kk < 2; ++kk) {
        int ua = (kk * 4 + lg) ^ (ra & 7);
        af[i][kk] = *(const bf16x8*)(&Alds[buf][0] + ra * 64 + ua * 8);
      }
    }
#pragma unroll
    for (int i = 0; i < 2; ++i) {
      int rb = wc * 32 + i * 16 + l15;
#pragma unroll
      for (int kk = 0; kk < 2; ++kk) {
        int ub = (kk * 4 + lg) ^ (rb & 7);
        bfr[i][kk] = *(const bf16x8*)(&Blds[buf][0] + rb * 64 + ub * 8);
      }
    }
#pragma unroll
    for (int kk = 0; kk < 2; ++kk)
#pragma unroll
      for (int mi = 0; mi < 4; ++mi)
#pragma unroll
        for (int ni = 0; ni < 2; ++ni)
          acc[mi][ni] = MFMA16(af[mi][kk], bfr[ni][kk], acc[mi][ni]);
    if (kt + 2 < nk) {
      asm volatile("s_waitcnt vmcnt(4)" ::: "memory");
    } else {
      asm volatile("s_waitcnt vmcnt(0)" ::: "memory");
    }
    __builtin_amdgcn_s_barrier();
    asm volatile("" ::: "memory");
  }
#undef STG_W
#pragma unroll
  for (int mi = 0; mi < 4; ++mi) {
#pragma unroll
    for (int r = 0; r < 4; ++r) {
      int row = m0 + wr * 64 + mi * 16 + lg * 4 + r;
      size_t base = (size_t)row * N;
#pragma unroll
      for (int ni = 0; ni < 2; ++ni) {
        int col = n0 + wc * 32 + ni * 16 + l15;
        C[base + col] = acc[mi][ni][r] + Res[base + col];
      }
    }
  }
}

// ---------------- V transpose: V[B*S][H*64] -> Vt[bh][64][2048] ----------------
__global__ __launch_bounds__(256) void vtranspose(const short* __restrict__ V,
                                                  short* __restrict__ Vt) {
  __shared__ short T[64 * 72];
  int bh = blockIdx.y;
  int s0 = blockIdx.x * 64;
  int t = threadIdx.x;
  int r = t >> 2, cq = t & 3;
  const short* src = V + (size_t)((bh >> 4) * 2048 + s0 + r) * 1024 + (bh & 15) * 64 + cq * 16;
  *(int4*)(T + r * 72 + cq * 16) = *(const int4*)src;
  *(int4*)(T + r * 72 + cq * 16 + 8) = *(const int4*)(src + 8);
  __syncthreads();
  int d = t >> 2, sq = t & 3;
  short* dst = Vt + (size_t)bh * 131072 + (size_t)d * 2048 + s0 + sq * 16;
#pragma unroll
  for (int q = 0; q < 4; ++q) {
    short4v o;
#pragma unroll
    for (int j = 0; j < 4; ++j) o[j] = T[(sq * 16 + q * 4 + j) * 72 + d];
    *(short4v*)(dst + q * 4) = o;
  }
}

// ---------------- Flash attention v6 (r10/r15-proven): LDS-staged K/V, 2-phase
// dbuf, stage_rc XOR swizzle. p = exp(s/8 - 24), l via ones-MFMA.
__global__ __launch_bounds__(256) void attn6(const short* __restrict__ Q,
                                             const short* __restrict__ K,
                                             const short* __restrict__ Vt,
                                             short* __restrict__ O) {
  __shared__ __attribute__((aligned(16))) short Klds[2][64 * 64];
  __shared__ __attribute__((aligned(16))) short Vlds[2][64 * 64];
  __shared__ __attribute__((aligned(16))) short Ptlds[4][64 * 20];
  int bx = blockIdx.x;
  int bh = bx & 31;
  int qt = 31 - (bx >> 5);
  int tid = threadIdx.x;
  int w = tid >> 6, lane = tid & 63;
  int l15 = lane & 15, lg = lane >> 4;
  int qbase = qt * 64 + w * 16;
  size_t rowbase = (size_t)(bh >> 4) * 2048 * 1024 + (size_t)(bh & 15) * 64;
  const short* vtb = Vt + (size_t)bh * 131072;
  const short* Kb0 = K + rowbase;
  bf16x8 qf[2];
  {
    const short* qp = Q + rowbase + (size_t)(qbase + l15) * 1024 + lg * 8;
    qf[0] = *(const bf16x8*)qp;
    qf[1] = *(const bf16x8*)(qp + 32);
  }
  bf16x8 ones;
#pragma unroll
  for (int j = 0; j < 8; ++j) ones[j] = (short)0x3F80;
  f32x4 oacc[4] = {};
  f32x4 lacc = {};
  int nchunk = qt + 1;
  short* pt = Ptlds[w];
  int i0 = w * 64 + lane;
  int r0 = i0 >> 3, c0 = i0 & 7, cs0 = c0 ^ (r0 & 7);
  int i1 = 256 + i0;
  int r1 = i1 >> 3, c1 = i1 & 7, cs1 = c1 ^ (r1 & 7);
#define STAGE_KV(buf, kt)                                                      \
  {                                                                            \
    int ks = (kt) * 64;                                                        \
    gl_lds16(Kb0 + (size_t)(ks + r0) * 1024 + cs0 * 8, &Klds[buf][0] + i0 * 8);\
    gl_lds16(Kb0 + (size_t)(ks + r1) * 1024 + cs1 * 8, &Klds[buf][0] + i1 * 8);\
    gl_lds16(vtb + (size_t)r0 * 2048 + ks + cs0 * 8, &Vlds[buf][0] + i0 * 8);  \
    gl_lds16(vtb + (size_t)r1 * 2048 + ks + cs1 * 8, &Vlds[buf][0] + i1 * 8);  \
  }
  STAGE_KV(0, 0);
  __syncthreads();
  int cur = 0;
  for (int kt = 0; kt < nchunk; ++kt) {
    if (kt + 1 < nchunk) STAGE_KV(cur ^ 1, kt + 1);
    int kstart = kt * 64;
    f32x4 s[4] = {};
#pragma unroll
    for (int g = 0; g < 4; ++g) {
      int krow = g * 16 + l15;
      bf16x8 k0 = *(const bf16x8*)(&Klds[cur][0] + krow * 64 + ((lg ^ (l15 & 7)) * 8));
      bf16x8 k1 = *(const bf16x8*)(&Klds[cur][0] + krow * 64 + (((4 + lg) ^ (l15 & 7)) * 8));
      s[g] = MFMA16(qf[0], k0, s[g]);
      s[g] = MFMA16(qf[1], k1, s[g]);
    }
#pragma unroll
    for (int g = 0; g < 4; ++g) {
      short4v pk;
#pragma unroll
      for (int r = 0; r < 4; ++r) {
        int qg = qbase + lg * 4 + r;
        int kg = kstart + g * 16 + l15;
        float v = __expf(s[g][r] * 0.125f - 24.f);
        pk[r] = f2b((kg > qg) ? 0.f : v);
      }
      *(short4v*)(pt + (g * 16 + l15) * 20 + lg * 4) = pk;
    }
    bf16x8 pa0, pa1;
#pragma unroll
    for (int j = 0; j < 8; ++j) {
      pa0[j] = pt[(lg * 8 + j) * 20 + l15];
      pa1[j] = pt[(32 + lg * 8 + j) * 20 + l15];
    }
#pragma unroll
    for (int t = 0; t < 4; ++t) {
      int drow = t * 16 + l15;
      bf16x8 vf0 = *(const bf16x8*)(&Vlds[cur][0] + drow * 64 + ((lg ^ (l15 & 7)) * 8));
      bf16x8 vf1 = *(const bf16x8*)(&Vlds[cur][0] + drow * 64 + (((4 + lg) ^ (l15 & 7)) * 8));
      oacc[t] = MFMA16(pa0, vf0, oacc[t]);
      oacc[t] = MFMA16(pa1, vf1, oacc[t]);
    }
    lacc = MFMA16(pa0, ones, lacc);
    lacc = MFMA16(pa1, ones, lacc);
    __syncthreads();
    cur ^= 1;
  }
#undef STAGE_KV
#pragma unroll
  for (int t = 0; t < 4; ++t) {
#pragma unroll
    for (int r = 0; r < 4; ++r) {
      int row = qbase + lg * 4 + r;
      float denom = fmaxf(lacc[r], 1e-30f);
      O[rowbase + (size_t)row * 1024 + t * 16 + l15] = f2b(oacc[t][r] / denom);
    }
  }
}

extern "C" void kernel_launch(void* const* d_in, const int* in_sizes, int n_in,
                              void* d_out, int out_size, void* d_ws, size_t ws_size,
                              hipStream_t stream) {
  const float* xf = (const float*)d_in[0];
  const float* G1f = (const float*)d_in[8];
  const float* G2f = (const float*)d_in[9];
  char* ws = (char*)d_ws;
  const size_t MB = 1048576;
  short* Wslot = (short*)(ws);            // [0,8): WOb early, then W1, then W2
  short* WOb   = (short*)(ws);
  short* Wcat  = (short*)(ws + 8 * MB);   // [8,14): fused QKV weights
  short* Vt    = (short*)(ws + 8 * MB);   // [8,16): V^T (after Wcat dead)
  short* h     = (short*)(ws + 16 * MB);  // [16,24)
  short* Qb    = (short*)(ws + 24 * MB);  // [24,32)
  short* Kb    = (short*)(ws + 32 * MB);  // [32,40)
  short* Vb    = (short*)(ws + 40 * MB);  // [40,48)
  short* att   = (short*)(ws + 48 * MB);  // [48,56)
  short* W3b   = (short*)(ws + 56 * MB);  // [56,64): W3 bf16
  short* w1x   = Qb;                      // [24,56): Q/K/V/att dead by FFN time
  float* x1f   = (float*)d_out;
  float* outf  = (float*)d_out;

  dim3 blk(256);
  convert_kernel<<<512, blk, 0, stream>>>((const float*)d_in[1], Wcat, 1048576);
  convert_kernel<<<512, blk, 0, stream>>>((const float*)d_in[2], Wcat + 1048576, 1048576);
  convert_kernel<<<512, blk, 0, stream>>>((const float*)d_in[3], Wcat + 2097152, 1048576);
  convert_kernel<<<512, blk, 0, stream>>>((const float*)d_in[4], WOb, 1048576);

  rmsnorm_f32<<<4096, blk, 0, stream>>>(xf, G1f, h);
  dim3 gqkv(24, 32);
  gemm_bt<3><<<gqkv, blk, 0, stream>>>(h, Wcat, nullptr, Qb, Kb, Vb, 4096, 1024, 1024);
  dim3 gvt(32, 32);
  vtranspose<<<gvt, blk, 0, stream>>>(Vb, Vt);
  attn6<<<1024, blk, 0, stream>>>(Qb, Kb, Vt, att);
  dim3 g1(8, 32);
  gemm_wide<<<g1, dim3(512), 0, stream>>>(att, WOb, xf, x1f, 4096, 1024, 1024);
  rmsnorm_f32<<<4096, blk, 0, stream>>>(x1f, G2f, h);
  convert_kernel<<<2048, blk, 0, stream>>>((const float*)d_in[5], Wslot, 4194304);
  convert_kernel<<<2048, blk, 0, stream>>>((const float*)d_in[7], W3b, 4194304);
  gemm256_fused<<<256, dim3(512), 0, stream>>>(h, Wslot, W3b, w1x, 4096, 4096, 1024);
  convert_kernel<<<2048, blk, 0, stream>>>((const float*)d_in[6], Wslot, 4194304);
  gemm_wide<<<g1, dim3(512), 0, stream>>>(w1x, Wslot, x1f, outf, 4096, 1024, 4096);
}

// Round 20
// 290.285 us; speedup vs baseline: 1.8097x; 1.0436x over previous
//
#include <hip/hip_runtime.h>
#include <stdint.h>

typedef __attribute__((ext_vector_type(8))) short bf16x8;
typedef __attribute__((ext_vector_type(4))) short short4v;
typedef __attribute__((ext_vector_type(4))) float f32x4;

#define MFMA16(a, b, c) __builtin_amdgcn_mfma_f32_16x16x32_bf16((a), (b), (c), 0, 0, 0)

__device__ __forceinline__ float b2f(short s) {
  unsigned u = ((unsigned)(unsigned short)s) << 16;
  return __builtin_bit_cast(float, u);
}
__device__ __forceinline__ short f2b(float f) {
  unsigned u = __builtin_bit_cast(unsigned, f);
  u = (u + 0x7fffu + ((u >> 16) & 1u)) >> 16;
  return (short)u;
}

// async global->LDS, 16B per lane; lds dest is wave-uniform base (HW adds lane*16)
__device__ __forceinline__ void gl_lds16(const short* g, short* l) {
  __builtin_amdgcn_global_load_lds((const __attribute__((address_space(1))) void*)g,
                                   (__attribute__((address_space(3))) void*)l, 16, 0, 0);
}

// -------- convert f32 -> bf16 (8 elems/thread) --------
__global__ __launch_bounds__(256) void convert_kernel(const float* __restrict__ src,
                                                      short* __restrict__ dst, int n) {
  int i = (blockIdx.x * 256 + threadIdx.x) * 8;
  if (i >= n) return;
  f32x4 a = *(const f32x4*)(src + i);
  f32x4 b = *(const f32x4*)(src + i + 4);
  short4v o0, o1;
#pragma unroll
  for (int j = 0; j < 4; ++j) { o0[j] = f2b(a[j]); o1[j] = f2b(b[j]); }
  *(short4v*)(dst + i) = o0;
  *(short4v*)(dst + i + 4) = o1;
}

// -------- RMSNorm: f32 in, f32 gamma, bf16 out; one block per row of 1024 --------
__global__ __launch_bounds__(256) void rmsnorm_f32(const float* __restrict__ X,
                                                   const float* __restrict__ G,
                                                   short* __restrict__ O) {
  int row = blockIdx.x;
  int t = threadIdx.x;
  f32x4 v = *(const f32x4*)(X + (size_t)row * 1024 + t * 4);
  float ss = 0.f;
#pragma unroll
  for (int j = 0; j < 4; ++j) ss += v[j] * v[j];
#pragma unroll
  for (int d = 1; d < 64; d <<= 1) ss += __shfl_xor(ss, d, 64);
  __shared__ float red[4];
  if ((t & 63) == 0) red[t >> 6] = ss;
  __syncthreads();
  float tot = red[0] + red[1] + red[2] + red[3];
  float rinv = rsqrtf(tot * (1.0f / 1024.0f) + 1e-5f);
  f32x4 g = *(const f32x4*)(G + t * 4);
  short4v o;
#pragma unroll
  for (int j = 0; j < 4; ++j) o[j] = f2b(v[j] * rinv * g[j]);
  *(short4v*)(O + (size_t)row * 1024 + t * 4) = o;
}

// ---------------- GEMM 2-phase: 256 thr, 4 waves 2x2, 128x128, BK=32, dbuf LDS
// MODE 0: C = AB | MODE 3: QKV-split + fused RoPE
template <int MODE>
__global__ __launch_bounds__(256) void gemm_bt(const short* __restrict__ A,
                                               const short* __restrict__ Bt,
                                               const void* Res, void* C,
                                               void* C1, void* C2,
                                               int M, int N, int K) {
  __shared__ __attribute__((aligned(16))) short Alds[2][128 * 32];
  __shared__ __attribute__((aligned(16))) short Blds[2][128 * 32];
  int tid = threadIdx.x;
  int lane = tid & 63, w = tid >> 6;
  int wr = w >> 1, wc = w & 1;
  int l15 = lane & 15, lg = lane >> 4;
  int m0 = blockIdx.y * 128, n0 = blockIdx.x * 128;
  void* Cw = C;
  int ncol0 = n0;
  int seg = 0;
  if (MODE == 3) {
    seg = n0 >> 10;
    Cw = (seg == 0) ? C : (seg == 1) ? C1 : C2;
    ncol0 = n0 & 1023;
  }
  f32x4 acc[4][4] = {};
  int arow = tid >> 2, acol = (tid & 3) * 8;
  const short* Ap = A + (size_t)(m0 + arow) * K + acol;
  const short* Bp = Bt + (size_t)(n0 + arow) * K + acol;
  int wb = w * 512;
#define STAGE_BT(buf, k0s)                                   \
  {                                                          \
    gl_lds16(Ap + (k0s), &Alds[buf][0] + wb);                \
    gl_lds16(Ap + (size_t)64 * K + (k0s), &Alds[buf][0] + 2048 + wb); \
    gl_lds16(Bp + (k0s), &Blds[buf][0] + wb);                \
    gl_lds16(Bp + (size_t)64 * K + (k0s), &Blds[buf][0] + 2048 + wb); \
  }
  STAGE_BT(0, 0);
  __syncthreads();
  int cur = 0;
  for (int k0 = 0; k0 < K; k0 += 32) {
    if (k0 + 32 < K) STAGE_BT(cur ^ 1, k0 + 32);
    bf16x8 af[4], bfr[4];
#pragma unroll
    for (int i = 0; i < 4; ++i) {
      af[i] = *(const bf16x8*)(&Alds[cur][0] + (wr * 64 + i * 16 + l15) * 32 + lg * 8);
      bfr[i] = *(const bf16x8*)(&Blds[cur][0] + (wc * 64 + i * 16 + l15) * 32 + lg * 8);
    }
#pragma unroll
    for (int mi = 0; mi < 4; ++mi)
#pragma unroll
      for (int ni = 0; ni < 4; ++ni)
        acc[mi][ni] = MFMA16(af[mi], bfr[ni], acc[mi][ni]);
    __syncthreads();
    cur ^= 1;
  }
#undef STAGE_BT
#pragma unroll
  for (int mi = 0; mi < 4; ++mi) {
#pragma unroll
    for (int r = 0; r < 4; ++r) {
      int row = m0 + wr * 64 + mi * 16 + lg * 4 + r;
      size_t base = (size_t)row * N;
#pragma unroll
      for (int ni = 0; ni < 4; ++ni) {
        int col = ncol0 + wc * 64 + ni * 16 + l15;
        float v = acc[mi][ni][r];
        if (MODE == 3 && seg <= 1) {
          int pos = row & 2047;
          int ii = (col & 62) >> 1;
          float invf2 = exp2f(-(float)ii * 0.4152410118f) * 0.15915494309f;
          float rev = (float)pos * invf2;
          rev -= rintf(rev);
          float angr = rev * 6.28318530718f;
          float sn = __sinf(angr), cs = __cosf(angr);
          float partner = __shfl_xor(v, 1, 64);
          float t = partner * sn;
          v = v * cs + (((l15 & 1) == 0) ? -t : t);
        }
        ((short*)Cw)[base + col] = f2b(v);
      }
    }
  }
}

// ---------------- Fused W1+W3 GEMM (r15-proven, 717 TF): 256x256, BK=64, 2-phase.
__global__ __launch_bounds__(512) void gemm256_fused(const short* __restrict__ A,
                                                     const short* __restrict__ B1,
                                                     const short* __restrict__ B3,
                                                     short* __restrict__ C,
                                                     int M, int N, int K) {
  __shared__ __attribute__((aligned(16))) short Alds[2][256 * 64];
  __shared__ __attribute__((aligned(16))) short Blds[2][256 * 64];
  int tid = threadIdx.x;
  int lane = tid & 63, w = tid >> 6;
  int wr = w >> 2, wc = w & 3;  // 2 x 4 waves
  int l15 = lane & 15, lg = lane >> 4;
  int wg = blockIdx.x;
  int swz = (wg & 7) * 32 + (wg >> 3);
  int by = swz >> 4, bx = swz & 15;
  int m0 = by * 256, n0 = bx * 256;
  int rr = tid >> 3;
  int cs = (tid & 7) ^ (rr & 7);
  const short* Apt = A + (size_t)(m0 + rr) * K + cs * 8;
  const short* Bpt1 = B1 + (size_t)(n0 + rr) * K + cs * 8;
  const short* Bpt3 = B3 + (size_t)(n0 + rr) * K + cs * 8;
  int nt = K >> 6;
  f32x4 acc[8][4];
  short4v stash[8][4];
#define STAGE_A(buf, kt)                                                             \
  {                                                                                  \
    int ko = (kt) * 64;                                                              \
    _Pragma("unroll") for (int j = 0; j < 4; ++j)                                    \
        gl_lds16(Apt + (size_t)(j * 64) * K + ko, &Alds[buf][0] + j * 4096 + w * 512); \
  }
#define STAGE_B(buf, kt, Bp)                                                         \
  {                                                                                  \
    int ko = (kt) * 64;                                                              \
    _Pragma("unroll") for (int j = 0; j < 4; ++j)                                    \
        gl_lds16((Bp) + (size_t)(j * 64) * K + ko, &Blds[buf][0] + j * 4096 + w * 512); \
  }
#define KLOOP(Bp)                                                                    \
  {                                                                                  \
    STAGE_A(0, 0);                                                                   \
    STAGE_B(0, 0, Bp);                                                               \
    __syncthreads();                                                                 \
    int cur = 0;                                                                     \
    for (int kt = 0; kt < nt; ++kt) {                                                \
      if (kt + 1 < nt) { STAGE_A(cur ^ 1, kt + 1); STAGE_B(cur ^ 1, kt + 1, Bp); }   \
      _Pragma("unroll") for (int kk = 0; kk < 2; ++kk) {                             \
        bf16x8 af[8], bfr[4];                                                        \
        _Pragma("unroll") for (int i = 0; i < 8; ++i) {                              \
          int ra = wr * 128 + i * 16 + l15;                                          \
          int ua = (kk * 4 + lg) ^ (ra & 7);                                         \
          af[i] = *(const bf16x8*)(&Alds[cur][0] + ra * 64 + ua * 8);                \
        }                                                                            \
        _Pragma("unroll") for (int n = 0; n < 4; ++n) {                              \
          int rb = wc * 64 + n * 16 + l15;                                           \
          int ub = (kk * 4 + lg) ^ (rb & 7);                                         \
          bfr[n] = *(const bf16x8*)(&Blds[cur][0] + rb * 64 + ub * 8);               \
        }                                                                            \
        _Pragma("unroll") for (int i = 0; i < 8; ++i)                                \
        _Pragma("unroll") for (int n = 0; n < 4; ++n)                                \
            acc[i][n] = MFMA16(af[i], bfr[n], acc[i][n]);                            \
      }                                                                              \
      __syncthreads();                                                               \
      cur ^= 1;                                                                      \
    }                                                                                \
  }
  // ---- pass 1: W1 ----
#pragma unroll
  for (int i = 0; i < 8; ++i)
#pragma unroll
    for (int n = 0; n < 4; ++n) acc[i][n] = (f32x4){0.f, 0.f, 0.f, 0.f};
  KLOOP(Bpt1);
#pragma unroll
  for (int i = 0; i < 8; ++i)
#pragma unroll
    for (int n = 0; n < 4; ++n)
#pragma unroll
      for (int r = 0; r < 4; ++r) stash[i][n][r] = f2b(acc[i][n][r]);
  // ---- pass 2: W3 ----
#pragma unroll
  for (int i = 0; i < 8; ++i)
#pragma unroll
    for (int n = 0; n < 4; ++n) acc[i][n] = (f32x4){0.f, 0.f, 0.f, 0.f};
  KLOOP(Bpt3);
#undef KLOOP
#undef STAGE_A
#undef STAGE_B
  // ---- epilogue: C = silu(w1x) * w3x ----
#pragma unroll
  for (int i = 0; i < 8; ++i) {
#pragma unroll
    for (int r = 0; r < 4; ++r) {
      int row = m0 + wr * 128 + i * 16 + lg * 4 + r;
      size_t base = (size_t)row * N;
#pragma unroll
      for (int n = 0; n < 4; ++n) {
        int col = n0 + wc * 64 + n * 16 + l15;
        float w1v = b2f(stash[i][n][r]);
        float v = w1v / (1.f + __expf(-w1v)) * acc[i][n][r];
        C[base + col] = f2b(v);
      }
    }
  }
}

// ---------------- GEMM wide, BK=128 2-phase: 512 thr, 8 waves 2x4, 128x128 tile,
// 32 MFMA/iter, stage_rc swizzle (16 units/row: LDS(row,c) holds global unit
// c^(row&7); read ua=(kk*4+lg)^(row&7)), C = AB + Resf (f32 out). XCD m-chunk remap.
__global__ __launch_bounds__(512) void gemm_wide(const short* __restrict__ A,
                                                 const short* __restrict__ Bt,
                                                 const float* Res, float* C,
                                                 int M, int N, int K) {
  __shared__ __attribute__((aligned(16))) short Alds[2][128 * 128];
  __shared__ __attribute__((aligned(16))) short Blds[2][128 * 128];
  int tid = threadIdx.x;
  int lane = tid & 63, w = tid >> 6;
  int wr = w >> 2, wc = w & 3;
  int l15 = lane & 15, lg = lane >> 4;
  int lin = blockIdx.y * gridDim.x + blockIdx.x;
  int nx = gridDim.x;
  int xcd = lin & 7, idx = lin >> 3;
  int mpX = (gridDim.y >> 3);
  int m0 = (xcd * mpX + idx / nx) * 128;
  int n0 = (idx % nx) * 128;
  f32x4 acc[4][2] = {};
  // staging: 2048 16B-units/tile; thread covers o = j*512+tid, j=0..3.
  // row = j*32 + (tid>>4), c = tid&15, src unit csw = c ^ (row&7)  (j*32%8==0)
  int rloc = tid >> 4;
  int csw = (tid & 15) ^ (rloc & 7);
  int wso = w * 512;
#define STG_W(buf, k0s)                                                              \
  {                                                                                  \
    _Pragma("unroll") for (int j = 0; j < 4; ++j) {                                  \
      gl_lds16(A + (size_t)(m0 + j * 32 + rloc) * K + csw * 8 + (k0s),               \
               &Alds[buf][0] + j * 4096 + wso);                                      \
      gl_lds16(Bt + (size_t)(n0 + j * 32 + rloc) * K + csw * 8 + (k0s),              \
               &Blds[buf][0] + j * 4096 + wso);                                      \
    }                                                                                \
  }
  int nk = K >> 7;
  STG_W(0, 0);
  __syncthreads();
  int cur = 0;
  for (int kt = 0; kt < nk; ++kt) {
    if (kt + 1 < nk) STG_W(cur ^ 1, (kt + 1) * 128);
#pragma unroll
    for (int kk = 0; kk < 4; ++kk) {
      bf16x8 af[4], bfr[2];
#pragma unroll
      for (int i = 0; i < 4; ++i) {
        int ra = wr * 64 + i * 16 + l15;
        int ua = (kk * 4 + lg) ^ (ra & 7);
        af[i] = *(const bf16x8*)(&Alds[cur][0] + ra * 128 + ua * 8);
      }
#pragma unroll
      for (int i = 0; i < 2; ++i) {
        int rb = wc * 32 + i * 16 + l15;
        int ub = (kk * 4 + lg) ^ (rb & 7);
        bfr[i] = *(const bf16x8*)(&Blds[cur][0] + rb * 128 + ub * 8);
      }
#pragma unroll
      for (int mi = 0; mi < 4; ++mi)
#pragma unroll
        for (int ni = 0; ni < 2; ++ni)
          acc[mi][ni] = MFMA16(af[mi], bfr[ni], acc[mi][ni]);
    }
    __syncthreads();
    cur ^= 1;
  }
#undef STG_W
#pragma unroll
  for (int mi = 0; mi < 4; ++mi) {
#pragma unroll
    for (int r = 0; r < 4; ++r) {
      int row = m0 + wr * 64 + mi * 16 + lg * 4 + r;
      size_t base = (size_t)row * N;
#pragma unroll
      for (int ni = 0; ni < 2; ++ni) {
        int col = n0 + wc * 32 + ni * 16 + l15;
        C[base + col] = acc[mi][ni][r] + Res[base + col];
      }
    }
  }
}

// ---------------- V transpose: V[B*S][H*64] -> Vt[bh][64][2048] ----------------
__global__ __launch_bounds__(256) void vtranspose(const short* __restrict__ V,
                                                  short* __restrict__ Vt) {
  __shared__ short T[64 * 72];
  int bh = blockIdx.y;
  int s0 = blockIdx.x * 64;
  int t = threadIdx.x;
  int r = t >> 2, cq = t & 3;
  const short* src = V + (size_t)((bh >> 4) * 2048 + s0 + r) * 1024 + (bh & 15) * 64 + cq * 16;
  *(int4*)(T + r * 72 + cq * 16) = *(const int4*)src;
  *(int4*)(T + r * 72 + cq * 16 + 8) = *(const int4*)(src + 8);
  __syncthreads();
  int d = t >> 2, sq = t & 3;
  short* dst = Vt + (size_t)bh * 131072 + (size_t)d * 2048 + s0 + sq * 16;
#pragma unroll
  for (int q = 0; q < 4; ++q) {
    short4v o;
#pragma unroll
    for (int j = 0; j < 4; ++j) o[j] = T[(sq * 16 + q * 4 + j) * 72 + d];
    *(short4v*)(dst + q * 4) = o;
  }
}

// ---------------- Flash attention v6 (r10/r15-proven): LDS-staged K/V, 2-phase
// dbuf, stage_rc XOR swizzle. p = exp(s/8 - 24), l via ones-MFMA.
__global__ __launch_bounds__(256) void attn6(const short* __restrict__ Q,
                                             const short* __restrict__ K,
                                             const short* __restrict__ Vt,
                                             short* __restrict__ O) {
  __shared__ __attribute__((aligned(16))) short Klds[2][64 * 64];
  __shared__ __attribute__((aligned(16))) short Vlds[2][64 * 64];
  __shared__ __attribute__((aligned(16))) short Ptlds[4][64 * 20];
  int bx = blockIdx.x;
  int bh = bx & 31;
  int qt = 31 - (bx >> 5);
  int tid = threadIdx.x;
  int w = tid >> 6, lane = tid & 63;
  int l15 = lane & 15, lg = lane >> 4;
  int qbase = qt * 64 + w * 16;
  size_t rowbase = (size_t)(bh >> 4) * 2048 * 1024 + (size_t)(bh & 15) * 64;
  const short* vtb = Vt + (size_t)bh * 131072;
  const short* Kb0 = K + rowbase;
  bf16x8 qf[2];
  {
    const short* qp = Q + rowbase + (size_t)(qbase + l15) * 1024 + lg * 8;
    qf[0] = *(const bf16x8*)qp;
    qf[1] = *(const bf16x8*)(qp + 32);
  }
  bf16x8 ones;
#pragma unroll
  for (int j = 0; j < 8; ++j) ones[j] = (short)0x3F80;
  f32x4 oacc[4] = {};
  f32x4 lacc = {};
  int nchunk = qt + 1;
  short* pt = Ptlds[w];
  int i0 = w * 64 + lane;
  int r0 = i0 >> 3, c0 = i0 & 7, cs0 = c0 ^ (r0 & 7);
  int i1 = 256 + i0;
  int r1 = i1 >> 3, c1 = i1 & 7, cs1 = c1 ^ (r1 & 7);
#define STAGE_KV(buf, kt)                                                      \
  {                                                                            \
    int ks = (kt) * 64;                                                        \
    gl_lds16(Kb0 + (size_t)(ks + r0) * 1024 + cs0 * 8, &Klds[buf][0] + i0 * 8);\
    gl_lds16(Kb0 + (size_t)(ks + r1) * 1024 + cs1 * 8, &Klds[buf][0] + i1 * 8);\
    gl_lds16(vtb + (size_t)r0 * 2048 + ks + cs0 * 8, &Vlds[buf][0] + i0 * 8);  \
    gl_lds16(vtb + (size_t)r1 * 2048 + ks + cs1 * 8, &Vlds[buf][0] + i1 * 8);  \
  }
  STAGE_KV(0, 0);
  __syncthreads();
  int cur = 0;
  for (int kt = 0; kt < nchunk; ++kt) {
    if (kt + 1 < nchunk) STAGE_KV(cur ^ 1, kt + 1);
    int kstart = kt * 64;
    f32x4 s[4] = {};
#pragma unroll
    for (int g = 0; g < 4; ++g) {
      int krow = g * 16 + l15;
      bf16x8 k0 = *(const bf16x8*)(&Klds[cur][0] + krow * 64 + ((lg ^ (l15 & 7)) * 8));
      bf16x8 k1 = *(const bf16x8*)(&Klds[cur][0] + krow * 64 + (((4 + lg) ^ (l15 & 7)) * 8));
      s[g] = MFMA16(qf[0], k0, s[g]);
      s[g] = MFMA16(qf[1], k1, s[g]);
    }
#pragma unroll
    for (int g = 0; g < 4; ++g) {
      short4v pk;
#pragma unroll
      for (int r = 0; r < 4; ++r) {
        int qg = qbase + lg * 4 + r;
        int kg = kstart + g * 16 + l15;
        float v = __expf(s[g][r] * 0.125f - 24.f);
        pk[r] = f2b((kg > qg) ? 0.f : v);
      }
      *(short4v*)(pt + (g * 16 + l15) * 20 + lg * 4) = pk;
    }
    bf16x8 pa0, pa1;
#pragma unroll
    for (int j = 0; j < 8; ++j) {
      pa0[j] = pt[(lg * 8 + j) * 20 + l15];
      pa1[j] = pt[(32 + lg * 8 + j) * 20 + l15];
    }
#pragma unroll
    for (int t = 0; t < 4; ++t) {
      int drow = t * 16 + l15;
      bf16x8 vf0 = *(const bf16x8*)(&Vlds[cur][0] + drow * 64 + ((lg ^ (l15 & 7)) * 8));
      bf16x8 vf1 = *(const bf16x8*)(&Vlds[cur][0] + drow * 64 + (((4 + lg) ^ (l15 & 7)) * 8));
      oacc[t] = MFMA16(pa0, vf0, oacc[t]);
      oacc[t] = MFMA16(pa1, vf1, oacc[t]);
    }
    lacc = MFMA16(pa0, ones, lacc);
    lacc = MFMA16(pa1, ones, lacc);
    __syncthreads();
    cur ^= 1;
  }
#undef STAGE_KV
#pragma unroll
  for (int t = 0; t < 4; ++t) {
#pragma unroll
    for (int r = 0; r < 4; ++r) {
      int row = qbase + lg * 4 + r;
      float denom = fmaxf(lacc[r], 1e-30f);
      O[rowbase + (size_t)row * 1024 + t * 16 + l15] = f2b(oacc[t][r] / denom);
    }
  }
}

extern "C" void kernel_launch(void* const* d_in, const int* in_sizes, int n_in,
                              void* d_out, int out_size, void* d_ws, size_t ws_size,
                              hipStream_t stream) {
  const float* xf = (const float*)d_in[0];
  const float* G1f = (const float*)d_in[8];
  const float* G2f = (const float*)d_in[9];
  char* ws = (char*)d_ws;
  const size_t MB = 1048576;
  short* Wslot = (short*)(ws);            // [0,8): WOb early, then W1, then W2
  short* WOb   = (short*)(ws);
  short* Wcat  = (short*)(ws + 8 * MB);   // [8,14): fused QKV weights
  short* Vt    = (short*)(ws + 8 * MB);   // [8,16): V^T (after Wcat dead)
  short* h     = (short*)(ws + 16 * MB);  // [16,24)
  short* Qb    = (short*)(ws + 24 * MB);  // [24,32)
  short* Kb    = (short*)(ws + 32 * MB);  // [32,40)
  short* Vb    = (short*)(ws + 40 * MB);  // [40,48)
  short* att   = (short*)(ws + 48 * MB);  // [48,56)
  short* W3b   = (short*)(ws + 56 * MB);  // [56,64): W3 bf16
  short* w1x   = Qb;                      // [24,56): Q/K/V/att dead by FFN time
  float* x1f   = (float*)d_out;
  float* outf  = (float*)d_out;

  dim3 blk(256);
  convert_kernel<<<512, blk, 0, stream>>>((const float*)d_in[1], Wcat, 1048576);
  convert_kernel<<<512, blk, 0, stream>>>((const float*)d_in[2], Wcat + 1048576, 1048576);
  convert_kernel<<<512, blk, 0, stream>>>((const float*)d_in[3], Wcat + 2097152, 1048576);
  convert_kernel<<<512, blk, 0, stream>>>((const float*)d_in[4], WOb, 1048576);

  rmsnorm_f32<<<4096, blk, 0, stream>>>(xf, G1f, h);
  dim3 gqkv(24, 32);
  gemm_bt<3><<<gqkv, blk, 0, stream>>>(h, Wcat, nullptr, Qb, Kb, Vb, 4096, 1024, 1024);
  dim3 gvt(32, 32);
  vtranspose<<<gvt, blk, 0, stream>>>(Vb, Vt);
  attn6<<<1024, blk, 0, stream>>>(Qb, Kb, Vt, att);
  dim3 g1(8, 32);
  gemm_wide<<<g1, dim3(512), 0, stream>>>(att, WOb, xf, x1f, 4096, 1024, 1024);
  rmsnorm_f32<<<4096, blk, 0, stream>>>(x1f, G2f, h);
  convert_kernel<<<2048, blk, 0, stream>>>((const float*)d_in[5], Wslot, 4194304);
  convert_kernel<<<2048, blk, 0, stream>>>((const float*)d_in[7], W3b, 4194304);
  gemm256_fused<<<256, dim3(512), 0, stream>>>(h, Wslot, W3b, w1x, 4096, 4096, 1024);
  convert_kernel<<<2048, blk, 0, stream>>>((const float*)d_in[6], Wslot, 4194304);
  gemm_wide<<<g1, dim3(512), 0, stream>>>(w1x, Wslot, x1f, outf, 4096, 1024, 4096);
}

// Round 21
// 283.007 us; speedup vs baseline: 1.8562x; 1.0257x over previous
//
#include <hip/hip_runtime.h>
#include <stdint.h>

typedef __attribute__((ext_vector_type(8))) short bf16x8;
typedef __attribute__((ext_vector_type(4))) short short4v;
typedef __attribute__((ext_vector_type(4))) float f32x4;

#define MFMA16(a, b, c) __builtin_amdgcn_mfma_f32_16x16x32_bf16((a), (b), (c), 0, 0, 0)

__device__ __forceinline__ float b2f(short s) {
  unsigned u = ((unsigned)(unsigned short)s) << 16;
  return __builtin_bit_cast(float, u);
}
__device__ __forceinline__ short f2b(float f) {
  unsigned u = __builtin_bit_cast(unsigned, f);
  u = (u + 0x7fffu + ((u >> 16) & 1u)) >> 16;
  return (short)u;
}

// async global->LDS, 16B per lane; lds dest is wave-uniform base (HW adds lane*16)
__device__ __forceinline__ void gl_lds16(const short* g, short* l) {
  __builtin_amdgcn_global_load_lds((const __attribute__((address_space(1))) void*)g,
                                   (__attribute__((address_space(3))) void*)l, 16, 0, 0);
}

__device__ __forceinline__ void conv8(const float* src, short* dst, int i) {
  f32x4 a = *(const f32x4*)(src + i);
  f32x4 b = *(const f32x4*)(src + i + 4);
  short4v o0, o1;
#pragma unroll
  for (int j = 0; j < 4; ++j) { o0[j] = f2b(a[j]); o1[j] = f2b(b[j]); }
  *(short4v*)(dst + i) = o0;
  *(short4v*)(dst + i + 4) = o1;
}

// -------- convert f32 -> bf16 (8 elems/thread) --------
__global__ __launch_bounds__(256) void convert_kernel(const float* __restrict__ src,
                                                      short* __restrict__ dst, int n) {
  int i = (blockIdx.x * 256 + threadIdx.x) * 8;
  if (i >= n) return;
  conv8(src, dst, i);
}

// -------- batched convert: 4 x 1M-elem segments (512 blocks each) --------
__global__ __launch_bounds__(256) void convert4(const float* __restrict__ s0,
                                                const float* __restrict__ s1,
                                                const float* __restrict__ s2,
                                                const float* __restrict__ s3,
                                                short* __restrict__ d0,
                                                short* __restrict__ d1,
                                                short* __restrict__ d2,
                                                short* __restrict__ d3) {
  int b = blockIdx.x;
  int seg = b >> 9;
  const float* src = (seg == 0) ? s0 : (seg == 1) ? s1 : (seg == 2) ? s2 : s3;
  short* dst = (seg == 0) ? d0 : (seg == 1) ? d1 : (seg == 2) ? d2 : d3;
  int i = ((b & 511) * 256 + threadIdx.x) * 8;
  conv8(src, dst, i);
}

// -------- batched convert: 2 x 4M-elem segments (2048 blocks each) --------
__global__ __launch_bounds__(256) void convert2(const float* __restrict__ s0,
                                                const float* __restrict__ s1,
                                                short* __restrict__ d0,
                                                short* __restrict__ d1) {
  int b = blockIdx.x;
  int seg = b >> 11;
  const float* src = (seg == 0) ? s0 : s1;
  short* dst = (seg == 0) ? d0 : d1;
  int i = ((b & 2047) * 256 + threadIdx.x) * 8;
  conv8(src, dst, i);
}

// -------- RMSNorm: f32 in, f32 gamma, bf16 out; one block per row of 1024 --------
__global__ __launch_bounds__(256) void rmsnorm_f32(const float* __restrict__ X,
                                                   const float* __restrict__ G,
                                                   short* __restrict__ O) {
  int row = blockIdx.x;
  int t = threadIdx.x;
  f32x4 v = *(const f32x4*)(X + (size_t)row * 1024 + t * 4);
  float ss = 0.f;
#pragma unroll
  for (int j = 0; j < 4; ++j) ss += v[j] * v[j];
#pragma unroll
  for (int d = 1; d < 64; d <<= 1) ss += __shfl_xor(ss, d, 64);
  __shared__ float red[4];
  if ((t & 63) == 0) red[t >> 6] = ss;
  __syncthreads();
  float tot = red[0] + red[1] + red[2] + red[3];
  float rinv = rsqrtf(tot * (1.0f / 1024.0f) + 1e-5f);
  f32x4 g = *(const f32x4*)(G + t * 4);
  short4v o;
#pragma unroll
  for (int j = 0; j < 4; ++j) o[j] = f2b(v[j] * rinv * g[j]);
  *(short4v*)(O + (size_t)row * 1024 + t * 4) = o;
}

// ---------------- GEMM 2-phase: 256 thr, 4 waves 2x2, 128x128, BK=32, dbuf LDS
// MODE 0: C = AB | MODE 3: QKV-split + fused RoPE
template <int MODE>
__global__ __launch_bounds__(256) void gemm_bt(const short* __restrict__ A,
                                               const short* __restrict__ Bt,
                                               const void* Res, void* C,
                                               void* C1, void* C2,
                                               int M, int N, int K) {
  __shared__ __attribute__((aligned(16))) short Alds[2][128 * 32];
  __shared__ __attribute__((aligned(16))) short Blds[2][128 * 32];
  int tid = threadIdx.x;
  int lane = tid & 63, w = tid >> 6;
  int wr = w >> 1, wc = w & 1;
  int l15 = lane & 15, lg = lane >> 4;
  int m0 = blockIdx.y * 128, n0 = blockIdx.x * 128;
  void* Cw = C;
  int ncol0 = n0;
  int seg = 0;
  if (MODE == 3) {
    seg = n0 >> 10;
    Cw = (seg == 0) ? C : (seg == 1) ? C1 : C2;
    ncol0 = n0 & 1023;
  }
  f32x4 acc[4][4] = {};
  int arow = tid >> 2, acol = (tid & 3) * 8;
  const short* Ap = A + (size_t)(m0 + arow) * K + acol;
  const short* Bp = Bt + (size_t)(n0 + arow) * K + acol;
  int wb = w * 512;
#define STAGE_BT(buf, k0s)                                   \
  {                                                          \
    gl_lds16(Ap + (k0s), &Alds[buf][0] + wb);                \
    gl_lds16(Ap + (size_t)64 * K + (k0s), &Alds[buf][0] + 2048 + wb); \
    gl_lds16(Bp + (k0s), &Blds[buf][0] + wb);                \
    gl_lds16(Bp + (size_t)64 * K + (k0s), &Blds[buf][0] + 2048 + wb); \
  }
  STAGE_BT(0, 0);
  __syncthreads();
  int cur = 0;
  for (int k0 = 0; k0 < K; k0 += 32) {
    if (k0 + 32 < K) STAGE_BT(cur ^ 1, k0 + 32);
    bf16x8 af[4], bfr[4];
#pragma unroll
    for (int i = 0; i < 4; ++i) {
      af[i] = *(const bf16x8*)(&Alds[cur][0] + (wr * 64 + i * 16 + l15) * 32 + lg * 8);
      bfr[i] = *(const bf16x8*)(&Blds[cur][0] + (wc * 64 + i * 16 + l15) * 32 + lg * 8);
    }
#pragma unroll
    for (int mi = 0; mi < 4; ++mi)
#pragma unroll
      for (int ni = 0; ni < 4; ++ni)
        acc[mi][ni] = MFMA16(af[mi], bfr[ni], acc[mi][ni]);
    __syncthreads();
    cur ^= 1;
  }
#undef STAGE_BT
#pragma unroll
  for (int mi = 0; mi < 4; ++mi) {
#pragma unroll
    for (int r = 0; r < 4; ++r) {
      int row = m0 + wr * 64 + mi * 16 + lg * 4 + r;
      size_t base = (size_t)row * N;
#pragma unroll
      for (int ni = 0; ni < 4; ++ni) {
        int col = ncol0 + wc * 64 + ni * 16 + l15;
        float v = acc[mi][ni][r];
        if (MODE == 3 && seg <= 1) {
          int pos = row & 2047;
          int ii = (col & 62) >> 1;
          float invf2 = exp2f(-(float)ii * 0.4152410118f) * 0.15915494309f;
          float rev = (float)pos * invf2;
          rev -= rintf(rev);
          float angr = rev * 6.28318530718f;
          float sn = __sinf(angr), cs = __cosf(angr);
          float partner = __shfl_xor(v, 1, 64);
          float t = partner * sn;
          v = v * cs + (((l15 & 1) == 0) ? -t : t);
        }
        ((short*)Cw)[base + col] = f2b(v);
      }
    }
  }
}

// ---------------- Fused W1+W3 GEMM (r15-proven, 717 TF): 256x256, BK=64, 2-phase.
__global__ __launch_bounds__(512) void gemm256_fused(const short* __restrict__ A,
                                                     const short* __restrict__ B1,
                                                     const short* __restrict__ B3,
                                                     short* __restrict__ C,
                                                     int M, int N, int K) {
  __shared__ __attribute__((aligned(16))) short Alds[2][256 * 64];
  __shared__ __attribute__((aligned(16))) short Blds[2][256 * 64];
  int tid = threadIdx.x;
  int lane = tid & 63, w = tid >> 6;
  int wr = w >> 2, wc = w & 3;  // 2 x 4 waves
  int l15 = lane & 15, lg = lane >> 4;
  int wg = blockIdx.x;
  int swz = (wg & 7) * 32 + (wg >> 3);
  int by = swz >> 4, bx = swz & 15;
  int m0 = by * 256, n0 = bx * 256;
  int rr = tid >> 3;
  int cs = (tid & 7) ^ (rr & 7);
  const short* Apt = A + (size_t)(m0 + rr) * K + cs * 8;
  const short* Bpt1 = B1 + (size_t)(n0 + rr) * K + cs * 8;
  const short* Bpt3 = B3 + (size_t)(n0 + rr) * K + cs * 8;
  int nt = K >> 6;
  f32x4 acc[8][4];
  short4v stash[8][4];
#define STAGE_A(buf, kt)                                                             \
  {                                                                                  \
    int ko = (kt) * 64;                                                              \
    _Pragma("unroll") for (int j = 0; j < 4; ++j)                                    \
        gl_lds16(Apt + (size_t)(j * 64) * K + ko, &Alds[buf][0] + j * 4096 + w * 512); \
  }
#define STAGE_B(buf, kt, Bp)                                                         \
  {                                                                                  \
    int ko = (kt) * 64;                                                              \
    _Pragma("unroll") for (int j = 0; j < 4; ++j)                                    \
        gl_lds16((Bp) + (size_t)(j * 64) * K + ko, &Blds[buf][0] + j * 4096 + w * 512); \
  }
#define KLOOP(Bp)                                                                    \
  {                                                                                  \
    STAGE_A(0, 0);                                                                   \
    STAGE_B(0, 0, Bp);                                                               \
    __syncthreads();                                                                 \
    int cur = 0;                                                                     \
    for (int kt = 0; kt < nt; ++kt) {                                                \
      if (kt + 1 < nt) { STAGE_A(cur ^ 1, kt + 1); STAGE_B(cur ^ 1, kt + 1, Bp); }   \
      _Pragma("unroll") for (int kk = 0; kk < 2; ++kk) {                             \
        bf16x8 af[8], bfr[4];                                                        \
        _Pragma("unroll") for (int i = 0; i < 8; ++i) {                              \
          int ra = wr * 128 + i * 16 + l15;                                          \
          int ua = (kk * 4 + lg) ^ (ra & 7);                                         \
          af[i] = *(const bf16x8*)(&Alds[cur][0] + ra * 64 + ua * 8);                \
        }                                                                            \
        _Pragma("unroll") for (int n = 0; n < 4; ++n) {                              \
          int rb = wc * 64 + n * 16 + l15;                                           \
          int ub = (kk * 4 + lg) ^ (rb & 7);                                         \
          bfr[n] = *(const bf16x8*)(&Blds[cur][0] + rb * 64 + ub * 8);               \
        }                                                                            \
        _Pragma("unroll") for (int i = 0; i < 8; ++i)                                \
        _Pragma("unroll") for (int n = 0; n < 4; ++n)                                \
            acc[i][n] = MFMA16(af[i], bfr[n], acc[i][n]);                            \
      }                                                                              \
      __syncthreads();                                                               \
      cur ^= 1;                                                                      \
    }                                                                                \
  }
  // ---- pass 1: W1 ----
#pragma unroll
  for (int i = 0; i < 8; ++i)
#pragma unroll
    for (int n = 0; n < 4; ++n) acc[i][n] = (f32x4){0.f, 0.f, 0.f, 0.f};
  KLOOP(Bpt1);
#pragma unroll
  for (int i = 0; i < 8; ++i)
#pragma unroll
    for (int n = 0; n < 4; ++n)
#pragma unroll
      for (int r = 0; r < 4; ++r) stash[i][n][r] = f2b(acc[i][n][r]);
  // ---- pass 2: W3 ----
#pragma unroll
  for (int i = 0; i < 8; ++i)
#pragma unroll
    for (int n = 0; n < 4; ++n) acc[i][n] = (f32x4){0.f, 0.f, 0.f, 0.f};
  KLOOP(Bpt3);
#undef KLOOP
#undef STAGE_A
#undef STAGE_B
  // ---- epilogue: C = silu(w1x) * w3x ----
#pragma unroll
  for (int i = 0; i < 8; ++i) {
#pragma unroll
    for (int r = 0; r < 4; ++r) {
      int row = m0 + wr * 128 + i * 16 + lg * 4 + r;
      size_t base = (size_t)row * N;
#pragma unroll
      for (int n = 0; n < 4; ++n) {
        int col = n0 + wc * 64 + n * 16 + l15;
        float w1v = b2f(stash[i][n][r]);
        float v = w1v / (1.f + __expf(-w1v)) * acc[i][n][r];
        C[base + col] = f2b(v);
      }
    }
  }
}

// ---------------- GEMM wide, BK=128 2-phase (r20-proven): 512 thr, 8 waves 2x4,
// 128x128 tile, 32 MFMA/iter, stage_rc swizzle, C = AB + Resf. XCD m-chunk remap.
__global__ __launch_bounds__(512) void gemm_wide(const short* __restrict__ A,
                                                 const short* __restrict__ Bt,
                                                 const float* Res, float* C,
                                                 int M, int N, int K) {
  __shared__ __attribute__((aligned(16))) short Alds[2][128 * 128];
  __shared__ __attribute__((aligned(16))) short Blds[2][128 * 128];
  int tid = threadIdx.x;
  int lane = tid & 63, w = tid >> 6;
  int wr = w >> 2, wc = w & 3;
  int l15 = lane & 15, lg = lane >> 4;
  int lin = blockIdx.y * gridDim.x + blockIdx.x;
  int nx = gridDim.x;
  int xcd = lin & 7, idx = lin >> 3;
  int mpX = (gridDim.y >> 3);
  int m0 = (xcd * mpX + idx / nx) * 128;
  int n0 = (idx % nx) * 128;
  f32x4 acc[4][2] = {};
  int rloc = tid >> 4;
  int csw = (tid & 15) ^ (rloc & 7);
  int wso = w * 512;
#define STG_W(buf, k0s)                                                              \
  {                                                                                  \
    _Pragma("unroll") for (int j = 0; j < 4; ++j) {                                  \
      gl_lds16(A + (size_t)(m0 + j * 32 + rloc) * K + csw * 8 + (k0s),               \
               &Alds[buf][0] + j * 4096 + wso);                                      \
      gl_lds16(Bt + (size_t)(n0 + j * 32 + rloc) * K + csw * 8 + (k0s),              \
               &Blds[buf][0] + j * 4096 + wso);                                      \
    }                                                                                \
  }
  int nk = K >> 7;
  STG_W(0, 0);
  __syncthreads();
  int cur = 0;
  for (int kt = 0; kt < nk; ++kt) {
    if (kt + 1 < nk) STG_W(cur ^ 1, (kt + 1) * 128);
#pragma unroll
    for (int kk = 0; kk < 4; ++kk) {
      bf16x8 af[4], bfr[2];
#pragma unroll
      for (int i = 0; i < 4; ++i) {
        int ra = wr * 64 + i * 16 + l15;
        int ua = (kk * 4 + lg) ^ (ra & 7);
        af[i] = *(const bf16x8*)(&Alds[cur][0] + ra * 128 + ua * 8);
      }
#pragma unroll
      for (int i = 0; i < 2; ++i) {
        int rb = wc * 32 + i * 16 + l15;
        int ub = (kk * 4 + lg) ^ (rb & 7);
        bfr[i] = *(const bf16x8*)(&Blds[cur][0] + rb * 128 + ub * 8);
      }
#pragma unroll
      for (int mi = 0; mi < 4; ++mi)
#pragma unroll
        for (int ni = 0; ni < 2; ++ni)
          acc[mi][ni] = MFMA16(af[mi], bfr[ni], acc[mi][ni]);
    }
    __syncthreads();
    cur ^= 1;
  }
#undef STG_W
#pragma unroll
  for (int mi = 0; mi < 4; ++mi) {
#pragma unroll
    for (int r = 0; r < 4; ++r) {
      int row = m0 + wr * 64 + mi * 16 + lg * 4 + r;
      size_t base = (size_t)row * N;
#pragma unroll
      for (int ni = 0; ni < 2; ++ni) {
        int col = n0 + wc * 32 + ni * 16 + l15;
        C[base + col] = acc[mi][ni][r] + Res[base + col];
      }
    }
  }
}

// ---------------- V transpose: V[B*S][H*64] -> Vt[bh][64][2048] ----------------
__global__ __launch_bounds__(256) void vtranspose(const short* __restrict__ V,
                                                  short* __restrict__ Vt) {
  __shared__ short T[64 * 72];
  int bh = blockIdx.y;
  int s0 = blockIdx.x * 64;
  int t = threadIdx.x;
  int r = t >> 2, cq = t & 3;
  const short* src = V + (size_t)((bh >> 4) * 2048 + s0 + r) * 1024 + (bh & 15) * 64 + cq * 16;
  *(int4*)(T + r * 72 + cq * 16) = *(const int4*)src;
  *(int4*)(T + r * 72 + cq * 16 + 8) = *(const int4*)(src + 8);
  __syncthreads();
  int d = t >> 2, sq = t & 3;
  short* dst = Vt + (size_t)bh * 131072 + (size_t)d * 2048 + s0 + sq * 16;
#pragma unroll
  for (int q = 0; q < 4; ++q) {
    short4v o;
#pragma unroll
    for (int j = 0; j < 4; ++j) o[j] = T[(sq * 16 + q * 4 + j) * 72 + d];
    *(short4v*)(dst + q * 4) = o;
  }
}

// ---------------- Flash attention v6 (r10/r15-proven): LDS-staged K/V, 2-phase
// dbuf, stage_rc XOR swizzle. p = exp(s/8 - 24), l via ones-MFMA.
__global__ __launch_bounds__(256) void attn6(const short* __restrict__ Q,
                                             const short* __restrict__ K,
                                             const short* __restrict__ Vt,
                                             short* __restrict__ O) {
  __shared__ __attribute__((aligned(16))) short Klds[2][64 * 64];
  __shared__ __attribute__((aligned(16))) short Vlds[2][64 * 64];
  __shared__ __attribute__((aligned(16))) short Ptlds[4][64 * 20];
  int bx = blockIdx.x;
  int bh = bx & 31;
  int qt = 31 - (bx >> 5);
  int tid = threadIdx.x;
  int w = tid >> 6, lane = tid & 63;
  int l15 = lane & 15, lg = lane >> 4;
  int qbase = qt * 64 + w * 16;
  size_t rowbase = (size_t)(bh >> 4) * 2048 * 1024 + (size_t)(bh & 15) * 64;
  const short* vtb = Vt + (size_t)bh * 131072;
  const short* Kb0 = K + rowbase;
  bf16x8 qf[2];
  {
    const short* qp = Q + rowbase + (size_t)(qbase + l15) * 1024 + lg * 8;
    qf[0] = *(const bf16x8*)qp;
    qf[1] = *(const bf16x8*)(qp + 32);
  }
  bf16x8 ones;
#pragma unroll
  for (int j = 0; j < 8; ++j) ones[j] = (short)0x3F80;
  f32x4 oacc[4] = {};
  f32x4 lacc = {};
  int nchunk = qt + 1;
  short* pt = Ptlds[w];
  int i0 = w * 64 + lane;
  int r0 = i0 >> 3, c0 = i0 & 7, cs0 = c0 ^ (r0 & 7);
  int i1 = 256 + i0;
  int r1 = i1 >> 3, c1 = i1 & 7, cs1 = c1 ^ (r1 & 7);
#define STAGE_KV(buf, kt)                                                      \
  {                                                                            \
    int ks = (kt) * 64;                                                        \
    gl_lds16(Kb0 + (size_t)(ks + r0) * 1024 + cs0 * 8, &Klds[buf][0] + i0 * 8);\
    gl_lds16(Kb0 + (size_t)(ks + r1) * 1024 + cs1 * 8, &Klds[buf][0] + i1 * 8);\
    gl_lds16(vtb + (size_t)r0 * 2048 + ks + cs0 * 8, &Vlds[buf][0] + i0 * 8);  \
    gl_lds16(vtb + (size_t)r1 * 2048 + ks + cs1 * 8, &Vlds[buf][0] + i1 * 8);  \
  }
  STAGE_KV(0, 0);
  __syncthreads();
  int cur = 0;
  for (int kt = 0; kt < nchunk; ++kt) {
    if (kt + 1 < nchunk) STAGE_KV(cur ^ 1, kt + 1);
    int kstart = kt * 64;
    f32x4 s[4] = {};
#pragma unroll
    for (int g = 0; g < 4; ++g) {
      int krow = g * 16 + l15;
      bf16x8 k0 = *(const bf16x8*)(&Klds[cur][0] + krow * 64 + ((lg ^ (l15 & 7)) * 8));
      bf16x8 k1 = *(const bf16x8*)(&Klds[cur][0] + krow * 64 + (((4 + lg) ^ (l15 & 7)) * 8));
      s[g] = MFMA16(qf[0], k0, s[g]);
      s[g] = MFMA16(qf[1], k1, s[g]);
    }
#pragma unroll
    for (int g = 0; g < 4; ++g) {
      short4v pk;
#pragma unroll
      for (int r = 0; r < 4; ++r) {
        int qg = qbase + lg * 4 + r;
        int kg = kstart + g * 16 + l15;
        float v = __expf(s[g][r] * 0.125f - 24.f);
        pk[r] = f2b((kg > qg) ? 0.f : v);
      }
      *(short4v*)(pt + (g * 16 + l15) * 20 + lg * 4) = pk;
    }
    bf16x8 pa0, pa1;
#pragma unroll
    for (int j = 0; j < 8; ++j) {
      pa0[j] = pt[(lg * 8 + j) * 20 + l15];
      pa1[j] = pt[(32 + lg * 8 + j) * 20 + l15];
    }
#pragma unroll
    for (int t = 0; t < 4; ++t) {
      int drow = t * 16 + l15;
      bf16x8 vf0 = *(const bf16x8*)(&Vlds[cur][0] + drow * 64 + ((lg ^ (l15 & 7)) * 8));
      bf16x8 vf1 = *(const bf16x8*)(&Vlds[cur][0] + drow * 64 + (((4 + lg) ^ (l15 & 7)) * 8));
      oacc[t] = MFMA16(pa0, vf0, oacc[t]);
      oacc[t] = MFMA16(pa1, vf1, oacc[t]);
    }
    lacc = MFMA16(pa0, ones, lacc);
    lacc = MFMA16(pa1, ones, lacc);
    __syncthreads();
    cur ^= 1;
  }
#undef STAGE_KV
#pragma unroll
  for (int t = 0; t < 4; ++t) {
#pragma unroll
    for (int r = 0; r < 4; ++r) {
      int row = qbase + lg * 4 + r;
      float denom = fmaxf(lacc[r], 1e-30f);
      O[rowbase + (size_t)row * 1024 + t * 16 + l15] = f2b(oacc[t][r] / denom);
    }
  }
}

extern "C" void kernel_launch(void* const* d_in, const int* in_sizes, int n_in,
                              void* d_out, int out_size, void* d_ws, size_t ws_size,
                              hipStream_t stream) {
  const float* xf = (const float*)d_in[0];
  const float* G1f = (const float*)d_in[8];
  const float* G2f = (const float*)d_in[9];
  char* ws = (char*)d_ws;
  const size_t MB = 1048576;
  short* Wslot = (short*)(ws);            // [0,8): WOb early, then W1, then W2
  short* WOb   = (short*)(ws);
  short* Wcat  = (short*)(ws + 8 * MB);   // [8,14): fused QKV weights
  short* Vt    = (short*)(ws + 8 * MB);   // [8,16): V^T (after Wcat dead)
  short* h     = (short*)(ws + 16 * MB);  // [16,24)
  short* Qb    = (short*)(ws + 24 * MB);  // [24,32)
  short* Kb    = (short*)(ws + 32 * MB);  // [32,40)
  short* Vb    = (short*)(ws + 40 * MB);  // [40,48)
  short* att   = (short*)(ws + 48 * MB);  // [48,56)
  short* W3b   = (short*)(ws + 56 * MB);  // [56,64): W3 bf16
  short* w1x   = Qb;                      // [24,56): Q/K/V/att dead by FFN time
  float* x1f   = (float*)d_out;
  float* outf  = (float*)d_out;

  dim3 blk(256);
  // batched converts: WQ/WK/WV -> Wcat segments, WO -> WOb (1 launch, was 4)
  convert4<<<2048, blk, 0, stream>>>((const float*)d_in[1], (const float*)d_in[2],
                                     (const float*)d_in[3], (const float*)d_in[4],
                                     Wcat, Wcat + 1048576, Wcat + 2097152, WOb);

  rmsnorm_f32<<<4096, blk, 0, stream>>>(xf, G1f, h);
  dim3 gqkv(24, 32);
  gemm_bt<3><<<gqkv, blk, 0, stream>>>(h, Wcat, nullptr, Qb, Kb, Vb, 4096, 1024, 1024);
  dim3 gvt(32, 32);
  vtranspose<<<gvt, blk, 0, stream>>>(Vb, Vt);
  attn6<<<1024, blk, 0, stream>>>(Qb, Kb, Vt, att);
  dim3 g1(8, 32);
  gemm_wide<<<g1, dim3(512), 0, stream>>>(att, WOb, xf, x1f, 4096, 1024, 1024);
  rmsnorm_f32<<<4096, blk, 0, stream>>>(x1f, G2f, h);
  // batched convert: W1 -> Wslot, W3 -> W3b (1 launch, was 2)
  convert2<<<4096, blk, 0, stream>>>((const float*)d_in[5], (const float*)d_in[7],
                                     Wslot, W3b);
  gemm256_fused<<<256, dim3(512), 0, stream>>>(h, Wslot, W3b, w1x, 4096, 4096, 1024);
  convert_kernel<<<2048, blk, 0, stream>>>((const float*)d_in[6], Wslot, 4194304);
  gemm_wide<<<g1, dim3(512), 0, stream>>>(w1x, Wslot, x1f, outf, 4096, 1024, 4096);
}

// Round 22
// 279.570 us; speedup vs baseline: 1.8790x; 1.0123x over previous
//
#include <hip/hip_runtime.h>
#include <stdint.h>

typedef __attribute__((ext_vector_type(8))) short bf16x8;
typedef __attribute__((ext_vector_type(4))) short short4v;
typedef __attribute__((ext_vector_type(4))) float f32x4;

#define MFMA16(a, b, c) __builtin_amdgcn_mfma_f32_16x16x32_bf16((a), (b), (c), 0, 0, 0)

__device__ __forceinline__ float b2f(short s) {
  unsigned u = ((unsigned)(unsigned short)s) << 16;
  return __builtin_bit_cast(float, u);
}
__device__ __forceinline__ short f2b(float f) {
  unsigned u = __builtin_bit_cast(unsigned, f);
  u = (u + 0x7fffu + ((u >> 16) & 1u)) >> 16;
  return (short)u;
}

// async global->LDS, 16B per lane; lds dest is wave-uniform base (HW adds lane*16)
__device__ __forceinline__ void gl_lds16(const short* g, short* l) {
  __builtin_amdgcn_global_load_lds((const __attribute__((address_space(1))) void*)g,
                                   (__attribute__((address_space(3))) void*)l, 16, 0, 0);
}

__device__ __forceinline__ void conv8(const float* src, short* dst, int i) {
  f32x4 a = *(const f32x4*)(src + i);
  f32x4 b = *(const f32x4*)(src + i + 4);
  short4v o0, o1;
#pragma unroll
  for (int j = 0; j < 4; ++j) { o0[j] = f2b(a[j]); o1[j] = f2b(b[j]); }
  *(short4v*)(dst + i) = o0;
  *(short4v*)(dst + i + 4) = o1;
}

// -------- batched convert: 4 x 1M-elem segments (512 blocks each) --------
__global__ __launch_bounds__(256) void convert4(const float* __restrict__ s0,
                                                const float* __restrict__ s1,
                                                const float* __restrict__ s2,
                                                const float* __restrict__ s3,
                                                short* __restrict__ d0,
                                                short* __restrict__ d1,
                                                short* __restrict__ d2,
                                                short* __restrict__ d3) {
  int b = blockIdx.x;
  int seg = b >> 9;
  const float* src = (seg == 0) ? s0 : (seg == 1) ? s1 : (seg == 2) ? s2 : s3;
  short* dst = (seg == 0) ? d0 : (seg == 1) ? d1 : (seg == 2) ? d2 : d3;
  int i = ((b & 511) * 256 + threadIdx.x) * 8;
  conv8(src, dst, i);
}

// -------- batched convert: 3 x 4M-elem segments (2048 blocks each) --------
__global__ __launch_bounds__(256) void convert3(const float* __restrict__ s0,
                                                const float* __restrict__ s1,
                                                const float* __restrict__ s2,
                                                short* __restrict__ d0,
                                                short* __restrict__ d1,
                                                short* __restrict__ d2) {
  int b = blockIdx.x;
  int seg = b >> 11;
  const float* src = (seg == 0) ? s0 : (seg == 1) ? s1 : s2;
  short* dst = (seg == 0) ? d0 : (seg == 1) ? d1 : d2;
  int i = ((b & 2047) * 256 + threadIdx.x) * 8;
  conv8(src, dst, i);
}

// -------- RMSNorm: f32 in, f32 gamma, bf16 out; one block per row of 1024 --------
__global__ __launch_bounds__(256) void rmsnorm_f32(const float* __restrict__ X,
                                                   const float* __restrict__ G,
                                                   short* __restrict__ O) {
  int row = blockIdx.x;
  int t = threadIdx.x;
  f32x4 v = *(const f32x4*)(X + (size_t)row * 1024 + t * 4);
  float ss = 0.f;
#pragma unroll
  for (int j = 0; j < 4; ++j) ss += v[j] * v[j];
#pragma unroll
  for (int d = 1; d < 64; d <<= 1) ss += __shfl_xor(ss, d, 64);
  __shared__ float red[4];
  if ((t & 63) == 0) red[t >> 6] = ss;
  __syncthreads();
  float tot = red[0] + red[1] + red[2] + red[3];
  float rinv = rsqrtf(tot * (1.0f / 1024.0f) + 1e-5f);
  f32x4 g = *(const f32x4*)(G + t * 4);
  short4v o;
#pragma unroll
  for (int j = 0; j < 4; ++j) o[j] = f2b(v[j] * rinv * g[j]);
  *(short4v*)(O + (size_t)row * 1024 + t * 4) = o;
}

// ---------------- GEMM 2-phase: 256 thr, 4 waves 2x2, 128x128, BK=32, dbuf LDS
// MODE 0: C = AB | MODE 3: QKV-split + fused RoPE
template <int MODE>
__global__ __launch_bounds__(256) void gemm_bt(const short* __restrict__ A,
                                               const short* __restrict__ Bt,
                                               const void* Res, void* C,
                                               void* C1, void* C2,
                                               int M, int N, int K) {
  __shared__ __attribute__((aligned(16))) short Alds[2][128 * 32];
  __shared__ __attribute__((aligned(16))) short Blds[2][128 * 32];
  int tid = threadIdx.x;
  int lane = tid & 63, w = tid >> 6;
  int wr = w >> 1, wc = w & 1;
  int l15 = lane & 15, lg = lane >> 4;
  int m0 = blockIdx.y * 128, n0 = blockIdx.x * 128;
  void* Cw = C;
  int ncol0 = n0;
  int seg = 0;
  if (MODE == 3) {
    seg = n0 >> 10;
    Cw = (seg == 0) ? C : (seg == 1) ? C1 : C2;
    ncol0 = n0 & 1023;
  }
  f32x4 acc[4][4] = {};
  int arow = tid >> 2, acol = (tid & 3) * 8;
  const short* Ap = A + (size_t)(m0 + arow) * K + acol;
  const short* Bp = Bt + (size_t)(n0 + arow) * K + acol;
  int wb = w * 512;
#define STAGE_BT(buf, k0s)                                   \
  {                                                          \
    gl_lds16(Ap + (k0s), &Alds[buf][0] + wb);                \
    gl_lds16(Ap + (size_t)64 * K + (k0s), &Alds[buf][0] + 2048 + wb); \
    gl_lds16(Bp + (k0s), &Blds[buf][0] + wb);                \
    gl_lds16(Bp + (size_t)64 * K + (k0s), &Blds[buf][0] + 2048 + wb); \
  }
  STAGE_BT(0, 0);
  __syncthreads();
  int cur = 0;
  for (int k0 = 0; k0 < K; k0 += 32) {
    if (k0 + 32 < K) STAGE_BT(cur ^ 1, k0 + 32);
    bf16x8 af[4], bfr[4];
#pragma unroll
    for (int i = 0; i < 4; ++i) {
      af[i] = *(const bf16x8*)(&Alds[cur][0] + (wr * 64 + i * 16 + l15) * 32 + lg * 8);
      bfr[i] = *(const bf16x8*)(&Blds[cur][0] + (wc * 64 + i * 16 + l15) * 32 + lg * 8);
    }
#pragma unroll
    for (int mi = 0; mi < 4; ++mi)
#pragma unroll
      for (int ni = 0; ni < 4; ++ni)
        acc[mi][ni] = MFMA16(af[mi], bfr[ni], acc[mi][ni]);
    __syncthreads();
    cur ^= 1;
  }
#undef STAGE_BT
#pragma unroll
  for (int mi = 0; mi < 4; ++mi) {
#pragma unroll
    for (int r = 0; r < 4; ++r) {
      int row = m0 + wr * 64 + mi * 16 + lg * 4 + r;
      size_t base = (size_t)row * N;
#pragma unroll
      for (int ni = 0; ni < 4; ++ni) {
        int col = ncol0 + wc * 64 + ni * 16 + l15;
        float v = acc[mi][ni][r];
        if (MODE == 3 && seg <= 1) {
          int pos = row & 2047;
          int ii = (col & 62) >> 1;
          float invf2 = exp2f(-(float)ii * 0.4152410118f) * 0.15915494309f;
          float rev = (float)pos * invf2;
          rev -= rintf(rev);
          float angr = rev * 6.28318530718f;
          float sn = __sinf(angr), cs = __cosf(angr);
          float partner = __shfl_xor(v, 1, 64);
          float t = partner * sn;
          v = v * cs + (((l15 & 1) == 0) ? -t : t);
        }
        ((short*)Cw)[base + col] = f2b(v);
      }
    }
  }
}

// ---------------- Fused W1+W3 GEMM (r15-proven, 717 TF): 256x256, BK=64, 2-phase.
__global__ __launch_bounds__(512) void gemm256_fused(const short* __restrict__ A,
                                                     const short* __restrict__ B1,
                                                     const short* __restrict__ B3,
                                                     short* __restrict__ C,
                                                     int M, int N, int K) {
  __shared__ __attribute__((aligned(16))) short Alds[2][256 * 64];
  __shared__ __attribute__((aligned(16))) short Blds[2][256 * 64];
  int tid = threadIdx.x;
  int lane = tid & 63, w = tid >> 6;
  int wr = w >> 2, wc = w & 3;  // 2 x 4 waves
  int l15 = lane & 15, lg = lane >> 4;
  int wg = blockIdx.x;
  int swz = (wg & 7) * 32 + (wg >> 3);
  int by = swz >> 4, bx = swz & 15;
  int m0 = by * 256, n0 = bx * 256;
  int rr = tid >> 3;
  int cs = (tid & 7) ^ (rr & 7);
  const short* Apt = A + (size_t)(m0 + rr) * K + cs * 8;
  const short* Bpt1 = B1 + (size_t)(n0 + rr) * K + cs * 8;
  const short* Bpt3 = B3 + (size_t)(n0 + rr) * K + cs * 8;
  int nt = K >> 6;
  f32x4 acc[8][4];
  short4v stash[8][4];
#define STAGE_A(buf, kt)                                                             \
  {                                                                                  \
    int ko = (kt) * 64;                                                              \
    _Pragma("unroll") for (int j = 0; j < 4; ++j)                                    \
        gl_lds16(Apt + (size_t)(j * 64) * K + ko, &Alds[buf][0] + j * 4096 + w * 512); \
  }
#define STAGE_B(buf, kt, Bp)                                                         \
  {                                                                                  \
    int ko = (kt) * 64;                                                              \
    _Pragma("unroll") for (int j = 0; j < 4; ++j)                                    \
        gl_lds16((Bp) + (size_t)(j * 64) * K + ko, &Blds[buf][0] + j * 4096 + w * 512); \
  }
#define KLOOP(Bp)                                                                    \
  {                                                                                  \
    STAGE_A(0, 0);                                                                   \
    STAGE_B(0, 0, Bp);                                                               \
    __syncthreads();                                                                 \
    int cur = 0;                                                                     \
    for (int kt = 0; kt < nt; ++kt) {                                                \
      if (kt + 1 < nt) { STAGE_A(cur ^ 1, kt + 1); STAGE_B(cur ^ 1, kt + 1, Bp); }   \
      _Pragma("unroll") for (int kk = 0; kk < 2; ++kk) {                             \
        bf16x8 af[8], bfr[4];                                                        \
        _Pragma("unroll") for (int i = 0; i < 8; ++i) {                              \
          int ra = wr * 128 + i * 16 + l15;                                          \
          int ua = (kk * 4 + lg) ^ (ra & 7);                                         \
          af[i] = *(const bf16x8*)(&Alds[cur][0] + ra * 64 + ua * 8);                \
        }                                                                            \
        _Pragma("unroll") for (int n = 0; n < 4; ++n) {                              \
          int rb = wc * 64 + n * 16 + l15;                                           \
          int ub = (kk * 4 + lg) ^ (rb & 7);                                         \
          bfr[n] = *(const bf16x8*)(&Blds[cur][0] + rb * 64 + ub * 8);               \
        }                                                                            \
        _Pragma("unroll") for (int i = 0; i < 8; ++i)                                \
        _Pragma("unroll") for (int n = 0; n < 4; ++n)                                \
            acc[i][n] = MFMA16(af[i], bfr[n], acc[i][n]);                            \
      }                                                                              \
      __syncthreads();                                                               \
      cur ^= 1;                                                                      \
    }                                                                                \
  }
  // ---- pass 1: W1 ----
#pragma unroll
  for (int i = 0; i < 8; ++i)
#pragma unroll
    for (int n = 0; n < 4; ++n) acc[i][n] = (f32x4){0.f, 0.f, 0.f, 0.f};
  KLOOP(Bpt1);
#pragma unroll
  for (int i = 0; i < 8; ++i)
#pragma unroll
    for (int n = 0; n < 4; ++n)
#pragma unroll
      for (int r = 0; r < 4; ++r) stash[i][n][r] = f2b(acc[i][n][r]);
  // ---- pass 2: W3 ----
#pragma unroll
  for (int i = 0; i < 8; ++i)
#pragma unroll
    for (int n = 0; n < 4; ++n) acc[i][n] = (f32x4){0.f, 0.f, 0.f, 0.f};
  KLOOP(Bpt3);
#undef KLOOP
#undef STAGE_A
#undef STAGE_B
  // ---- epilogue: C = silu(w1x) * w3x ----
#pragma unroll
  for (int i = 0; i < 8; ++i) {
#pragma unroll
    for (int r = 0; r < 4; ++r) {
      int row = m0 + wr * 128 + i * 16 + lg * 4 + r;
      size_t base = (size_t)row * N;
#pragma unroll
      for (int n = 0; n < 4; ++n) {
        int col = n0 + wc * 64 + n * 16 + l15;
        float w1v = b2f(stash[i][n][r]);
        float v = w1v / (1.f + __expf(-w1v)) * acc[i][n][r];
        C[base + col] = f2b(v);
      }
    }
  }
}

// ---------------- GEMM wide, BK=128 2-phase (r20-proven): 512 thr, 8 waves 2x4,
// 128x128 tile, 32 MFMA/iter, stage_rc swizzle, C = AB + Resf. XCD m-chunk remap.
__global__ __launch_bounds__(512) void gemm_wide(const short* __restrict__ A,
                                                 const short* __restrict__ Bt,
                                                 const float* Res, float* C,
                                                 int M, int N, int K) {
  __shared__ __attribute__((aligned(16))) short Alds[2][128 * 128];
  __shared__ __attribute__((aligned(16))) short Blds[2][128 * 128];
  int tid = threadIdx.x;
  int lane = tid & 63, w = tid >> 6;
  int wr = w >> 2, wc = w & 3;
  int l15 = lane & 15, lg = lane >> 4;
  int lin = blockIdx.y * gridDim.x + blockIdx.x;
  int nx = gridDim.x;
  int xcd = lin & 7, idx = lin >> 3;
  int mpX = (gridDim.y >> 3);
  int m0 = (xcd * mpX + idx / nx) * 128;
  int n0 = (idx % nx) * 128;
  f32x4 acc[4][2] = {};
  int rloc = tid >> 4;
  int csw = (tid & 15) ^ (rloc & 7);
  int wso = w * 512;
#define STG_W(buf, k0s)                                                              \
  {                                                                                  \
    _Pragma("unroll") for (int j = 0; j < 4; ++j) {                                  \
      gl_lds16(A + (size_t)(m0 + j * 32 + rloc) * K + csw * 8 + (k0s),               \
               &Alds[buf][0] + j * 4096 + wso);                                      \
      gl_lds16(Bt + (size_t)(n0 + j * 32 + rloc) * K + csw * 8 + (k0s),              \
               &Blds[buf][0] + j * 4096 + wso);                                      \
    }                                                                                \
  }
  int nk = K >> 7;
  STG_W(0, 0);
  __syncthreads();
  int cur = 0;
  for (int kt = 0; kt < nk; ++kt) {
    if (kt + 1 < nk) STG_W(cur ^ 1, (kt + 1) * 128);
#pragma unroll
    for (int kk = 0; kk < 4; ++kk) {
      bf16x8 af[4], bfr[2];
#pragma unroll
      for (int i = 0; i < 4; ++i) {
        int ra = wr * 64 + i * 16 + l15;
        int ua = (kk * 4 + lg) ^ (ra & 7);
        af[i] = *(const bf16x8*)(&Alds[cur][0] + ra * 128 + ua * 8);
      }
#pragma unroll
      for (int i = 0; i < 2; ++i) {
        int rb = wc * 32 + i * 16 + l15;
        int ub = (kk * 4 + lg) ^ (rb & 7);
        bfr[i] = *(const bf16x8*)(&Blds[cur][0] + rb * 128 + ub * 8);
      }
#pragma unroll
      for (int mi = 0; mi < 4; ++mi)
#pragma unroll
        for (int ni = 0; ni < 2; ++ni)
          acc[mi][ni] = MFMA16(af[mi], bfr[ni], acc[mi][ni]);
    }
    __syncthreads();
    cur ^= 1;
  }
#undef STG_W
#pragma unroll
  for (int mi = 0; mi < 4; ++mi) {
#pragma unroll
    for (int r = 0; r < 4; ++r) {
      int row = m0 + wr * 64 + mi * 16 + lg * 4 + r;
      size_t base = (size_t)row * N;
#pragma unroll
      for (int ni = 0; ni < 2; ++ni) {
        int col = n0 + wc * 32 + ni * 16 + l15;
        C[base + col] = acc[mi][ni][r] + Res[base + col];
      }
    }
  }
}

// ---------------- V transpose: V[B*S][H*64] -> Vt[bh][64][2048] ----------------
__global__ __launch_bounds__(256) void vtranspose(const short* __restrict__ V,
                                                  short* __restrict__ Vt) {
  __shared__ short T[64 * 72];
  int bh = blockIdx.y;
  int s0 = blockIdx.x * 64;
  int t = threadIdx.x;
  int r = t >> 2, cq = t & 3;
  const short* src = V + (size_t)((bh >> 4) * 2048 + s0 + r) * 1024 + (bh & 15) * 64 + cq * 16;
  *(int4*)(T + r * 72 + cq * 16) = *(const int4*)src;
  *(int4*)(T + r * 72 + cq * 16 + 8) = *(const int4*)(src + 8);
  __syncthreads();
  int d = t >> 2, sq = t & 3;
  short* dst = Vt + (size_t)bh * 131072 + (size_t)d * 2048 + s0 + sq * 16;
#pragma unroll
  for (int q = 0; q < 4; ++q) {
    short4v o;
#pragma unroll
    for (int j = 0; j < 4; ++j) o[j] = T[(sq * 16 + q * 4 + j) * 72 + d];
    *(short4v*)(dst + q * 4) = o;
  }
}

// ---------------- Flash attention v6 (r10/r15-proven): LDS-staged K/V, 2-phase
// dbuf, stage_rc XOR swizzle. p = exp(s/8 - 24), l via ones-MFMA.
__global__ __launch_bounds__(256) void attn6(const short* __restrict__ Q,
                                             const short* __restrict__ K,
                                             const short* __restrict__ Vt,
                                             short* __restrict__ O) {
  __shared__ __attribute__((aligned(16))) short Klds[2][64 * 64];
  __shared__ __attribute__((aligned(16))) short Vlds[2][64 * 64];
  __shared__ __attribute__((aligned(16))) short Ptlds[4][64 * 20];
  int bx = blockIdx.x;
  int bh = bx & 31;
  int qt = 31 - (bx >> 5);
  int tid = threadIdx.x;
  int w = tid >> 6, lane = tid & 63;
  int l15 = lane & 15, lg = lane >> 4;
  int qbase = qt * 64 + w * 16;
  size_t rowbase = (size_t)(bh >> 4) * 2048 * 1024 + (size_t)(bh & 15) * 64;
  const short* vtb = Vt + (size_t)bh * 131072;
  const short* Kb0 = K + rowbase;
  bf16x8 qf[2];
  {
    const short* qp = Q + rowbase + (size_t)(qbase + l15) * 1024 + lg * 8;
    qf[0] = *(const bf16x8*)qp;
    qf[1] = *(const bf16x8*)(qp + 32);
  }
  bf16x8 ones;
#pragma unroll
  for (int j = 0; j < 8; ++j) ones[j] = (short)0x3F80;
  f32x4 oacc[4] = {};
  f32x4 lacc = {};
  int nchunk = qt + 1;
  short* pt = Ptlds[w];
  int i0 = w * 64 + lane;
  int r0 = i0 >> 3, c0 = i0 & 7, cs0 = c0 ^ (r0 & 7);
  int i1 = 256 + i0;
  int r1 = i1 >> 3, c1 = i1 & 7, cs1 = c1 ^ (r1 & 7);
#define STAGE_KV(buf, kt)                                                      \
  {                                                                            \
    int ks = (kt) * 64;                                                        \
    gl_lds16(Kb0 + (size_t)(ks + r0) * 1024 + cs0 * 8, &Klds[buf][0] + i0 * 8);\
    gl_lds16(Kb0 + (size_t)(ks + r1) * 1024 + cs1 * 8, &Klds[buf][0] + i1 * 8);\
    gl_lds16(vtb + (size_t)r0 * 2048 + ks + cs0 * 8, &Vlds[buf][0] + i0 * 8);  \
    gl_lds16(vtb + (size_t)r1 * 2048 + ks + cs1 * 8, &Vlds[buf][0] + i1 * 8);  \
  }
  STAGE_KV(0, 0);
  __syncthreads();
  int cur = 0;
  for (int kt = 0; kt < nchunk; ++kt) {
    if (kt + 1 < nchunk) STAGE_KV(cur ^ 1, kt + 1);
    int kstart = kt * 64;
    f32x4 s[4] = {};
#pragma unroll
    for (int g = 0; g < 4; ++g) {
      int krow = g * 16 + l15;
      bf16x8 k0 = *(const bf16x8*)(&Klds[cur][0] + krow * 64 + ((lg ^ (l15 & 7)) * 8));
      bf16x8 k1 = *(const bf16x8*)(&Klds[cur][0] + krow * 64 + (((4 + lg) ^ (l15 & 7)) * 8));
      s[g] = MFMA16(qf[0], k0, s[g]);
      s[g] = MFMA16(qf[1], k1, s[g]);
    }
#pragma unroll
    for (int g = 0; g < 4; ++g) {
      short4v pk;
#pragma unroll
      for (int r = 0; r < 4; ++r) {
        int qg = qbase + lg * 4 + r;
        int kg = kstart + g * 16 + l15;
        float v = __expf(s[g][r] * 0.125f - 24.f);
        pk[r] = f2b((kg > qg) ? 0.f : v);
      }
      *(short4v*)(pt + (g * 16 + l15) * 20 + lg * 4) = pk;
    }
    bf16x8 pa0, pa1;
#pragma unroll
    for (int j = 0; j < 8; ++j) {
      pa0[j] = pt[(lg * 8 + j) * 20 + l15];
      pa1[j] = pt[(32 + lg * 8 + j) * 20 + l15];
    }
#pragma unroll
    for (int t = 0; t < 4; ++t) {
      int drow = t * 16 + l15;
      bf16x8 vf0 = *(const bf16x8*)(&Vlds[cur][0] + drow * 64 + ((lg ^ (l15 & 7)) * 8));
      bf16x8 vf1 = *(const bf16x8*)(&Vlds[cur][0] + drow * 64 + (((4 + lg) ^ (l15 & 7)) * 8));
      oacc[t] = MFMA16(pa0, vf0, oacc[t]);
      oacc[t] = MFMA16(pa1, vf1, oacc[t]);
    }
    lacc = MFMA16(pa0, ones, lacc);
    lacc = MFMA16(pa1, ones, lacc);
    __syncthreads();
    cur ^= 1;
  }
#undef STAGE_KV
#pragma unroll
  for (int t = 0; t < 4; ++t) {
#pragma unroll
    for (int r = 0; r < 4; ++r) {
      int row = qbase + lg * 4 + r;
      float denom = fmaxf(lacc[r], 1e-30f);
      O[rowbase + (size_t)row * 1024 + t * 16 + l15] = f2b(oacc[t][r] / denom);
    }
  }
}

extern "C" void kernel_launch(void* const* d_in, const int* in_sizes, int n_in,
                              void* d_out, int out_size, void* d_ws, size_t ws_size,
                              hipStream_t stream) {
  const float* xf = (const float*)d_in[0];
  const float* G1f = (const float*)d_in[8];
  const float* G2f = (const float*)d_in[9];
  char* ws = (char*)d_ws;
  const size_t MB = 1048576;
  short* Wslot = (short*)(ws);            // [0,8): WOb early, then W1
  short* WOb   = (short*)(ws);
  short* Wcat  = (short*)(ws + 8 * MB);   // [8,14): fused QKV weights
  short* Vt    = (short*)(ws + 8 * MB);   // [8,16): V^T (after Wcat dead); then W2
  short* W2b   = (short*)(ws + 8 * MB);   //   (Vt dead after attn6)
  short* h     = (short*)(ws + 16 * MB);  // [16,24)
  short* Qb    = (short*)(ws + 24 * MB);  // [24,32)
  short* Kb    = (short*)(ws + 32 * MB);  // [32,40)
  short* Vb    = (short*)(ws + 40 * MB);  // [40,48)
  short* att   = (short*)(ws + 48 * MB);  // [48,56)
  short* W3b   = (short*)(ws + 56 * MB);  // [56,64): W3 bf16
  short* w1x   = Qb;                      // [24,56): Q/K/V/att dead by FFN time
  float* x1f   = (float*)d_out;
  float* outf  = (float*)d_out;

  dim3 blk(256);
  // batched converts: WQ/WK/WV -> Wcat segments, WO -> WOb (1 launch)
  convert4<<<2048, blk, 0, stream>>>((const float*)d_in[1], (const float*)d_in[2],
                                     (const float*)d_in[3], (const float*)d_in[4],
                                     Wcat, Wcat + 1048576, Wcat + 2097152, WOb);

  rmsnorm_f32<<<4096, blk, 0, stream>>>(xf, G1f, h);
  dim3 gqkv(24, 32);
  gemm_bt<3><<<gqkv, blk, 0, stream>>>(h, Wcat, nullptr, Qb, Kb, Vb, 4096, 1024, 1024);
  dim3 gvt(32, 32);
  vtranspose<<<gvt, blk, 0, stream>>>(Vb, Vt);
  attn6<<<1024, blk, 0, stream>>>(Qb, Kb, Vt, att);
  dim3 g1(8, 32);
  gemm_wide<<<g1, dim3(512), 0, stream>>>(att, WOb, xf, x1f, 4096, 1024, 1024);
  rmsnorm_f32<<<4096, blk, 0, stream>>>(x1f, G2f, h);
  // batched convert: W1 -> Wslot, W3 -> W3b, W2 -> W2b (Vt region, dead) (1 launch)
  convert3<<<6144, blk, 0, stream>>>((const float*)d_in[5], (const float*)d_in[7],
                                     (const float*)d_in[6], Wslot, W3b, W2b);
  gemm256_fused<<<256, dim3(512), 0, stream>>>(h, Wslot, W3b, w1x, 4096, 4096, 1024);
  gemm_wide<<<g1, dim3(512), 0, stream>>>(w1x, W2b, x1f, outf, 4096, 1024, 4096);
}